// Round 6
// baseline (728.581 us; speedup 1.0000x reference)
//
#include <hip/hip_runtime.h>
#include <math.h>

// Problem constants (from reference)
constexpr int B    = 512;
constexpr int NPG  = 200;    // nodes per graph, stage 0
constexpr int EPER = 2000;   // edges per graph
constexpr int EMB  = 9;
constexpr int HID  = 128;
constexpr int K1   = 160;    // ceil(0.8*200)
constexpr int K2   = 128;    // ceil(0.8*160)
constexpr int K3   = 103;    // ceil(0.8*128)
constexpr int N0   = B * NPG;   // 102400
constexpr int N1   = B * K1;    // 81920
constexpr int N2   = B * K2;    // 65536
constexpr int N3   = B * K3;    // 52736
constexpr int E    = B * EPER;  // 1024000

// ---------------------------------------------------------------------------
// Embedding gather: x0[n][:] = emb[node_ids[n]][:]
__global__ __launch_bounds__(256) void k_gather(const int* __restrict__ node_ids,
                         const float* __restrict__ emb,
                         float* __restrict__ x0) {
    int n = blockIdx.x * blockDim.x + threadIdx.x;
    if (n < N0) {
        int id = node_ids[n];
        #pragma unroll
        for (int j = 0; j < EMB; j++) x0[n * EMB + j] = emb[id * EMB + j];
    }
}

// ---------------------------------------------------------------------------
// Stage-1 aggregation (width EMB=9), all edges valid. One block per graph,
// accumulate in LDS, write the MEAN directly (conv1 needs no cnt).
__global__ __launch_bounds__(256) void k_agg9(const float* __restrict__ x0,
                       const int* __restrict__ esrc,
                       const int* __restrict__ edst,
                       float* __restrict__ m9) {
    int g = blockIdx.x;
    __shared__ float lacc[NPG * EMB];
    __shared__ float lcnt[NPG];
    for (int i = threadIdx.x; i < NPG * EMB; i += 256) lacc[i] = 0.f;
    for (int i = threadIdx.x; i < NPG; i += 256) lcnt[i] = 0.f;
    __syncthreads();
    const int ebase = g * EPER;
    const int nbase = g * NPG;
    for (int idx = threadIdx.x; idx < EPER * EMB; idx += 256) {
        int el = idx / EMB;
        int j  = idx - el * EMB;
        int e  = ebase + el;
        int src = esrc[e];
        int dl  = edst[e] - nbase;
        atomicAdd(&lacc[dl * EMB + j], x0[src * EMB + j]);
        if (j == 0) atomicAdd(&lcnt[dl], 1.f);
    }
    __syncthreads();
    for (int i = threadIdx.x; i < NPG * EMB; i += 256) {
        int row = i / EMB;
        m9[nbase * EMB + i] = lacc[i] / fmaxf(lcnt[row], 1.f);
    }
}

// ---------------------------------------------------------------------------
// Stage-2/3 aggregation, CSR-based, with FUSED edge remap: takes the raw
// edge list + mapping chain (map1[, map2]) and computes validity inline.
// One block per (graph, feature-half). Emits the MEAN directly.
__global__ __launch_bounds__(256) void k_aggcsr(const float* __restrict__ x,
                         const int* __restrict__ es,
                         const int* __restrict__ ed,
                         const int* __restrict__ map1,
                         const int* __restrict__ map2,   // may be null
                         int npc,
                         float* __restrict__ sout) {
    int g = blockIdx.x;
    int w = blockIdx.y;   // feature half (0/1)
    int tid = threadIdx.x;  // 256
    __shared__ int deg[256];
    __shared__ int scanbuf[256];
    __shared__ int off[257];
    __shared__ int cur[256];
    __shared__ int csr[EPER];

    deg[tid] = 0;
    __syncthreads();
    const int ebase = g * EPER;
    const int nbase = g * npc;
    // pass 1: degrees (remap on the fly)
    for (int e = tid; e < EPER; e += 256) {
        int a = map1[es[ebase + e]];
        int b = map1[ed[ebase + e]];
        if (map2) {
            a = (a >= 0) ? map2[a] : -1;
            b = (b >= 0) ? map2[b] : -1;
        }
        if (a >= 0 && b >= 0) atomicAdd(&deg[b - nbase], 1);
    }
    __syncthreads();
    // Hillis-Steele inclusive scan over 256 entries
    int v = deg[tid];
    scanbuf[tid] = v;
    __syncthreads();
    #pragma unroll
    for (int d = 1; d < 256; d <<= 1) {
        int t = (tid >= d) ? scanbuf[tid - d] : 0;
        __syncthreads();
        scanbuf[tid] += t;
        __syncthreads();
    }
    if (tid == 0) off[0] = 0;
    off[tid + 1] = scanbuf[tid];
    __syncthreads();
    cur[tid] = off[tid];
    __syncthreads();
    // pass 2: scatter src ids into CSR slots
    for (int e = tid; e < EPER; e += 256) {
        int a = map1[es[ebase + e]];
        int b = map1[ed[ebase + e]];
        if (map2) {
            a = (a >= 0) ? map2[a] : -1;
            b = (b >= 0) ? map2[b] : -1;
        }
        if (a >= 0 && b >= 0) {
            int slot = atomicAdd(&cur[b - nbase], 1);
            csr[slot] = a;
        }
    }
    __syncthreads();
    // phase 2: one wave per dst, register accumulation, write mean
    int lane = tid & 63, wv = tid >> 6;
    int hoff = w * 64 + lane;
    for (int dl = wv; dl < npc; dl += 4) {
        int beg = off[dl], end = off[dl + 1];
        float acc = 0.f, acc2 = 0.f;
        int t = beg;
        for (; t + 1 < end; t += 2) {
            acc  += x[(long)csr[t]     * HID + hoff];
            acc2 += x[(long)csr[t + 1] * HID + hoff];
        }
        if (t < end) acc += x[(long)csr[t] * HID + hoff];
        float inv = 1.f / (float)((end - beg) > 1 ? (end - beg) : 1);
        sout[(long)(nbase + dl) * HID + hoff] = (acc + acc2) * inv;
    }
}

// ---------------------------------------------------------------------------
// Conv1: out[n][h] = relu( m9[n] . w1n[h] + x0[n] . w1r[h] + b[h] )
// m9 already holds the neighbor mean.
template <int NB>
__global__ __launch_bounds__(128) void k_conv1(const float* __restrict__ m9,
                        const float* __restrict__ x0,
                        const float* __restrict__ wn,
                        const float* __restrict__ wr,
                        const float* __restrict__ bb,
                        float* __restrict__ out) {
    __shared__ float sm[NB][EMB];
    __shared__ float sx[NB][EMB];
    int nb0 = blockIdx.x * NB;
    int h = threadIdx.x;  // 128
    for (int i = h; i < NB * EMB; i += 128) {
        int sl = i / EMB, j = i - sl * EMB;
        int n = nb0 + sl;
        sm[sl][j] = m9[n * EMB + j];
        sx[sl][j] = x0[n * EMB + j];
    }
    __syncthreads();
    float acc[NB];
    #pragma unroll
    for (int sl = 0; sl < NB; sl++) acc[sl] = bb[h];
    #pragma unroll
    for (int j = 0; j < EMB; j++) {
        float a = wn[h * EMB + j];
        float r = wr[h * EMB + j];
        #pragma unroll
        for (int sl = 0; sl < NB; sl++) acc[sl] += sm[sl][j] * a + sx[sl][j] * r;
    }
    #pragma unroll
    for (int sl = 0; sl < NB; sl++)
        out[(long)(nb0 + sl) * HID + h] = fmaxf(acc[sl], 0.f);
}

// ---------------------------------------------------------------------------
// Conv2/3 as LDS-tiled fp32 GEMM, K=256 (concat [mean_s, x] vs [wn; wr]).
// Row-major LDS tiles, pitch 36 floats, 16B-chunk XOR swizzle
// (chunk' = kq ^ (row>>3)): staging is direct float4 -> ds_write_b128.
// Inner loop per k-quad: load the 8 B-column fragments once (bf[8]), then
// stream A fragments one float4 at a time -> live set ~150 VGPRs, fits the
// (256,2) budget WITHOUT spilling (round-5 (256,3) + af[8] spilled acc to
// scratch: WRITE_SIZE 41->195 MB. Do not tighten the bound again.)
// In-place safe (out may alias s): block reads only its own 128 rows of s
// (all during prefetch of chunks 0..3), stores only in the epilogue.
constexpr int TP = 36;  // LDS row pitch in floats (9 bank-quads)
__global__ __launch_bounds__(256, 2) void k_convgemm(
        const float* s,                      // neighbor MEAN; may alias out
        const float* xin,
        const float* __restrict__ wn,
        const float* __restrict__ wr,
        const float* __restrict__ bb,
        float* out) {
    __shared__ float As[128 * TP];
    __shared__ float Bs[128 * TP];
    const int tid = threadIdx.x;
    const long row0 = (long)blockIdx.x * 128;
    const int srow = tid >> 3;      // 0..31 (+32i)
    const int skq  = tid & 7;       // staging k-quad
    const int tc = tid & 15, tr = tid >> 4;

    float acc[8][8];
    #pragma unroll
    for (int r = 0; r < 8; r++)
        #pragma unroll
        for (int c = 0; c < 8; c++) acc[r][c] = 0.f;

    // prefetch chunk 0
    float4 av[4], bv[4];
    #pragma unroll
    for (int i = 0; i < 4; i++) {
        int m = srow + 32 * i;
        av[i] = *(const float4*)(s  + (row0 + m) * HID + skq * 4);
        bv[i] = *(const float4*)(wn + (size_t)m * HID + skq * 4);
    }

    for (int ch = 0; ch < 8; ch++) {
        __syncthreads();
        #pragma unroll
        for (int i = 0; i < 4; i++) {
            int m = srow + 32 * i;
            int swz = skq ^ ((m >> 3) & 7);
            *(float4*)&As[m * TP + swz * 4] = av[i];
            *(float4*)&Bs[m * TP + swz * 4] = bv[i];
        }
        __syncthreads();
        if (ch + 1 < 8) {
            const float* xs = (ch + 1 < 4) ? s : xin;
            const float* ws = (ch + 1 < 4) ? wn : wr;
            int k0 = ((ch + 1) & 3) * 32;
            #pragma unroll
            for (int i = 0; i < 4; i++) {
                int m = srow + 32 * i;
                av[i] = *(const float4*)(xs + (row0 + m) * HID + k0 + skq * 4);
                bv[i] = *(const float4*)(ws + (size_t)m * HID + k0 + skq * 4);
            }
        }
        for (int kq = 0; kq < 8; kq++) {
            float4 bf[8];
            #pragma unroll
            for (int cp = 0; cp < 8; cp++) {
                int col = (cp < 4) ? (tc * 4 + cp) : (64 + tc * 4 + (cp - 4));
                bf[cp] = *(const float4*)&Bs[col * TP + (kq ^ ((col >> 3) & 7)) * 4];
            }
            #pragma unroll
            for (int rr = 0; rr < 8; rr++) {
                int m = tr * 8 + rr;
                float4 af = *(const float4*)&As[m * TP + (kq ^ (tr & 7)) * 4];
                #pragma unroll
                for (int cp = 0; cp < 8; cp++)
                    acc[rr][cp] += af.x * bf[cp].x + af.y * bf[cp].y +
                                   af.z * bf[cp].z + af.w * bf[cp].w;
            }
        }
    }

    // epilogue: bias + relu, coalesced float4 stores
    float4 bias0 = *(const float4*)&bb[tc * 4];
    float4 bias1 = *(const float4*)&bb[64 + tc * 4];
    #pragma unroll
    for (int r = 0; r < 8; r++) {
        long m = row0 + tr * 8 + r;
        float4 o0, o1;
        o0.x = fmaxf(acc[r][0] + bias0.x, 0.f);
        o0.y = fmaxf(acc[r][1] + bias0.y, 0.f);
        o0.z = fmaxf(acc[r][2] + bias0.z, 0.f);
        o0.w = fmaxf(acc[r][3] + bias0.w, 0.f);
        o1.x = fmaxf(acc[r][4] + bias1.x, 0.f);
        o1.y = fmaxf(acc[r][5] + bias1.y, 0.f);
        o1.z = fmaxf(acc[r][6] + bias1.z, 0.f);
        o1.w = fmaxf(acc[r][7] + bias1.w, 0.f);
        *(float4*)(out + m * HID + tc * 4) = o0;
        *(float4*)(out + m * HID + 64 + tc * 4) = o1;
    }
}

// ---------------------------------------------------------------------------
// TopK pool + FUSED global max/mean pool.
// score = tanh(x.p/||p||); jax.lax.top_k semantics (descending, lower index
// wins ties); xout[g*k+rank] = x[node]*score; mapping old->new (or -1);
// gout[g][0:128] = max over kept rows, gout[g][128:256] = mean.
__global__ __launch_bounds__(256) void k_pool(const float* __restrict__ x,
                       const float* __restrict__ p,
                       int npc, int k,
                       float* __restrict__ xout,
                       int* __restrict__ mapping,
                       float* __restrict__ gout) {
    int g = blockIdx.x;
    int tid = threadIdx.x;  // 256
    __shared__ float sc[256];
    __shared__ int   pos[256];
    __shared__ float redm[128];
    __shared__ float reds[128];
    int lane = tid & 63, wv = tid >> 6;
    float pl0 = p[lane], pl1 = p[64 + lane];
    // ||p||^2 via butterfly
    float pp = pl0 * pl0 + pl1 * pl1;
    #pragma unroll
    for (int o = 32; o >= 1; o >>= 1) pp += __shfl_xor(pp, o, 64);
    float nrm = sqrtf(pp);
    // scores: one wave per row, coalesced reads + butterfly reduce
    for (int i = wv; i < npc; i += 4) {
        const float* xr = x + (long)(g * npc + i) * HID;
        float d = xr[lane] * pl0 + xr[64 + lane] * pl1;
        #pragma unroll
        for (int o = 32; o >= 1; o >>= 1) d += __shfl_xor(d, o, 64);
        if (lane == 0) sc[i] = tanhf(d / nrm);
    }
    __syncthreads();
    // rank = position in descending stable order
    if (tid < npc) {
        float scv = sc[tid];
        int rank = 0;
        for (int j = 0; j < npc; j++) {
            float o = sc[j];
            rank += (o > scv) || (o == scv && j < tid);
        }
        bool keep = rank < k;
        pos[tid] = keep ? rank : -1;
        mapping[g * npc + tid] = keep ? (g * k + rank) : -1;
    }
    __syncthreads();
    // gather + scale into new ordering; accumulate global max/sum per column
    int h = tid & 127, half = tid >> 7;
    float pmax = -INFINITY, psum = 0.f;
    for (int i = half; i < npc; i += 2) {
        int r = pos[i];
        if (r >= 0) {
            float v = x[(long)(g * npc + i) * HID + h] * sc[i];
            xout[(long)(g * k + r) * HID + h] = v;
            pmax = fmaxf(pmax, v);
            psum += v;
        }
    }
    if (half) { redm[h] = pmax; reds[h] = psum; }
    __syncthreads();
    if (!half) {
        pmax = fmaxf(pmax, redm[h]);
        psum += reds[h];
        gout[g * 256 + h] = pmax;
        gout[g * 256 + 128 + h] = psum / (float)k;
    }
}

// ---------------------------------------------------------------------------
// MLP head: h=g1+g2+g3; relu(h@lw1.T+lb1); relu(@lw2.T+lb2); sigmoid(@lw3.T+lb3)
__global__ __launch_bounds__(128) void k_mlp(const float* __restrict__ g1, const float* __restrict__ g2,
                      const float* __restrict__ g3,
                      const float* __restrict__ lw1, const float* __restrict__ lb1,
                      const float* __restrict__ lw2, const float* __restrict__ lb2,
                      const float* __restrict__ lw3, const float* __restrict__ lb3,
                      float* __restrict__ out) {
    int g = blockIdx.x, t = threadIdx.x;  // 128 threads
    __shared__ float h0[256];
    __shared__ float h1[128];
    __shared__ float h2r[64];
    h0[t]       = g1[g * 256 + t] + g2[g * 256 + t] + g3[g * 256 + t];
    h0[t + 128] = g1[g * 256 + 128 + t] + g2[g * 256 + 128 + t] + g3[g * 256 + 128 + t];
    __syncthreads();
    float a = lb1[t];
    #pragma unroll 4
    for (int j = 0; j < 256; j++) a += h0[j] * lw1[t * 256 + j];
    h1[t] = fmaxf(a, 0.f);
    __syncthreads();
    if (t < 64) {
        float a2 = lb2[t];
        #pragma unroll 4
        for (int j = 0; j < 128; j++) a2 += h1[j] * lw2[t * 128 + j];
        h2r[t] = fmaxf(a2, 0.f) * lw3[t];
    }
    __syncthreads();
    if (t == 0) {
        float s = 0.f;
        for (int j = 0; j < 64; j++) s += h2r[j];
        s += lb3[0];
        out[g] = 1.f / (1.f + expf(-s));
    }
}

// ---------------------------------------------------------------------------
extern "C" void kernel_launch(void* const* d_in, const int* in_sizes, int n_in,
                              void* d_out, int out_size, void* d_ws, size_t ws_size,
                              hipStream_t stream) {
    const int*   node_ids = (const int*)d_in[0];
    const int*   ei   = (const int*)d_in[1];   // edge_index (2, E)
    const float* emb  = (const float*)d_in[3];
    const float* w1n  = (const float*)d_in[4];
    const float* w1r  = (const float*)d_in[5];
    const float* b1   = (const float*)d_in[6];
    const float* w2n  = (const float*)d_in[7];
    const float* w2r  = (const float*)d_in[8];
    const float* b2   = (const float*)d_in[9];
    const float* w3n  = (const float*)d_in[10];
    const float* w3r  = (const float*)d_in[11];
    const float* b3   = (const float*)d_in[12];
    const float* p1   = (const float*)d_in[13];
    const float* p2   = (const float*)d_in[14];
    const float* p3   = (const float*)d_in[15];
    const float* lw1  = (const float*)d_in[16];
    const float* lb1  = (const float*)d_in[17];
    const float* lw2  = (const float*)d_in[18];
    const float* lb2  = (const float*)d_in[19];
    const float* lw3  = (const float*)d_in[20];
    const float* lb3  = (const float*)d_in[21];
    float* out = (float*)d_out;

    // Workspace layout (floats). x0/m9 alias the front of D (dead before
    // D's first real use as pool-1 output).
    float* ws  = (float*)d_ws;
    float* C   = ws;                           // N0*HID   (x1 / mean / x2 / x3)
    float* D   = C + (size_t)N0 * HID;         // N1*HID   (x1p / x2p / x3p)
    float* x0  = D;                            // N0*EMB   (stage 1 only)
    float* m9  = D + (size_t)N0 * EMB;         // N0*EMB   (stage 1 only)
    float* g1  = D + (size_t)N1 * HID;         // B*256
    float* g2  = g1 + B * 2 * HID;             // B*256
    float* g3  = g2 + B * 2 * HID;             // B*256
    int* map1  = (int*)(g3 + B * 2 * HID);     // N0
    int* map2  = map1 + N0;                    // N1

    // ---- Stage 1 (EMB -> HID) ----
    k_gather<<<(N0 + 255) / 256, 256, 0, stream>>>(node_ids, emb, x0);
    k_agg9<<<B, 256, 0, stream>>>(x0, ei, ei + E, m9);
    k_conv1<8><<<N0 / 8, 128, 0, stream>>>(m9, x0, w1n, w1r, b1, C);
    k_pool<<<B, 256, 0, stream>>>(C, p1, NPG, K1, D, map1, g1);

    // ---- Stage 2 (HID -> HID), nodes N1 ----
    k_aggcsr<<<dim3(B, 2), 256, 0, stream>>>(D, ei, ei + E, map1, nullptr, K1, C);
    k_convgemm<<<N1 / 128, 256, 0, stream>>>(C, D, w2n, w2r, b2, C);
    k_pool<<<B, 256, 0, stream>>>(C, p2, K1, K2, D, map2, g2);

    // ---- Stage 3 (HID -> HID), nodes N2 ----
    k_aggcsr<<<dim3(B, 2), 256, 0, stream>>>(D, ei, ei + E, map1, map2, K2, C);
    k_convgemm<<<N2 / 128, 256, 0, stream>>>(C, D, w3n, w3r, b3, C);
    k_pool<<<B, 256, 0, stream>>>(C, p3, K2, K3, D, map1 /*scratch*/, g3);

    // ---- Head ----
    k_mlp<<<B, 128, 0, stream>>>(g1, g2, g3, lw1, lb1, lw2, lb2, lw3, lb3, out);
}

// Round 7
// 649.881 us; speedup vs baseline: 1.1211x; 1.1211x over previous
//
#include <hip/hip_runtime.h>
#include <math.h>

// Problem constants (from reference)
constexpr int B    = 512;
constexpr int NPG  = 200;    // nodes per graph, stage 0
constexpr int EPER = 2000;   // edges per graph
constexpr int EMB  = 9;
constexpr int HID  = 128;
constexpr int K1   = 160;    // ceil(0.8*200)
constexpr int K2   = 128;    // ceil(0.8*160)
constexpr int K3   = 103;    // ceil(0.8*128)
constexpr int N0   = B * NPG;   // 102400
constexpr int N1   = B * K1;    // 81920
constexpr int N2   = B * K2;    // 65536
constexpr int N3   = B * K3;    // 52736
constexpr int E    = B * EPER;  // 1024000

// ---------------------------------------------------------------------------
// Embedding gather: x0[n][:] = emb[node_ids[n]][:]
__global__ __launch_bounds__(256) void k_gather(const int* __restrict__ node_ids,
                         const float* __restrict__ emb,
                         float* __restrict__ x0) {
    int n = blockIdx.x * blockDim.x + threadIdx.x;
    if (n < N0) {
        int id = node_ids[n];
        #pragma unroll
        for (int j = 0; j < EMB; j++) x0[n * EMB + j] = emb[id * EMB + j];
    }
}

// ---------------------------------------------------------------------------
// Stage-1 aggregation (width EMB=9), all edges valid. One block per graph,
// accumulate in LDS, write the MEAN directly (conv1 needs no cnt).
__global__ __launch_bounds__(256) void k_agg9(const float* __restrict__ x0,
                       const int* __restrict__ esrc,
                       const int* __restrict__ edst,
                       float* __restrict__ m9) {
    int g = blockIdx.x;
    __shared__ float lacc[NPG * EMB];
    __shared__ float lcnt[NPG];
    for (int i = threadIdx.x; i < NPG * EMB; i += 256) lacc[i] = 0.f;
    for (int i = threadIdx.x; i < NPG; i += 256) lcnt[i] = 0.f;
    __syncthreads();
    const int ebase = g * EPER;
    const int nbase = g * NPG;
    for (int idx = threadIdx.x; idx < EPER * EMB; idx += 256) {
        int el = idx / EMB;
        int j  = idx - el * EMB;
        int e  = ebase + el;
        int src = esrc[e];
        int dl  = edst[e] - nbase;
        atomicAdd(&lacc[dl * EMB + j], x0[src * EMB + j]);
        if (j == 0) atomicAdd(&lcnt[dl], 1.f);
    }
    __syncthreads();
    for (int i = threadIdx.x; i < NPG * EMB; i += 256) {
        int row = i / EMB;
        m9[nbase * EMB + i] = lacc[i] / fmaxf(lcnt[row], 1.f);
    }
}

// ---------------------------------------------------------------------------
// Stage-2/3 aggregation, CSR-based, with FUSED edge remap: takes the raw
// edge list + mapping chain (map1[, map2]) and computes validity inline.
// One block per (graph, feature-half). Emits the MEAN directly.
__global__ __launch_bounds__(256) void k_aggcsr(const float* __restrict__ x,
                         const int* __restrict__ es,
                         const int* __restrict__ ed,
                         const int* __restrict__ map1,
                         const int* __restrict__ map2,   // may be null
                         int npc,
                         float* __restrict__ sout) {
    int g = blockIdx.x;
    int w = blockIdx.y;   // feature half (0/1)
    int tid = threadIdx.x;  // 256
    __shared__ int deg[256];
    __shared__ int scanbuf[256];
    __shared__ int off[257];
    __shared__ int cur[256];
    __shared__ int csr[EPER];

    deg[tid] = 0;
    __syncthreads();
    const int ebase = g * EPER;
    const int nbase = g * npc;
    // pass 1: degrees (remap on the fly)
    for (int e = tid; e < EPER; e += 256) {
        int a = map1[es[ebase + e]];
        int b = map1[ed[ebase + e]];
        if (map2) {
            a = (a >= 0) ? map2[a] : -1;
            b = (b >= 0) ? map2[b] : -1;
        }
        if (a >= 0 && b >= 0) atomicAdd(&deg[b - nbase], 1);
    }
    __syncthreads();
    // Hillis-Steele inclusive scan over 256 entries
    int v = deg[tid];
    scanbuf[tid] = v;
    __syncthreads();
    #pragma unroll
    for (int d = 1; d < 256; d <<= 1) {
        int t = (tid >= d) ? scanbuf[tid - d] : 0;
        __syncthreads();
        scanbuf[tid] += t;
        __syncthreads();
    }
    if (tid == 0) off[0] = 0;
    off[tid + 1] = scanbuf[tid];
    __syncthreads();
    cur[tid] = off[tid];
    __syncthreads();
    // pass 2: scatter src ids into CSR slots
    for (int e = tid; e < EPER; e += 256) {
        int a = map1[es[ebase + e]];
        int b = map1[ed[ebase + e]];
        if (map2) {
            a = (a >= 0) ? map2[a] : -1;
            b = (b >= 0) ? map2[b] : -1;
        }
        if (a >= 0 && b >= 0) {
            int slot = atomicAdd(&cur[b - nbase], 1);
            csr[slot] = a;
        }
    }
    __syncthreads();
    // phase 2: one wave per dst, register accumulation, write mean
    int lane = tid & 63, wv = tid >> 6;
    int hoff = w * 64 + lane;
    for (int dl = wv; dl < npc; dl += 4) {
        int beg = off[dl], end = off[dl + 1];
        float acc = 0.f, acc2 = 0.f;
        int t = beg;
        for (; t + 1 < end; t += 2) {
            acc  += x[(long)csr[t]     * HID + hoff];
            acc2 += x[(long)csr[t + 1] * HID + hoff];
        }
        if (t < end) acc += x[(long)csr[t] * HID + hoff];
        float inv = 1.f / (float)((end - beg) > 1 ? (end - beg) : 1);
        sout[(long)(nbase + dl) * HID + hoff] = (acc + acc2) * inv;
    }
}

// ---------------------------------------------------------------------------
// Conv1: out[n][h] = relu( m9[n] . w1n[h] + x0[n] . w1r[h] + b[h] )
// m9 already holds the neighbor mean.
template <int NB>
__global__ __launch_bounds__(128) void k_conv1(const float* __restrict__ m9,
                        const float* __restrict__ x0,
                        const float* __restrict__ wn,
                        const float* __restrict__ wr,
                        const float* __restrict__ bb,
                        float* __restrict__ out) {
    __shared__ float sm[NB][EMB];
    __shared__ float sx[NB][EMB];
    int nb0 = blockIdx.x * NB;
    int h = threadIdx.x;  // 128
    for (int i = h; i < NB * EMB; i += 128) {
        int sl = i / EMB, j = i - sl * EMB;
        int n = nb0 + sl;
        sm[sl][j] = m9[n * EMB + j];
        sx[sl][j] = x0[n * EMB + j];
    }
    __syncthreads();
    float acc[NB];
    #pragma unroll
    for (int sl = 0; sl < NB; sl++) acc[sl] = bb[h];
    #pragma unroll
    for (int j = 0; j < EMB; j++) {
        float a = wn[h * EMB + j];
        float r = wr[h * EMB + j];
        #pragma unroll
        for (int sl = 0; sl < NB; sl++) acc[sl] += sm[sl][j] * a + sx[sl][j] * r;
    }
    #pragma unroll
    for (int sl = 0; sl < NB; sl++)
        out[(long)(nb0 + sl) * HID + h] = fmaxf(acc[sl], 0.f);
}

// ---------------------------------------------------------------------------
// Conv2/3 as LDS-tiled fp32 GEMM with K=256 (concat [mean_s, x] against
// [wn; wr] rows). ROUND-4 STRUCTURE — do not replace with XOR-swizzled
// row-major tiles: that variant (r5/r6) triggers pathological codegen
// (~900B/thread scratch write-back, WRITE_SIZE 41->192 MB, dur 89->138 us)
// regardless of inner-loop ordering or launch bounds. This k-major
// structure measured WRITE_SIZE == output exactly.
// Block = 128 rows x 128 cols, 256 threads, 8x8 register tile per thread.
// K streamed in 8 chunks of 32, k-major LDS tiles (pitch GP=132).
// In-place safe (out may alias s): block reads only its own 128 rows of s,
// all during staging/prefetch, which completes before the epilogue stores.
constexpr int GP = 132;  // LDS row pitch (floats): 16B-aligned, breaks pow-2
__global__ __launch_bounds__(256, 3) void k_convgemm(
        const float* s,                      // neighbor MEAN; may alias out
        const float* xin,
        const float* __restrict__ wn,
        const float* __restrict__ wr,
        const float* __restrict__ bb,
        float* out) {
    __shared__ float As[32 * GP];
    __shared__ float Bs[32 * GP];
    const int tid = threadIdx.x;
    const long row0 = (long)blockIdx.x * 128;

    const int tc = tid & 15, tr = tid >> 4;
    const int srow = tid >> 3;        // 0..31 (+i*32)
    const int scol = (tid & 7) * 4;   // k-offset within chunk: 0,4,..,28

    float acc[8][8];
    #pragma unroll
    for (int r = 0; r < 8; r++)
        #pragma unroll
        for (int c = 0; c < 8; c++) acc[r][c] = 0.f;

    // prefetch chunk 0
    float4 av[4], bv[4];
    #pragma unroll
    for (int i = 0; i < 4; i++) {
        int r = srow + i * 32;
        av[i] = *(const float4*)(s + (row0 + r) * HID + scol);
        bv[i] = *(const float4*)(wn + (size_t)r * HID + scol);
    }

    for (int ch = 0; ch < 8; ch++) {
        __syncthreads();  // LDS free
        // write staged tile (k-major transpose via scalar writes)
        #pragma unroll
        for (int i = 0; i < 4; i++) {
            int r = srow + i * 32;
            As[(scol + 0) * GP + r] = av[i].x;
            As[(scol + 1) * GP + r] = av[i].y;
            As[(scol + 2) * GP + r] = av[i].z;
            As[(scol + 3) * GP + r] = av[i].w;
            Bs[(scol + 0) * GP + r] = bv[i].x;
            Bs[(scol + 1) * GP + r] = bv[i].y;
            Bs[(scol + 2) * GP + r] = bv[i].z;
            Bs[(scol + 3) * GP + r] = bv[i].w;
        }
        __syncthreads();
        // prefetch next chunk (overlaps compute)
        if (ch + 1 < 8) {
            const float* xsrc = (ch + 1 < 4) ? s : xin;
            const float* wsrc = (ch + 1 < 4) ? wn : wr;
            int kofs = ((ch + 1) & 3) * 32;
            #pragma unroll
            for (int i = 0; i < 4; i++) {
                int r = srow + i * 32;
                av[i] = *(const float4*)(xsrc + (row0 + r) * HID + kofs + scol);
                bv[i] = *(const float4*)(wsrc + (size_t)r * HID + kofs + scol);
            }
        }
        // compute 32 k-steps
        #pragma unroll 2
        for (int k = 0; k < 32; k++) {
            float4 a0 = *(const float4*)&As[k * GP + tr * 8];
            float4 a1 = *(const float4*)&As[k * GP + tr * 8 + 4];
            float4 b0 = *(const float4*)&Bs[k * GP + tc * 4];
            float4 b1 = *(const float4*)&Bs[k * GP + 64 + tc * 4];
            float a[8] = {a0.x, a0.y, a0.z, a0.w, a1.x, a1.y, a1.z, a1.w};
            float bb8[8] = {b0.x, b0.y, b0.z, b0.w, b1.x, b1.y, b1.z, b1.w};
            #pragma unroll
            for (int r = 0; r < 8; r++)
                #pragma unroll
                for (int c = 0; c < 8; c++) acc[r][c] += a[r] * bb8[c];
        }
    }

    // epilogue: bias + relu, coalesced float4 stores
    float4 bias0 = *(const float4*)&bb[tc * 4];
    float4 bias1 = *(const float4*)&bb[64 + tc * 4];
    #pragma unroll
    for (int r = 0; r < 8; r++) {
        long m = row0 + tr * 8 + r;
        float4 o0, o1;
        o0.x = fmaxf(acc[r][0] + bias0.x, 0.f);
        o0.y = fmaxf(acc[r][1] + bias0.y, 0.f);
        o0.z = fmaxf(acc[r][2] + bias0.z, 0.f);
        o0.w = fmaxf(acc[r][3] + bias0.w, 0.f);
        o1.x = fmaxf(acc[r][4] + bias1.x, 0.f);
        o1.y = fmaxf(acc[r][5] + bias1.y, 0.f);
        o1.z = fmaxf(acc[r][6] + bias1.z, 0.f);
        o1.w = fmaxf(acc[r][7] + bias1.w, 0.f);
        *(float4*)(out + m * HID + tc * 4) = o0;
        *(float4*)(out + m * HID + 64 + tc * 4) = o1;
    }
}

// ---------------------------------------------------------------------------
// TopK pool + FUSED global max/mean pool.
// score = tanh(x.p/||p||); jax.lax.top_k semantics (descending, lower index
// wins ties); xout[g*k+rank] = x[node]*score; mapping old->new (or -1);
// gout[g][0:128] = max over kept rows, gout[g][128:256] = mean.
__global__ __launch_bounds__(256) void k_pool(const float* __restrict__ x,
                       const float* __restrict__ p,
                       int npc, int k,
                       float* __restrict__ xout,
                       int* __restrict__ mapping,
                       float* __restrict__ gout) {
    int g = blockIdx.x;
    int tid = threadIdx.x;  // 256
    __shared__ float sc[256];
    __shared__ int   pos[256];
    __shared__ float redm[128];
    __shared__ float reds[128];
    int lane = tid & 63, wv = tid >> 6;
    float pl0 = p[lane], pl1 = p[64 + lane];
    // ||p||^2 via butterfly
    float pp = pl0 * pl0 + pl1 * pl1;
    #pragma unroll
    for (int o = 32; o >= 1; o >>= 1) pp += __shfl_xor(pp, o, 64);
    float nrm = sqrtf(pp);
    // scores: one wave per row, coalesced reads + butterfly reduce
    for (int i = wv; i < npc; i += 4) {
        const float* xr = x + (long)(g * npc + i) * HID;
        float d = xr[lane] * pl0 + xr[64 + lane] * pl1;
        #pragma unroll
        for (int o = 32; o >= 1; o >>= 1) d += __shfl_xor(d, o, 64);
        if (lane == 0) sc[i] = tanhf(d / nrm);
    }
    __syncthreads();
    // rank = position in descending stable order
    if (tid < npc) {
        float scv = sc[tid];
        int rank = 0;
        for (int j = 0; j < npc; j++) {
            float o = sc[j];
            rank += (o > scv) || (o == scv && j < tid);
        }
        bool keep = rank < k;
        pos[tid] = keep ? rank : -1;
        mapping[g * npc + tid] = keep ? (g * k + rank) : -1;
    }
    __syncthreads();
    // gather + scale into new ordering; accumulate global max/sum per column
    int h = tid & 127, half = tid >> 7;
    float pmax = -INFINITY, psum = 0.f;
    for (int i = half; i < npc; i += 2) {
        int r = pos[i];
        if (r >= 0) {
            float v = x[(long)(g * npc + i) * HID + h] * sc[i];
            xout[(long)(g * k + r) * HID + h] = v;
            pmax = fmaxf(pmax, v);
            psum += v;
        }
    }
    if (half) { redm[h] = pmax; reds[h] = psum; }
    __syncthreads();
    if (!half) {
        pmax = fmaxf(pmax, redm[h]);
        psum += reds[h];
        gout[g * 256 + h] = pmax;
        gout[g * 256 + 128 + h] = psum / (float)k;
    }
}

// ---------------------------------------------------------------------------
// MLP head: h=g1+g2+g3; relu(h@lw1.T+lb1); relu(@lw2.T+lb2); sigmoid(@lw3.T+lb3)
__global__ __launch_bounds__(128) void k_mlp(const float* __restrict__ g1, const float* __restrict__ g2,
                      const float* __restrict__ g3,
                      const float* __restrict__ lw1, const float* __restrict__ lb1,
                      const float* __restrict__ lw2, const float* __restrict__ lb2,
                      const float* __restrict__ lw3, const float* __restrict__ lb3,
                      float* __restrict__ out) {
    int g = blockIdx.x, t = threadIdx.x;  // 128 threads
    __shared__ float h0[256];
    __shared__ float h1[128];
    __shared__ float h2r[64];
    h0[t]       = g1[g * 256 + t] + g2[g * 256 + t] + g3[g * 256 + t];
    h0[t + 128] = g1[g * 256 + 128 + t] + g2[g * 256 + 128 + t] + g3[g * 256 + 128 + t];
    __syncthreads();
    float a = lb1[t];
    #pragma unroll 4
    for (int j = 0; j < 256; j++) a += h0[j] * lw1[t * 256 + j];
    h1[t] = fmaxf(a, 0.f);
    __syncthreads();
    if (t < 64) {
        float a2 = lb2[t];
        #pragma unroll 4
        for (int j = 0; j < 128; j++) a2 += h1[j] * lw2[t * 128 + j];
        h2r[t] = fmaxf(a2, 0.f) * lw3[t];
    }
    __syncthreads();
    if (t == 0) {
        float s = 0.f;
        for (int j = 0; j < 64; j++) s += h2r[j];
        s += lb3[0];
        out[g] = 1.f / (1.f + expf(-s));
    }
}

// ---------------------------------------------------------------------------
extern "C" void kernel_launch(void* const* d_in, const int* in_sizes, int n_in,
                              void* d_out, int out_size, void* d_ws, size_t ws_size,
                              hipStream_t stream) {
    const int*   node_ids = (const int*)d_in[0];
    const int*   ei   = (const int*)d_in[1];   // edge_index (2, E)
    const float* emb  = (const float*)d_in[3];
    const float* w1n  = (const float*)d_in[4];
    const float* w1r  = (const float*)d_in[5];
    const float* b1   = (const float*)d_in[6];
    const float* w2n  = (const float*)d_in[7];
    const float* w2r  = (const float*)d_in[8];
    const float* b2   = (const float*)d_in[9];
    const float* w3n  = (const float*)d_in[10];
    const float* w3r  = (const float*)d_in[11];
    const float* b3   = (const float*)d_in[12];
    const float* p1   = (const float*)d_in[13];
    const float* p2   = (const float*)d_in[14];
    const float* p3   = (const float*)d_in[15];
    const float* lw1  = (const float*)d_in[16];
    const float* lb1  = (const float*)d_in[17];
    const float* lw2  = (const float*)d_in[18];
    const float* lb2  = (const float*)d_in[19];
    const float* lw3  = (const float*)d_in[20];
    const float* lb3  = (const float*)d_in[21];
    float* out = (float*)d_out;

    // Workspace layout (floats). x0/m9 alias the front of D (dead before
    // D's first real use as pool-1 output).
    float* ws  = (float*)d_ws;
    float* C   = ws;                           // N0*HID   (x1 / mean / x2 / x3)
    float* D   = C + (size_t)N0 * HID;         // N1*HID   (x1p / x2p / x3p)
    float* x0  = D;                            // N0*EMB   (stage 1 only)
    float* m9  = D + (size_t)N0 * EMB;         // N0*EMB   (stage 1 only)
    float* g1  = D + (size_t)N1 * HID;         // B*256
    float* g2  = g1 + B * 2 * HID;             // B*256
    float* g3  = g2 + B * 2 * HID;             // B*256
    int* map1  = (int*)(g3 + B * 2 * HID);     // N0
    int* map2  = map1 + N0;                    // N1

    // ---- Stage 1 (EMB -> HID) ----
    k_gather<<<(N0 + 255) / 256, 256, 0, stream>>>(node_ids, emb, x0);
    k_agg9<<<B, 256, 0, stream>>>(x0, ei, ei + E, m9);
    k_conv1<8><<<N0 / 8, 128, 0, stream>>>(m9, x0, w1n, w1r, b1, C);
    k_pool<<<B, 256, 0, stream>>>(C, p1, NPG, K1, D, map1, g1);

    // ---- Stage 2 (HID -> HID), nodes N1 ----
    k_aggcsr<<<dim3(B, 2), 256, 0, stream>>>(D, ei, ei + E, map1, nullptr, K1, C);
    k_convgemm<<<N1 / 128, 256, 0, stream>>>(C, D, w2n, w2r, b2, C);
    k_pool<<<B, 256, 0, stream>>>(C, p2, K1, K2, D, map2, g2);

    // ---- Stage 3 (HID -> HID), nodes N2 ----
    k_aggcsr<<<dim3(B, 2), 256, 0, stream>>>(D, ei, ei + E, map1, map2, K2, C);
    k_convgemm<<<N2 / 128, 256, 0, stream>>>(C, D, w3n, w3r, b3, C);
    k_pool<<<B, 256, 0, stream>>>(C, p3, K2, K3, D, map1 /*scratch*/, g3);

    // ---- Head ----
    k_mlp<<<B, 128, 0, stream>>>(g1, g2, g3, lw1, lb1, lw2, lb2, lw3, lb3, out);
}

// Round 8
// 576.285 us; speedup vs baseline: 1.2643x; 1.1277x over previous
//
#include <hip/hip_runtime.h>
#include <math.h>

// Problem constants (from reference)
constexpr int B    = 512;
constexpr int NPG  = 200;    // nodes per graph, stage 0
constexpr int EPER = 2000;   // edges per graph
constexpr int EMB  = 9;
constexpr int HID  = 128;
constexpr int K1   = 160;    // ceil(0.8*200)
constexpr int K2   = 128;    // ceil(0.8*160)
constexpr int K3   = 103;    // ceil(0.8*128)
constexpr int N0   = B * NPG;   // 102400
constexpr int N1   = B * K1;    // 81920
constexpr int N2   = B * K2;    // 65536
constexpr int N3   = B * K3;    // 52736
constexpr int E    = B * EPER;  // 1024000

// ---------------------------------------------------------------------------
// Fused stage 1 (one block per graph, 256 threads):
//   gather emb -> x0 (LDS) -> CSR build (LDS) -> neighbor mean (registers,
//   no atomics: thread-per-dst) -> conv1 (per-lane weight rows in regs,
//   LDS broadcast reads) + fused tanh-score -> top-K1 rank -> pooled gather
//   (scale by score) + global max/mean pool.
// x0/m9 never touch global memory; the pool score phase re-read of x1 is
// replaced by a butterfly dot folded into the conv epilogue.
__global__ __launch_bounds__(256) void k_stage1(
        const int* __restrict__ node_ids,
        const float* __restrict__ emb,
        const int* __restrict__ es, const int* __restrict__ ed,
        const float* __restrict__ w1n, const float* __restrict__ w1r,
        const float* __restrict__ b1, const float* __restrict__ p1,
        float* __restrict__ x1,      // conv1 output (N0 x HID)
        float* __restrict__ xout,    // pooled output (N1 x HID)
        int* __restrict__ mapping,   // old node id -> new (or -1), N0
        float* __restrict__ gout) {  // B x 256 global-pool
    const int g = blockIdx.x, tid = threadIdx.x;
    __shared__ float x0L[NPG * EMB];    // 7.2 KB
    __shared__ float mnL[NPG * EMB];    // 7.2 KB
    __shared__ int   idsL[NPG];
    __shared__ int   deg[256];
    __shared__ int   off2[257];
    __shared__ int   cur[256];          // doubles as scan buffer
    __shared__ int   csr[EPER];         // 8 KB
    __shared__ float sc[NPG];
    __shared__ int   pos[NPG];
    __shared__ float redm[128], reds[128];

    // --- gather node ids, init degrees ---
    if (tid < NPG) idsL[tid] = node_ids[g * NPG + tid];
    deg[tid] = 0;
    __syncthreads();
    // --- gather embeddings into LDS ---
    for (int i = tid; i < NPG * EMB; i += 256) {
        int n = i / EMB, j = i - n * EMB;
        x0L[i] = emb[(size_t)idsL[n] * EMB + j];
    }
    // --- degrees (all edges valid in stage 1) ---
    const int ebase = g * EPER, nbase = g * NPG;
    int lsrc[8], ldst[8];
    #pragma unroll
    for (int q = 0; q < 8; q++) {
        int e = tid + q * 256;
        lsrc[q] = es[ebase + e] - nbase;
        ldst[q] = ed[ebase + e] - nbase;
        atomicAdd(&deg[ldst[q]], 1);
    }
    __syncthreads();
    // --- Hillis-Steele inclusive scan over 256 ---
    cur[tid] = deg[tid];
    __syncthreads();
    #pragma unroll
    for (int d = 1; d < 256; d <<= 1) {
        int t = (tid >= d) ? cur[tid - d] : 0;
        __syncthreads();
        cur[tid] += t;
        __syncthreads();
    }
    if (tid == 0) off2[0] = 0;
    off2[tid + 1] = cur[tid];
    __syncthreads();
    cur[tid] = off2[tid];
    __syncthreads();
    // --- scatter local src ids ---
    #pragma unroll
    for (int q = 0; q < 8; q++) {
        int slot = atomicAdd(&cur[ldst[q]], 1);
        csr[slot] = lsrc[q];
    }
    __syncthreads();
    // --- neighbor mean: thread-per-dst, register accumulation ---
    if (tid < NPG) {
        int bg = off2[tid], en = off2[tid + 1];
        float a[EMB];
        #pragma unroll
        for (int j = 0; j < EMB; j++) a[j] = 0.f;
        for (int t = bg; t < en; t++) {
            int s = csr[t];
            #pragma unroll
            for (int j = 0; j < EMB; j++) a[j] += x0L[s * EMB + j];
        }
        float inv = 1.f / (float)((en - bg) > 1 ? (en - bg) : 1);
        #pragma unroll
        for (int j = 0; j < EMB; j++) mnL[tid * EMB + j] = a[j] * inv;
    }
    // --- preload per-lane weights (rows lane, lane+64) while mean runs ---
    const int lane = tid & 63, wv = tid >> 6;
    float pl0 = p1[lane], pl1 = p1[64 + lane];
    float pp = pl0 * pl0 + pl1 * pl1;
    #pragma unroll
    for (int o = 32; o >= 1; o >>= 1) pp += __shfl_xor(pp, o, 64);
    float nrm = sqrtf(pp);
    float wn0[EMB], wn1[EMB], wr0[EMB], wr1[EMB];
    #pragma unroll
    for (int j = 0; j < EMB; j++) {
        wn0[j] = w1n[lane * EMB + j];
        wn1[j] = w1n[(lane + 64) * EMB + j];
        wr0[j] = w1r[lane * EMB + j];
        wr1[j] = w1r[(lane + 64) * EMB + j];
    }
    float bb0 = b1[lane], bb1 = b1[64 + lane];
    __syncthreads();
    // --- conv1 + fused score: one wave per node ---
    for (int i = wv; i < NPG; i += 4) {
        float c0 = bb0, c1 = bb1;
        #pragma unroll
        for (int j = 0; j < EMB; j++) {
            float m = mnL[i * EMB + j];   // wave-uniform -> broadcast
            float x = x0L[i * EMB + j];
            c0 += m * wn0[j] + x * wr0[j];
            c1 += m * wn1[j] + x * wr1[j];
        }
        c0 = fmaxf(c0, 0.f);
        c1 = fmaxf(c1, 0.f);
        long rowp = (long)(g * NPG + i) * HID;
        x1[rowp + lane] = c0;
        x1[rowp + 64 + lane] = c1;
        float d = c0 * pl0 + c1 * pl1;
        #pragma unroll
        for (int o = 32; o >= 1; o >>= 1) d += __shfl_xor(d, o, 64);
        if (lane == 0) sc[i] = tanhf(d / nrm);
    }
    __syncthreads();
    // --- rank (jax.lax.top_k: descending, lower index wins ties) ---
    if (tid < NPG) {
        float scv = sc[tid];
        int rank = 0;
        for (int j = 0; j < NPG; j++) {
            float o = sc[j];
            rank += (o > scv) || (o == scv && j < tid);
        }
        bool keep = rank < K1;
        pos[tid] = keep ? rank : -1;
        mapping[g * NPG + tid] = keep ? (g * K1 + rank) : -1;
    }
    __syncthreads();
    // --- pooled gather + global max/mean (rows re-read from L2-hot x1) ---
    int h = tid & 127, half = tid >> 7;
    float pmax = -INFINITY, psum = 0.f;
    for (int i = half; i < NPG; i += 2) {
        int r = pos[i];
        if (r >= 0) {
            float v = x1[(long)(g * NPG + i) * HID + h] * sc[i];
            xout[(long)(g * K1 + r) * HID + h] = v;
            pmax = fmaxf(pmax, v);
            psum += v;
        }
    }
    if (half) { redm[h] = pmax; reds[h] = psum; }
    __syncthreads();
    if (!half) {
        pmax = fmaxf(pmax, redm[h]);
        psum += reds[h];
        gout[g * 256 + h] = pmax;
        gout[g * 256 + 128 + h] = psum / (float)K1;
    }
}

// ---------------------------------------------------------------------------
// Stage-2/3 aggregation, CSR-based, with FUSED edge remap: takes the raw
// edge list + mapping chain (map1[, map2]) and computes validity inline.
// One block per (graph, feature-half). Emits the MEAN directly.
__global__ __launch_bounds__(256) void k_aggcsr(const float* __restrict__ x,
                         const int* __restrict__ es,
                         const int* __restrict__ ed,
                         const int* __restrict__ map1,
                         const int* __restrict__ map2,   // may be null
                         int npc,
                         float* __restrict__ sout) {
    int g = blockIdx.x;
    int w = blockIdx.y;   // feature half (0/1)
    int tid = threadIdx.x;  // 256
    __shared__ int deg[256];
    __shared__ int scanbuf[256];
    __shared__ int off[257];
    __shared__ int cur[256];
    __shared__ int csr[EPER];

    deg[tid] = 0;
    __syncthreads();
    const int ebase = g * EPER;
    const int nbase = g * npc;
    // pass 1: degrees (remap on the fly)
    for (int e = tid; e < EPER; e += 256) {
        int a = map1[es[ebase + e]];
        int b = map1[ed[ebase + e]];
        if (map2) {
            a = (a >= 0) ? map2[a] : -1;
            b = (b >= 0) ? map2[b] : -1;
        }
        if (a >= 0 && b >= 0) atomicAdd(&deg[b - nbase], 1);
    }
    __syncthreads();
    // Hillis-Steele inclusive scan over 256 entries
    int v = deg[tid];
    scanbuf[tid] = v;
    __syncthreads();
    #pragma unroll
    for (int d = 1; d < 256; d <<= 1) {
        int t = (tid >= d) ? scanbuf[tid - d] : 0;
        __syncthreads();
        scanbuf[tid] += t;
        __syncthreads();
    }
    if (tid == 0) off[0] = 0;
    off[tid + 1] = scanbuf[tid];
    __syncthreads();
    cur[tid] = off[tid];
    __syncthreads();
    // pass 2: scatter src ids into CSR slots
    for (int e = tid; e < EPER; e += 256) {
        int a = map1[es[ebase + e]];
        int b = map1[ed[ebase + e]];
        if (map2) {
            a = (a >= 0) ? map2[a] : -1;
            b = (b >= 0) ? map2[b] : -1;
        }
        if (a >= 0 && b >= 0) {
            int slot = atomicAdd(&cur[b - nbase], 1);
            csr[slot] = a;
        }
    }
    __syncthreads();
    // phase 2: one wave per dst, register accumulation, write mean
    int lane = tid & 63, wv = tid >> 6;
    int hoff = w * 64 + lane;
    for (int dl = wv; dl < npc; dl += 4) {
        int beg = off[dl], end = off[dl + 1];
        float acc = 0.f, acc2 = 0.f;
        int t = beg;
        for (; t + 1 < end; t += 2) {
            acc  += x[(long)csr[t]     * HID + hoff];
            acc2 += x[(long)csr[t + 1] * HID + hoff];
        }
        if (t < end) acc += x[(long)csr[t] * HID + hoff];
        float inv = 1.f / (float)((end - beg) > 1 ? (end - beg) : 1);
        sout[(long)(nbase + dl) * HID + hoff] = (acc + acc2) * inv;
    }
}

// ---------------------------------------------------------------------------
// Conv2/3 as LDS-tiled fp32 GEMM with K=256 (concat [mean_s, x] against
// [wn; wr] rows). ROUND-4 STRUCTURE — do not replace with XOR-swizzled
// row-major tiles: that variant (r5/r6) triggers pathological codegen
// (~900B/thread scratch write-back, WRITE_SIZE 41->192 MB, dur 89->138 us)
// regardless of inner-loop ordering or launch bounds. This k-major
// structure measured WRITE_SIZE == output exactly.
// Block = 128 rows x 128 cols, 256 threads, 8x8 register tile per thread.
// K streamed in 8 chunks of 32, k-major LDS tiles (pitch GP=132).
// In-place safe (out may alias s): block reads only its own 128 rows of s,
// all during staging/prefetch, which completes before the epilogue stores.
constexpr int GP = 132;  // LDS row pitch (floats): 16B-aligned, breaks pow-2
__global__ __launch_bounds__(256, 3) void k_convgemm(
        const float* s,                      // neighbor MEAN; may alias out
        const float* xin,
        const float* __restrict__ wn,
        const float* __restrict__ wr,
        const float* __restrict__ bb,
        float* out) {
    __shared__ float As[32 * GP];
    __shared__ float Bs[32 * GP];
    const int tid = threadIdx.x;
    const long row0 = (long)blockIdx.x * 128;

    const int tc = tid & 15, tr = tid >> 4;
    const int srow = tid >> 3;        // 0..31 (+i*32)
    const int scol = (tid & 7) * 4;   // k-offset within chunk: 0,4,..,28

    float acc[8][8];
    #pragma unroll
    for (int r = 0; r < 8; r++)
        #pragma unroll
        for (int c = 0; c < 8; c++) acc[r][c] = 0.f;

    // prefetch chunk 0
    float4 av[4], bv[4];
    #pragma unroll
    for (int i = 0; i < 4; i++) {
        int r = srow + i * 32;
        av[i] = *(const float4*)(s + (row0 + r) * HID + scol);
        bv[i] = *(const float4*)(wn + (size_t)r * HID + scol);
    }

    for (int ch = 0; ch < 8; ch++) {
        __syncthreads();  // LDS free
        // write staged tile (k-major transpose via scalar writes)
        #pragma unroll
        for (int i = 0; i < 4; i++) {
            int r = srow + i * 32;
            As[(scol + 0) * GP + r] = av[i].x;
            As[(scol + 1) * GP + r] = av[i].y;
            As[(scol + 2) * GP + r] = av[i].z;
            As[(scol + 3) * GP + r] = av[i].w;
            Bs[(scol + 0) * GP + r] = bv[i].x;
            Bs[(scol + 1) * GP + r] = bv[i].y;
            Bs[(scol + 2) * GP + r] = bv[i].z;
            Bs[(scol + 3) * GP + r] = bv[i].w;
        }
        __syncthreads();
        // prefetch next chunk (overlaps compute)
        if (ch + 1 < 8) {
            const float* xsrc = (ch + 1 < 4) ? s : xin;
            const float* wsrc = (ch + 1 < 4) ? wn : wr;
            int kofs = ((ch + 1) & 3) * 32;
            #pragma unroll
            for (int i = 0; i < 4; i++) {
                int r = srow + i * 32;
                av[i] = *(const float4*)(xsrc + (row0 + r) * HID + kofs + scol);
                bv[i] = *(const float4*)(wsrc + (size_t)r * HID + kofs + scol);
            }
        }
        // compute 32 k-steps
        #pragma unroll 2
        for (int k = 0; k < 32; k++) {
            float4 a0 = *(const float4*)&As[k * GP + tr * 8];
            float4 a1 = *(const float4*)&As[k * GP + tr * 8 + 4];
            float4 b0 = *(const float4*)&Bs[k * GP + tc * 4];
            float4 b1 = *(const float4*)&Bs[k * GP + 64 + tc * 4];
            float a[8] = {a0.x, a0.y, a0.z, a0.w, a1.x, a1.y, a1.z, a1.w};
            float bb8[8] = {b0.x, b0.y, b0.z, b0.w, b1.x, b1.y, b1.z, b1.w};
            #pragma unroll
            for (int r = 0; r < 8; r++)
                #pragma unroll
                for (int c = 0; c < 8; c++) acc[r][c] += a[r] * bb8[c];
        }
    }

    // epilogue: bias + relu, coalesced float4 stores
    float4 bias0 = *(const float4*)&bb[tc * 4];
    float4 bias1 = *(const float4*)&bb[64 + tc * 4];
    #pragma unroll
    for (int r = 0; r < 8; r++) {
        long m = row0 + tr * 8 + r;
        float4 o0, o1;
        o0.x = fmaxf(acc[r][0] + bias0.x, 0.f);
        o0.y = fmaxf(acc[r][1] + bias0.y, 0.f);
        o0.z = fmaxf(acc[r][2] + bias0.z, 0.f);
        o0.w = fmaxf(acc[r][3] + bias0.w, 0.f);
        o1.x = fmaxf(acc[r][4] + bias1.x, 0.f);
        o1.y = fmaxf(acc[r][5] + bias1.y, 0.f);
        o1.z = fmaxf(acc[r][6] + bias1.z, 0.f);
        o1.w = fmaxf(acc[r][7] + bias1.w, 0.f);
        *(float4*)(out + m * HID + tc * 4) = o0;
        *(float4*)(out + m * HID + 64 + tc * 4) = o1;
    }
}

// ---------------------------------------------------------------------------
// TopK pool + FUSED global max/mean pool (stages 2/3).
// score = tanh(x.p/||p||); jax.lax.top_k semantics (descending, lower index
// wins ties); xout[g*k+rank] = x[node]*score; mapping old->new (or -1);
// gout[g][0:128] = max over kept rows, gout[g][128:256] = mean.
__global__ __launch_bounds__(256) void k_pool(const float* __restrict__ x,
                       const float* __restrict__ p,
                       int npc, int k,
                       float* __restrict__ xout,
                       int* __restrict__ mapping,
                       float* __restrict__ gout) {
    int g = blockIdx.x;
    int tid = threadIdx.x;  // 256
    __shared__ float sc[256];
    __shared__ int   pos[256];
    __shared__ float redm[128];
    __shared__ float reds[128];
    int lane = tid & 63, wv = tid >> 6;
    float pl0 = p[lane], pl1 = p[64 + lane];
    // ||p||^2 via butterfly
    float pp = pl0 * pl0 + pl1 * pl1;
    #pragma unroll
    for (int o = 32; o >= 1; o >>= 1) pp += __shfl_xor(pp, o, 64);
    float nrm = sqrtf(pp);
    // scores: one wave per row, coalesced reads + butterfly reduce
    for (int i = wv; i < npc; i += 4) {
        const float* xr = x + (long)(g * npc + i) * HID;
        float d = xr[lane] * pl0 + xr[64 + lane] * pl1;
        #pragma unroll
        for (int o = 32; o >= 1; o >>= 1) d += __shfl_xor(d, o, 64);
        if (lane == 0) sc[i] = tanhf(d / nrm);
    }
    __syncthreads();
    // rank = position in descending stable order
    if (tid < npc) {
        float scv = sc[tid];
        int rank = 0;
        for (int j = 0; j < npc; j++) {
            float o = sc[j];
            rank += (o > scv) || (o == scv && j < tid);
        }
        bool keep = rank < k;
        pos[tid] = keep ? rank : -1;
        mapping[g * npc + tid] = keep ? (g * k + rank) : -1;
    }
    __syncthreads();
    // gather + scale into new ordering; accumulate global max/sum per column
    int h = tid & 127, half = tid >> 7;
    float pmax = -INFINITY, psum = 0.f;
    for (int i = half; i < npc; i += 2) {
        int r = pos[i];
        if (r >= 0) {
            float v = x[(long)(g * npc + i) * HID + h] * sc[i];
            xout[(long)(g * k + r) * HID + h] = v;
            pmax = fmaxf(pmax, v);
            psum += v;
        }
    }
    if (half) { redm[h] = pmax; reds[h] = psum; }
    __syncthreads();
    if (!half) {
        pmax = fmaxf(pmax, redm[h]);
        psum += reds[h];
        gout[g * 256 + h] = pmax;
        gout[g * 256 + 128 + h] = psum / (float)k;
    }
}

// ---------------------------------------------------------------------------
// MLP head: h=g1+g2+g3; relu(h@lw1.T+lb1); relu(@lw2.T+lb2); sigmoid(@lw3.T+lb3)
__global__ __launch_bounds__(128) void k_mlp(const float* __restrict__ g1, const float* __restrict__ g2,
                      const float* __restrict__ g3,
                      const float* __restrict__ lw1, const float* __restrict__ lb1,
                      const float* __restrict__ lw2, const float* __restrict__ lb2,
                      const float* __restrict__ lw3, const float* __restrict__ lb3,
                      float* __restrict__ out) {
    int g = blockIdx.x, t = threadIdx.x;  // 128 threads
    __shared__ float h0[256];
    __shared__ float h1[128];
    __shared__ float h2r[64];
    h0[t]       = g1[g * 256 + t] + g2[g * 256 + t] + g3[g * 256 + t];
    h0[t + 128] = g1[g * 256 + 128 + t] + g2[g * 256 + 128 + t] + g3[g * 256 + 128 + t];
    __syncthreads();
    float a = lb1[t];
    #pragma unroll 4
    for (int j = 0; j < 256; j++) a += h0[j] * lw1[t * 256 + j];
    h1[t] = fmaxf(a, 0.f);
    __syncthreads();
    if (t < 64) {
        float a2 = lb2[t];
        #pragma unroll 4
        for (int j = 0; j < 128; j++) a2 += h1[j] * lw2[t * 128 + j];
        h2r[t] = fmaxf(a2, 0.f) * lw3[t];
    }
    __syncthreads();
    if (t == 0) {
        float s = 0.f;
        for (int j = 0; j < 64; j++) s += h2r[j];
        s += lb3[0];
        out[g] = 1.f / (1.f + expf(-s));
    }
}

// ---------------------------------------------------------------------------
extern "C" void kernel_launch(void* const* d_in, const int* in_sizes, int n_in,
                              void* d_out, int out_size, void* d_ws, size_t ws_size,
                              hipStream_t stream) {
    const int*   node_ids = (const int*)d_in[0];
    const int*   ei   = (const int*)d_in[1];   // edge_index (2, E)
    const float* emb  = (const float*)d_in[3];
    const float* w1n  = (const float*)d_in[4];
    const float* w1r  = (const float*)d_in[5];
    const float* b1   = (const float*)d_in[6];
    const float* w2n  = (const float*)d_in[7];
    const float* w2r  = (const float*)d_in[8];
    const float* b2   = (const float*)d_in[9];
    const float* w3n  = (const float*)d_in[10];
    const float* w3r  = (const float*)d_in[11];
    const float* b3   = (const float*)d_in[12];
    const float* p1   = (const float*)d_in[13];
    const float* p2   = (const float*)d_in[14];
    const float* p3   = (const float*)d_in[15];
    const float* lw1  = (const float*)d_in[16];
    const float* lb1  = (const float*)d_in[17];
    const float* lw2  = (const float*)d_in[18];
    const float* lb2  = (const float*)d_in[19];
    const float* lw3  = (const float*)d_in[20];
    const float* lb3  = (const float*)d_in[21];
    float* out = (float*)d_out;

    // Workspace layout (floats).
    float* ws  = (float*)d_ws;
    float* C   = ws;                           // N0*HID   (x1 / mean / x2 / x3)
    float* D   = C + (size_t)N0 * HID;         // N1*HID   (x1p / x2p / x3p)
    float* g1  = D + (size_t)N1 * HID;         // B*256
    float* g2  = g1 + B * 2 * HID;             // B*256
    float* g3  = g2 + B * 2 * HID;             // B*256
    int* map1  = (int*)(g3 + B * 2 * HID);     // N0
    int* map2  = map1 + N0;                    // N1

    // ---- Stage 1 (EMB -> HID), fully fused per graph ----
    k_stage1<<<B, 256, 0, stream>>>(node_ids, emb, ei, ei + E,
                                    w1n, w1r, b1, p1, C, D, map1, g1);

    // ---- Stage 2 (HID -> HID), nodes N1 ----
    k_aggcsr<<<dim3(B, 2), 256, 0, stream>>>(D, ei, ei + E, map1, nullptr, K1, C);
    k_convgemm<<<N1 / 128, 256, 0, stream>>>(C, D, w2n, w2r, b2, C);
    k_pool<<<B, 256, 0, stream>>>(C, p2, K1, K2, D, map2, g2);

    // ---- Stage 3 (HID -> HID), nodes N2 ----
    k_aggcsr<<<dim3(B, 2), 256, 0, stream>>>(D, ei, ei + E, map1, map2, K2, C);
    k_convgemm<<<N2 / 128, 256, 0, stream>>>(C, D, w3n, w3r, b3, C);
    k_pool<<<B, 256, 0, stream>>>(C, p3, K2, K3, D, map1 /*scratch*/, g3);

    // ---- Head ----
    k_mlp<<<B, 128, 0, stream>>>(g1, g2, g3, lw1, lb1, lw2, lb2, lw3, lb3, out);
}

// Round 9
// 537.418 us; speedup vs baseline: 1.3557x; 1.0723x over previous
//
#include <hip/hip_runtime.h>
#include <math.h>

// Problem constants (from reference)
constexpr int B    = 512;
constexpr int NPG  = 200;    // nodes per graph, stage 0
constexpr int EPER = 2000;   // edges per graph
constexpr int EMB  = 9;
constexpr int HID  = 128;
constexpr int K1   = 160;    // ceil(0.8*200)
constexpr int K2   = 128;    // ceil(0.8*160)
constexpr int K3   = 103;    // ceil(0.8*128)
constexpr int N0   = B * NPG;   // 102400
constexpr int N1   = B * K1;    // 81920
constexpr int N2   = B * K2;    // 65536
constexpr int N3   = B * K3;    // 52736
constexpr int E    = B * EPER;  // 1024000

// ---------------------------------------------------------------------------
// Fused stage 1 (one block per graph, 256 threads):
//   gather emb -> x0 (LDS) -> CSR build (LDS) -> neighbor mean (registers,
//   thread-per-dst, no atomics) -> conv1 pass 1 (scores only) -> top-K1 rank
//   -> conv1 RECOMPUTE for kept nodes -> pooled write + global max/mean.
// The full x1 matrix never touches global memory (r8: writing+re-reading it
// cost 52MB write + re-read; conv1 is 18 FMA/elem — recompute is ~free).
__global__ __launch_bounds__(256) void k_stage1(
        const int* __restrict__ node_ids,
        const float* __restrict__ emb,
        const int* __restrict__ es, const int* __restrict__ ed,
        const float* __restrict__ w1n, const float* __restrict__ w1r,
        const float* __restrict__ b1, const float* __restrict__ p1,
        float* __restrict__ xout,    // pooled output (N1 x HID)
        int* __restrict__ mapping,   // old node id -> new (or -1), N0
        float* __restrict__ gout) {  // B x 256 global-pool
    const int g = blockIdx.x, tid = threadIdx.x;
    __shared__ float x0L[NPG * EMB];    // 7.2 KB
    __shared__ float mnL[NPG * EMB];    // 7.2 KB
    __shared__ int   idsL[NPG];
    __shared__ int   deg[256];
    __shared__ int   off2[257];
    __shared__ int   cur[256];          // doubles as scan buffer
    __shared__ int   csr[EPER];         // 8 KB
    __shared__ float sc[NPG];
    __shared__ int   pos[NPG];
    __shared__ float redM[4 * 128], redS[4 * 128];

    // --- gather node ids, init degrees ---
    if (tid < NPG) idsL[tid] = node_ids[g * NPG + tid];
    deg[tid] = 0;
    __syncthreads();
    // --- gather embeddings into LDS ---
    for (int i = tid; i < NPG * EMB; i += 256) {
        int n = i / EMB, j = i - n * EMB;
        x0L[i] = emb[(size_t)idsL[n] * EMB + j];
    }
    // --- degrees (all edges valid in stage 1) ---
    const int ebase = g * EPER, nbase = g * NPG;
    int lsrc[8], ldst[8];
    #pragma unroll
    for (int q = 0; q < 8; q++) {
        int e = tid + q * 256;
        lsrc[q] = es[ebase + e] - nbase;
        ldst[q] = ed[ebase + e] - nbase;
        atomicAdd(&deg[ldst[q]], 1);
    }
    __syncthreads();
    // --- Hillis-Steele inclusive scan over 256 ---
    cur[tid] = deg[tid];
    __syncthreads();
    #pragma unroll
    for (int d = 1; d < 256; d <<= 1) {
        int t = (tid >= d) ? cur[tid - d] : 0;
        __syncthreads();
        cur[tid] += t;
        __syncthreads();
    }
    if (tid == 0) off2[0] = 0;
    off2[tid + 1] = cur[tid];
    __syncthreads();
    cur[tid] = off2[tid];
    __syncthreads();
    // --- scatter local src ids ---
    #pragma unroll
    for (int q = 0; q < 8; q++) {
        int slot = atomicAdd(&cur[ldst[q]], 1);
        csr[slot] = lsrc[q];
    }
    __syncthreads();
    // --- neighbor mean: thread-per-dst, register accumulation ---
    if (tid < NPG) {
        int bg = off2[tid], en = off2[tid + 1];
        float a[EMB];
        #pragma unroll
        for (int j = 0; j < EMB; j++) a[j] = 0.f;
        for (int t = bg; t < en; t++) {
            int s = csr[t];
            #pragma unroll
            for (int j = 0; j < EMB; j++) a[j] += x0L[s * EMB + j];
        }
        float inv = 1.f / (float)((en - bg) > 1 ? (en - bg) : 1);
        #pragma unroll
        for (int j = 0; j < EMB; j++) mnL[tid * EMB + j] = a[j] * inv;
    }
    // --- preload per-lane weights (rows lane, lane+64) ---
    const int lane = tid & 63, wv = tid >> 6;
    float pl0 = p1[lane], pl1 = p1[64 + lane];
    float pp = pl0 * pl0 + pl1 * pl1;
    #pragma unroll
    for (int o = 32; o >= 1; o >>= 1) pp += __shfl_xor(pp, o, 64);
    float nrm = sqrtf(pp);
    float wn0[EMB], wn1[EMB], wr0[EMB], wr1[EMB];
    #pragma unroll
    for (int j = 0; j < EMB; j++) {
        wn0[j] = w1n[lane * EMB + j];
        wn1[j] = w1n[(lane + 64) * EMB + j];
        wr0[j] = w1r[lane * EMB + j];
        wr1[j] = w1r[(lane + 64) * EMB + j];
    }
    float bb0 = b1[lane], bb1 = b1[64 + lane];
    __syncthreads();
    // --- conv1 pass 1: scores only (one wave per node) ---
    for (int i = wv; i < NPG; i += 4) {
        float c0 = bb0, c1 = bb1;
        #pragma unroll
        for (int j = 0; j < EMB; j++) {
            float m = mnL[i * EMB + j];   // wave-uniform -> broadcast
            float x = x0L[i * EMB + j];
            c0 += m * wn0[j] + x * wr0[j];
            c1 += m * wn1[j] + x * wr1[j];
        }
        c0 = fmaxf(c0, 0.f);
        c1 = fmaxf(c1, 0.f);
        float d = c0 * pl0 + c1 * pl1;
        #pragma unroll
        for (int o = 32; o >= 1; o >>= 1) d += __shfl_xor(d, o, 64);
        if (lane == 0) sc[i] = tanhf(d / nrm);
    }
    __syncthreads();
    // --- rank (jax.lax.top_k: descending, lower index wins ties) ---
    if (tid < NPG) {
        float scv = sc[tid];
        int rank = 0;
        for (int j = 0; j < NPG; j++) {
            float o = sc[j];
            rank += (o > scv) || (o == scv && j < tid);
        }
        bool keep = rank < K1;
        pos[tid] = keep ? rank : -1;
        mapping[g * NPG + tid] = keep ? (g * K1 + rank) : -1;
    }
    __syncthreads();
    // --- conv1 recompute for kept nodes: pooled write + global max/mean ---
    float pm0 = -INFINITY, pm1 = -INFINITY, ps0 = 0.f, ps1 = 0.f;
    for (int i = wv; i < NPG; i += 4) {
        int r = pos[i];
        if (r < 0) continue;
        float c0 = bb0, c1 = bb1;
        #pragma unroll
        for (int j = 0; j < EMB; j++) {
            float m = mnL[i * EMB + j];
            float x = x0L[i * EMB + j];
            c0 += m * wn0[j] + x * wr0[j];
            c1 += m * wn1[j] + x * wr1[j];
        }
        float s = sc[i];
        float v0 = fmaxf(c0, 0.f) * s;
        float v1 = fmaxf(c1, 0.f) * s;
        long rowp = (long)(g * K1 + r) * HID;
        xout[rowp + lane] = v0;
        xout[rowp + 64 + lane] = v1;
        pm0 = fmaxf(pm0, v0); ps0 += v0;
        pm1 = fmaxf(pm1, v1); ps1 += v1;
    }
    redM[wv * 128 + lane] = pm0;      redS[wv * 128 + lane] = ps0;
    redM[wv * 128 + 64 + lane] = pm1; redS[wv * 128 + 64 + lane] = ps1;
    __syncthreads();
    if (tid < 128) {
        float mx = redM[tid], sm = redS[tid];
        #pragma unroll
        for (int w2 = 1; w2 < 4; w2++) {
            mx = fmaxf(mx, redM[w2 * 128 + tid]);
            sm += redS[w2 * 128 + tid];
        }
        gout[g * 256 + tid] = mx;
        gout[g * 256 + 128 + tid] = sm / (float)K1;
    }
}

// ---------------------------------------------------------------------------
// Stage-2/3 aggregation, CSR-based, FUSED edge remap, LDS-staged features:
// the block's per-graph feature half (npc x 64 floats, row stride 68 ->
// conflict-free) is loaded once with coalesced float4, then the CSR gather
// runs out of LDS (r8: global gather was ~333MB logical volume through L2,
// latency-bound at 82us). One block per (graph, feature-half). Emits MEAN.
__global__ __launch_bounds__(256) void k_aggcsr(const float* __restrict__ x,
                         const int* __restrict__ es,
                         const int* __restrict__ ed,
                         const int* __restrict__ map1,
                         const int* __restrict__ map2,   // may be null
                         int npc,
                         float* __restrict__ sout) {
    int g = blockIdx.x;
    int w = blockIdx.y;   // feature half (0/1)
    int tid = threadIdx.x;  // 256
    __shared__ float xL[K1 * 68];   // 43.5 KB (npc <= 160)
    __shared__ int deg[256];
    __shared__ int scanbuf[256];
    __shared__ int off[257];
    __shared__ int cur[256];
    __shared__ int csr[EPER];

    deg[tid] = 0;
    const int ebase = g * EPER;
    const int nbase = g * npc;
    const int hoff0 = w * 64;
    // stage this graph's feature half into LDS (coalesced float4)
    for (int i = tid; i < npc * 16; i += 256) {
        int r = i >> 4, c = (i & 15) * 4;
        *(float4*)&xL[r * 68 + c] =
            *(const float4*)(x + (long)(nbase + r) * HID + hoff0 + c);
    }
    __syncthreads();
    // pass 1: degrees (remap on the fly)
    for (int e = tid; e < EPER; e += 256) {
        int a = map1[es[ebase + e]];
        int b = map1[ed[ebase + e]];
        if (map2) {
            a = (a >= 0) ? map2[a] : -1;
            b = (b >= 0) ? map2[b] : -1;
        }
        if (a >= 0 && b >= 0) atomicAdd(&deg[b - nbase], 1);
    }
    __syncthreads();
    // Hillis-Steele inclusive scan over 256 entries
    int v = deg[tid];
    scanbuf[tid] = v;
    __syncthreads();
    #pragma unroll
    for (int d = 1; d < 256; d <<= 1) {
        int t = (tid >= d) ? scanbuf[tid - d] : 0;
        __syncthreads();
        scanbuf[tid] += t;
        __syncthreads();
    }
    if (tid == 0) off[0] = 0;
    off[tid + 1] = scanbuf[tid];
    __syncthreads();
    cur[tid] = off[tid];
    __syncthreads();
    // pass 2: scatter LOCAL src ids into CSR slots
    for (int e = tid; e < EPER; e += 256) {
        int a = map1[es[ebase + e]];
        int b = map1[ed[ebase + e]];
        if (map2) {
            a = (a >= 0) ? map2[a] : -1;
            b = (b >= 0) ? map2[b] : -1;
        }
        if (a >= 0 && b >= 0) {
            int slot = atomicAdd(&cur[b - nbase], 1);
            csr[slot] = a - nbase;      // local row id
        }
    }
    __syncthreads();
    // phase 2: one wave per dst, accumulate from LDS, write mean
    int lane = tid & 63, wv = tid >> 6;
    for (int dl = wv; dl < npc; dl += 4) {
        int beg = off[dl], end = off[dl + 1];
        float acc = 0.f, acc2 = 0.f;
        int t = beg;
        for (; t + 1 < end; t += 2) {
            acc  += xL[csr[t]     * 68 + lane];
            acc2 += xL[csr[t + 1] * 68 + lane];
        }
        if (t < end) acc += xL[csr[t] * 68 + lane];
        float inv = 1.f / (float)((end - beg) > 1 ? (end - beg) : 1);
        sout[(long)(nbase + dl) * HID + hoff0 + lane] = (acc + acc2) * inv;
    }
}

// ---------------------------------------------------------------------------
// Conv2/3 as LDS-tiled fp32 GEMM with K=256 (concat [mean_s, x] against
// [wn; wr] rows). ROUND-4 STRUCTURE — do not replace with XOR-swizzled
// row-major tiles: that variant (r5/r6) triggers pathological codegen
// (~900B/thread scratch write-back, WRITE_SIZE 41->192 MB, dur 89->138 us)
// regardless of inner-loop ordering or launch bounds. This k-major
// structure measured WRITE_SIZE == output exactly.
constexpr int GP = 132;  // LDS row pitch (floats): 16B-aligned, breaks pow-2
__global__ __launch_bounds__(256, 3) void k_convgemm(
        const float* s,                      // neighbor MEAN; may alias out
        const float* xin,
        const float* __restrict__ wn,
        const float* __restrict__ wr,
        const float* __restrict__ bb,
        float* out) {
    __shared__ float As[32 * GP];
    __shared__ float Bs[32 * GP];
    const int tid = threadIdx.x;
    const long row0 = (long)blockIdx.x * 128;

    const int tc = tid & 15, tr = tid >> 4;
    const int srow = tid >> 3;        // 0..31 (+i*32)
    const int scol = (tid & 7) * 4;   // k-offset within chunk: 0,4,..,28

    float acc[8][8];
    #pragma unroll
    for (int r = 0; r < 8; r++)
        #pragma unroll
        for (int c = 0; c < 8; c++) acc[r][c] = 0.f;

    // prefetch chunk 0
    float4 av[4], bv[4];
    #pragma unroll
    for (int i = 0; i < 4; i++) {
        int r = srow + i * 32;
        av[i] = *(const float4*)(s + (row0 + r) * HID + scol);
        bv[i] = *(const float4*)(wn + (size_t)r * HID + scol);
    }

    for (int ch = 0; ch < 8; ch++) {
        __syncthreads();  // LDS free
        #pragma unroll
        for (int i = 0; i < 4; i++) {
            int r = srow + i * 32;
            As[(scol + 0) * GP + r] = av[i].x;
            As[(scol + 1) * GP + r] = av[i].y;
            As[(scol + 2) * GP + r] = av[i].z;
            As[(scol + 3) * GP + r] = av[i].w;
            Bs[(scol + 0) * GP + r] = bv[i].x;
            Bs[(scol + 1) * GP + r] = bv[i].y;
            Bs[(scol + 2) * GP + r] = bv[i].z;
            Bs[(scol + 3) * GP + r] = bv[i].w;
        }
        __syncthreads();
        if (ch + 1 < 8) {
            const float* xsrc = (ch + 1 < 4) ? s : xin;
            const float* wsrc = (ch + 1 < 4) ? wn : wr;
            int kofs = ((ch + 1) & 3) * 32;
            #pragma unroll
            for (int i = 0; i < 4; i++) {
                int r = srow + i * 32;
                av[i] = *(const float4*)(xsrc + (row0 + r) * HID + kofs + scol);
                bv[i] = *(const float4*)(wsrc + (size_t)r * HID + kofs + scol);
            }
        }
        #pragma unroll 2
        for (int k = 0; k < 32; k++) {
            float4 a0 = *(const float4*)&As[k * GP + tr * 8];
            float4 a1 = *(const float4*)&As[k * GP + tr * 8 + 4];
            float4 b0 = *(const float4*)&Bs[k * GP + tc * 4];
            float4 b1 = *(const float4*)&Bs[k * GP + 64 + tc * 4];
            float a[8] = {a0.x, a0.y, a0.z, a0.w, a1.x, a1.y, a1.z, a1.w};
            float bb8[8] = {b0.x, b0.y, b0.z, b0.w, b1.x, b1.y, b1.z, b1.w};
            #pragma unroll
            for (int r = 0; r < 8; r++)
                #pragma unroll
                for (int c = 0; c < 8; c++) acc[r][c] += a[r] * bb8[c];
        }
    }

    float4 bias0 = *(const float4*)&bb[tc * 4];
    float4 bias1 = *(const float4*)&bb[64 + tc * 4];
    #pragma unroll
    for (int r = 0; r < 8; r++) {
        long m = row0 + tr * 8 + r;
        float4 o0, o1;
        o0.x = fmaxf(acc[r][0] + bias0.x, 0.f);
        o0.y = fmaxf(acc[r][1] + bias0.y, 0.f);
        o0.z = fmaxf(acc[r][2] + bias0.z, 0.f);
        o0.w = fmaxf(acc[r][3] + bias0.w, 0.f);
        o1.x = fmaxf(acc[r][4] + bias1.x, 0.f);
        o1.y = fmaxf(acc[r][5] + bias1.y, 0.f);
        o1.z = fmaxf(acc[r][6] + bias1.z, 0.f);
        o1.w = fmaxf(acc[r][7] + bias1.w, 0.f);
        *(float4*)(out + m * HID + tc * 4) = o0;
        *(float4*)(out + m * HID + 64 + tc * 4) = o1;
    }
}

// ---------------------------------------------------------------------------
// TopK pool + FUSED global max/mean pool (stages 2/3).
__global__ __launch_bounds__(256) void k_pool(const float* __restrict__ x,
                       const float* __restrict__ p,
                       int npc, int k,
                       float* __restrict__ xout,
                       int* __restrict__ mapping,
                       float* __restrict__ gout) {
    int g = blockIdx.x;
    int tid = threadIdx.x;  // 256
    __shared__ float sc[256];
    __shared__ int   pos[256];
    __shared__ float redm[128];
    __shared__ float reds[128];
    int lane = tid & 63, wv = tid >> 6;
    float pl0 = p[lane], pl1 = p[64 + lane];
    float pp = pl0 * pl0 + pl1 * pl1;
    #pragma unroll
    for (int o = 32; o >= 1; o >>= 1) pp += __shfl_xor(pp, o, 64);
    float nrm = sqrtf(pp);
    for (int i = wv; i < npc; i += 4) {
        const float* xr = x + (long)(g * npc + i) * HID;
        float d = xr[lane] * pl0 + xr[64 + lane] * pl1;
        #pragma unroll
        for (int o = 32; o >= 1; o >>= 1) d += __shfl_xor(d, o, 64);
        if (lane == 0) sc[i] = tanhf(d / nrm);
    }
    __syncthreads();
    if (tid < npc) {
        float scv = sc[tid];
        int rank = 0;
        for (int j = 0; j < npc; j++) {
            float o = sc[j];
            rank += (o > scv) || (o == scv && j < tid);
        }
        bool keep = rank < k;
        pos[tid] = keep ? rank : -1;
        mapping[g * npc + tid] = keep ? (g * k + rank) : -1;
    }
    __syncthreads();
    int h = tid & 127, half = tid >> 7;
    float pmax = -INFINITY, psum = 0.f;
    for (int i = half; i < npc; i += 2) {
        int r = pos[i];
        if (r >= 0) {
            float v = x[(long)(g * npc + i) * HID + h] * sc[i];
            xout[(long)(g * k + r) * HID + h] = v;
            pmax = fmaxf(pmax, v);
            psum += v;
        }
    }
    if (half) { redm[h] = pmax; reds[h] = psum; }
    __syncthreads();
    if (!half) {
        pmax = fmaxf(pmax, redm[h]);
        psum += reds[h];
        gout[g * 256 + h] = pmax;
        gout[g * 256 + 128 + h] = psum / (float)k;
    }
}

// ---------------------------------------------------------------------------
// MLP head: h=g1+g2+g3; relu(h@lw1.T+lb1); relu(@lw2.T+lb2); sigmoid(@lw3.T+lb3)
__global__ __launch_bounds__(128) void k_mlp(const float* __restrict__ g1, const float* __restrict__ g2,
                      const float* __restrict__ g3,
                      const float* __restrict__ lw1, const float* __restrict__ lb1,
                      const float* __restrict__ lw2, const float* __restrict__ lb2,
                      const float* __restrict__ lw3, const float* __restrict__ lb3,
                      float* __restrict__ out) {
    int g = blockIdx.x, t = threadIdx.x;  // 128 threads
    __shared__ float h0[256];
    __shared__ float h1[128];
    __shared__ float h2r[64];
    h0[t]       = g1[g * 256 + t] + g2[g * 256 + t] + g3[g * 256 + t];
    h0[t + 128] = g1[g * 256 + 128 + t] + g2[g * 256 + 128 + t] + g3[g * 256 + 128 + t];
    __syncthreads();
    float a = lb1[t];
    #pragma unroll 4
    for (int j = 0; j < 256; j++) a += h0[j] * lw1[t * 256 + j];
    h1[t] = fmaxf(a, 0.f);
    __syncthreads();
    if (t < 64) {
        float a2 = lb2[t];
        #pragma unroll 4
        for (int j = 0; j < 128; j++) a2 += h1[j] * lw2[t * 128 + j];
        h2r[t] = fmaxf(a2, 0.f) * lw3[t];
    }
    __syncthreads();
    if (t == 0) {
        float s = 0.f;
        for (int j = 0; j < 64; j++) s += h2r[j];
        s += lb3[0];
        out[g] = 1.f / (1.f + expf(-s));
    }
}

// ---------------------------------------------------------------------------
extern "C" void kernel_launch(void* const* d_in, const int* in_sizes, int n_in,
                              void* d_out, int out_size, void* d_ws, size_t ws_size,
                              hipStream_t stream) {
    const int*   node_ids = (const int*)d_in[0];
    const int*   ei   = (const int*)d_in[1];   // edge_index (2, E)
    const float* emb  = (const float*)d_in[3];
    const float* w1n  = (const float*)d_in[4];
    const float* w1r  = (const float*)d_in[5];
    const float* b1   = (const float*)d_in[6];
    const float* w2n  = (const float*)d_in[7];
    const float* w2r  = (const float*)d_in[8];
    const float* b2   = (const float*)d_in[9];
    const float* w3n  = (const float*)d_in[10];
    const float* w3r  = (const float*)d_in[11];
    const float* b3   = (const float*)d_in[12];
    const float* p1   = (const float*)d_in[13];
    const float* p2   = (const float*)d_in[14];
    const float* p3   = (const float*)d_in[15];
    const float* lw1  = (const float*)d_in[16];
    const float* lb1  = (const float*)d_in[17];
    const float* lw2  = (const float*)d_in[18];
    const float* lb2  = (const float*)d_in[19];
    const float* lw3  = (const float*)d_in[20];
    const float* lb3  = (const float*)d_in[21];
    float* out = (float*)d_out;

    // Workspace layout (floats).
    float* ws  = (float*)d_ws;
    float* C   = ws;                           // N0*HID   (mean / x2 / x3)
    float* D   = C + (size_t)N0 * HID;         // N1*HID   (x1p / x2p / x3p)
    float* g1  = D + (size_t)N1 * HID;         // B*256
    float* g2  = g1 + B * 2 * HID;             // B*256
    float* g3  = g2 + B * 2 * HID;             // B*256
    int* map1  = (int*)(g3 + B * 2 * HID);     // N0
    int* map2  = map1 + N0;                    // N1

    // ---- Stage 1 (EMB -> HID), fully fused per graph ----
    k_stage1<<<B, 256, 0, stream>>>(node_ids, emb, ei, ei + E,
                                    w1n, w1r, b1, p1, D, map1, g1);

    // ---- Stage 2 (HID -> HID), nodes N1 ----
    k_aggcsr<<<dim3(B, 2), 256, 0, stream>>>(D, ei, ei + E, map1, nullptr, K1, C);
    k_convgemm<<<N1 / 128, 256, 0, stream>>>(C, D, w2n, w2r, b2, C);
    k_pool<<<B, 256, 0, stream>>>(C, p2, K1, K2, D, map2, g2);

    // ---- Stage 3 (HID -> HID), nodes N2 ----
    k_aggcsr<<<dim3(B, 2), 256, 0, stream>>>(D, ei, ei + E, map1, map2, K2, C);
    k_convgemm<<<N2 / 128, 256, 0, stream>>>(C, D, w3n, w3r, b3, C);
    k_pool<<<B, 256, 0, stream>>>(C, p3, K2, K3, D, map1 /*scratch*/, g3);

    // ---- Head ----
    k_mlp<<<B, 128, 0, stream>>>(g1, g2, g3, lw1, lb1, lw2, lb2, lw3, lb3, out);
}

// Round 10
// 459.525 us; speedup vs baseline: 1.5855x; 1.1695x over previous
//
#include <hip/hip_runtime.h>
#include <math.h>

// Problem constants (from reference)
constexpr int B    = 512;
constexpr int NPG  = 200;    // nodes per graph, stage 0
constexpr int EPER = 2000;   // edges per graph
constexpr int EMB  = 9;
constexpr int HID  = 128;
constexpr int K1   = 160;    // ceil(0.8*200)
constexpr int K2   = 128;    // ceil(0.8*160)
constexpr int K3   = 103;    // ceil(0.8*128)
constexpr int N0   = B * NPG;   // 102400
constexpr int N1   = B * K1;    // 81920
constexpr int N2   = B * K2;    // 65536
constexpr int E    = B * EPER;  // 1024000

// ---------------------------------------------------------------------------
// Fused stage 1 (one block per graph, 256 threads): gather emb -> LDS,
// CSR build in LDS, neighbor mean (thread-per-dst), conv1 scores, top-K1
// rank, conv1 recompute for kept nodes -> pooled write + global max/mean.
__global__ __launch_bounds__(256) void k_stage1(
        const int* __restrict__ node_ids,
        const float* __restrict__ emb,
        const int* __restrict__ es, const int* __restrict__ ed,
        const float* __restrict__ w1n, const float* __restrict__ w1r,
        const float* __restrict__ b1, const float* __restrict__ p1,
        float* __restrict__ xout,    // pooled output (N1 x HID)
        int* __restrict__ mapping,   // old node id -> new (or -1), N0
        float* __restrict__ gout) {  // B x 256 global-pool
    const int g = blockIdx.x, tid = threadIdx.x;
    __shared__ float x0L[NPG * EMB];
    __shared__ float mnL[NPG * EMB];
    __shared__ int   idsL[NPG];
    __shared__ int   deg[256];
    __shared__ int   off2[257];
    __shared__ int   cur[256];
    __shared__ int   csr[EPER];
    __shared__ float sc[NPG];
    __shared__ int   pos[NPG];
    __shared__ float redM[4 * 128], redS[4 * 128];

    if (tid < NPG) idsL[tid] = node_ids[g * NPG + tid];
    deg[tid] = 0;
    __syncthreads();
    for (int i = tid; i < NPG * EMB; i += 256) {
        int n = i / EMB, j = i - n * EMB;
        x0L[i] = emb[(size_t)idsL[n] * EMB + j];
    }
    const int ebase = g * EPER, nbase = g * NPG;
    int lsrc[8], ldst[8];
    #pragma unroll
    for (int q = 0; q < 8; q++) {
        int e = tid + q * 256;
        lsrc[q] = es[ebase + e] - nbase;
        ldst[q] = ed[ebase + e] - nbase;
        atomicAdd(&deg[ldst[q]], 1);
    }
    __syncthreads();
    cur[tid] = deg[tid];
    __syncthreads();
    #pragma unroll
    for (int d = 1; d < 256; d <<= 1) {
        int t = (tid >= d) ? cur[tid - d] : 0;
        __syncthreads();
        cur[tid] += t;
        __syncthreads();
    }
    if (tid == 0) off2[0] = 0;
    off2[tid + 1] = cur[tid];
    __syncthreads();
    cur[tid] = off2[tid];
    __syncthreads();
    #pragma unroll
    for (int q = 0; q < 8; q++) {
        int slot = atomicAdd(&cur[ldst[q]], 1);
        csr[slot] = lsrc[q];
    }
    __syncthreads();
    if (tid < NPG) {
        int bg = off2[tid], en = off2[tid + 1];
        float a[EMB];
        #pragma unroll
        for (int j = 0; j < EMB; j++) a[j] = 0.f;
        for (int t = bg; t < en; t++) {
            int s = csr[t];
            #pragma unroll
            for (int j = 0; j < EMB; j++) a[j] += x0L[s * EMB + j];
        }
        float inv = 1.f / (float)((en - bg) > 1 ? (en - bg) : 1);
        #pragma unroll
        for (int j = 0; j < EMB; j++) mnL[tid * EMB + j] = a[j] * inv;
    }
    const int lane = tid & 63, wv = tid >> 6;
    float pl0 = p1[lane], pl1 = p1[64 + lane];
    float pp = pl0 * pl0 + pl1 * pl1;
    #pragma unroll
    for (int o = 32; o >= 1; o >>= 1) pp += __shfl_xor(pp, o, 64);
    float nrm = sqrtf(pp);
    float wn0[EMB], wn1[EMB], wr0[EMB], wr1[EMB];
    #pragma unroll
    for (int j = 0; j < EMB; j++) {
        wn0[j] = w1n[lane * EMB + j];
        wn1[j] = w1n[(lane + 64) * EMB + j];
        wr0[j] = w1r[lane * EMB + j];
        wr1[j] = w1r[(lane + 64) * EMB + j];
    }
    float bb0 = b1[lane], bb1 = b1[64 + lane];
    __syncthreads();
    for (int i = wv; i < NPG; i += 4) {
        float c0 = bb0, c1 = bb1;
        #pragma unroll
        for (int j = 0; j < EMB; j++) {
            float m = mnL[i * EMB + j];
            float x = x0L[i * EMB + j];
            c0 += m * wn0[j] + x * wr0[j];
            c1 += m * wn1[j] + x * wr1[j];
        }
        c0 = fmaxf(c0, 0.f);
        c1 = fmaxf(c1, 0.f);
        float d = c0 * pl0 + c1 * pl1;
        #pragma unroll
        for (int o = 32; o >= 1; o >>= 1) d += __shfl_xor(d, o, 64);
        if (lane == 0) sc[i] = tanhf(d / nrm);
    }
    __syncthreads();
    if (tid < NPG) {
        float scv = sc[tid];
        int rank = 0;
        for (int j = 0; j < NPG; j++) {
            float o = sc[j];
            rank += (o > scv) || (o == scv && j < tid);
        }
        bool keep = rank < K1;
        pos[tid] = keep ? rank : -1;
        mapping[g * NPG + tid] = keep ? (g * K1 + rank) : -1;
    }
    __syncthreads();
    float pm0 = -INFINITY, pm1 = -INFINITY, ps0 = 0.f, ps1 = 0.f;
    for (int i = wv; i < NPG; i += 4) {
        int r = pos[i];
        if (r < 0) continue;
        float c0 = bb0, c1 = bb1;
        #pragma unroll
        for (int j = 0; j < EMB; j++) {
            float m = mnL[i * EMB + j];
            float x = x0L[i * EMB + j];
            c0 += m * wn0[j] + x * wr0[j];
            c1 += m * wn1[j] + x * wr1[j];
        }
        float s = sc[i];
        float v0 = fmaxf(c0, 0.f) * s;
        float v1 = fmaxf(c1, 0.f) * s;
        long rowp = (long)(g * K1 + r) * HID;
        xout[rowp + lane] = v0;
        xout[rowp + 64 + lane] = v1;
        pm0 = fmaxf(pm0, v0); ps0 += v0;
        pm1 = fmaxf(pm1, v1); ps1 += v1;
    }
    redM[wv * 128 + lane] = pm0;      redS[wv * 128 + lane] = ps0;
    redM[wv * 128 + 64 + lane] = pm1; redS[wv * 128 + 64 + lane] = ps1;
    __syncthreads();
    if (tid < 128) {
        float mx = redM[tid], sm = redS[tid];
        #pragma unroll
        for (int w2 = 1; w2 < 4; w2++) {
            mx = fmaxf(mx, redM[w2 * 128 + tid]);
            sm += redS[w2 * 128 + tid];
        }
        gout[g * 256 + tid] = mx;
        gout[g * 256 + 128 + tid] = sm / (float)K1;
    }
}

// ---------------------------------------------------------------------------
// Stage-2/3 aggregation, CSR-based, FUSED edge remap, LDS-staged features.
// One block per (graph, feature-half). Emits the MEAN directly.
__global__ __launch_bounds__(256) void k_aggcsr(const float* __restrict__ x,
                         const int* __restrict__ es,
                         const int* __restrict__ ed,
                         const int* __restrict__ map1,
                         const int* __restrict__ map2,   // may be null
                         int npc,
                         float* __restrict__ sout) {
    int g = blockIdx.x;
    int w = blockIdx.y;   // feature half (0/1)
    int tid = threadIdx.x;  // 256
    __shared__ float xL[K1 * 68];   // 43.5 KB (npc <= 160)
    __shared__ int deg[256];
    __shared__ int scanbuf[256];
    __shared__ int off[257];
    __shared__ int cur[256];
    __shared__ int csr[EPER];

    deg[tid] = 0;
    const int ebase = g * EPER;
    const int nbase = g * npc;
    const int hoff0 = w * 64;
    for (int i = tid; i < npc * 16; i += 256) {
        int r = i >> 4, c = (i & 15) * 4;
        *(float4*)&xL[r * 68 + c] =
            *(const float4*)(x + (long)(nbase + r) * HID + hoff0 + c);
    }
    __syncthreads();
    for (int e = tid; e < EPER; e += 256) {
        int a = map1[es[ebase + e]];
        int b = map1[ed[ebase + e]];
        if (map2) {
            a = (a >= 0) ? map2[a] : -1;
            b = (b >= 0) ? map2[b] : -1;
        }
        if (a >= 0 && b >= 0) atomicAdd(&deg[b - nbase], 1);
    }
    __syncthreads();
    int v = deg[tid];
    scanbuf[tid] = v;
    __syncthreads();
    #pragma unroll
    for (int d = 1; d < 256; d <<= 1) {
        int t = (tid >= d) ? scanbuf[tid - d] : 0;
        __syncthreads();
        scanbuf[tid] += t;
        __syncthreads();
    }
    if (tid == 0) off[0] = 0;
    off[tid + 1] = scanbuf[tid];
    __syncthreads();
    cur[tid] = off[tid];
    __syncthreads();
    for (int e = tid; e < EPER; e += 256) {
        int a = map1[es[ebase + e]];
        int b = map1[ed[ebase + e]];
        if (map2) {
            a = (a >= 0) ? map2[a] : -1;
            b = (b >= 0) ? map2[b] : -1;
        }
        if (a >= 0 && b >= 0) {
            int slot = atomicAdd(&cur[b - nbase], 1);
            csr[slot] = a - nbase;      // local row id
        }
    }
    __syncthreads();
    int lane = tid & 63, wv = tid >> 6;
    for (int dl = wv; dl < npc; dl += 4) {
        int beg = off[dl], end = off[dl + 1];
        float acc = 0.f, acc2 = 0.f;
        int t = beg;
        for (; t + 1 < end; t += 2) {
            acc  += xL[csr[t]     * 68 + lane];
            acc2 += xL[csr[t + 1] * 68 + lane];
        }
        if (t < end) acc += xL[csr[t] * 68 + lane];
        float inv = 1.f / (float)((end - beg) > 1 ? (end - beg) : 1);
        sout[(long)(nbase + dl) * HID + hoff0 + lane] = (acc + acc2) * inv;
    }
}

// ---------------------------------------------------------------------------
// Conv (K=256: concat [mean, x] vs [wn; wr]) + FUSED topk-pool + global
// max/mean pool, ONE GRAPH PER BLOCK (MROWS = K1 or K2 rows).
// K-loop is byte-identical to the r4/r7 known-good structure (do NOT
// replace with XOR-swizzled tiles: r5/r6 spill pathology, WRITE 41->192MB).
// Epilogue: bias+relu in regs -> per-row score partials (fixed-order LDS
// tree, deterministic) -> rank (top_k semantics) -> pooled write (scaled)
// + per-column max/sum reduce. Stage 3 passes xout=mapping=null: x3/x3p
// never touch global memory (only gout).
template <int MROWS, int NTHR, int KKEEP>
__global__ __launch_bounds__(NTHR, 2) void k_convpool(
        const float* __restrict__ s,    // mean, rows g*MROWS..
        const float* __restrict__ xin,  // prev pooled x, rows g*MROWS..
        const float* __restrict__ wn, const float* __restrict__ wr,
        const float* __restrict__ bb, const float* __restrict__ p,
        float* __restrict__ xout,       // may be null; rows g*KKEEP..
        int* __restrict__ mapping,      // may be null
        float* __restrict__ gout) {
    constexpr int GPA = (MROWS == 160) ? 164 : 132;
    constexpr int RST = MROWS / 4;   // A staging row stride (40 / 32)
    constexpr int TRM = MROWS / 8;   // 20 / 16
    __shared__ float As[32 * GPA];
    __shared__ float Bs[32 * 132];
    __shared__ float sc[MROWS];
    __shared__ int   pos[MROWS];
    __shared__ float nrmL;
    const int tid = threadIdx.x;
    const int g = blockIdx.x;
    const long row0 = (long)g * MROWS;
    const int tc = tid & 15, tr = tid >> 4;
    const int srow = tid >> 3;
    const int scol = (tid & 7) * 4;

    // ||p|| (wave 0)
    if (tid < 64) {
        float a = p[tid], b = p[64 + tid];
        float pp = a * a + b * b;
        #pragma unroll
        for (int o = 32; o >= 1; o >>= 1) pp += __shfl_xor(pp, o, 64);
        if (tid == 0) nrmL = sqrtf(pp);
    }

    float acc[8][8];
    #pragma unroll
    for (int r = 0; r < 8; r++)
        #pragma unroll
        for (int c = 0; c < 8; c++) acc[r][c] = 0.f;

    // prefetch chunk 0
    float4 av[4], bv[4];
    #pragma unroll
    for (int i = 0; i < 4; i++)
        av[i] = *(const float4*)(s + (row0 + srow + i * RST) * HID + scol);
    if (srow < 32) {
        #pragma unroll
        for (int i = 0; i < 4; i++)
            bv[i] = *(const float4*)(wn + (size_t)(srow + i * 32) * HID + scol);
    }

    for (int ch = 0; ch < 8; ch++) {
        __syncthreads();
        #pragma unroll
        for (int i = 0; i < 4; i++) {
            int r = srow + i * RST;
            As[(scol + 0) * GPA + r] = av[i].x;
            As[(scol + 1) * GPA + r] = av[i].y;
            As[(scol + 2) * GPA + r] = av[i].z;
            As[(scol + 3) * GPA + r] = av[i].w;
        }
        if (srow < 32) {
            #pragma unroll
            for (int i = 0; i < 4; i++) {
                int r = srow + i * 32;
                Bs[(scol + 0) * 132 + r] = bv[i].x;
                Bs[(scol + 1) * 132 + r] = bv[i].y;
                Bs[(scol + 2) * 132 + r] = bv[i].z;
                Bs[(scol + 3) * 132 + r] = bv[i].w;
            }
        }
        __syncthreads();
        if (ch + 1 < 8) {
            const float* xs = (ch + 1 < 4) ? s : xin;
            const float* ws = (ch + 1 < 4) ? wn : wr;
            int kofs = ((ch + 1) & 3) * 32;
            #pragma unroll
            for (int i = 0; i < 4; i++)
                av[i] = *(const float4*)(xs + (row0 + srow + i * RST) * HID + kofs + scol);
            if (srow < 32) {
                #pragma unroll
                for (int i = 0; i < 4; i++)
                    bv[i] = *(const float4*)(ws + (size_t)(srow + i * 32) * HID + kofs + scol);
            }
        }
        #pragma unroll 2
        for (int k = 0; k < 32; k++) {
            float4 a0 = *(const float4*)&As[k * GPA + tr * 8];
            float4 a1 = *(const float4*)&As[k * GPA + tr * 8 + 4];
            float4 b0 = *(const float4*)&Bs[k * 132 + tc * 4];
            float4 b1 = *(const float4*)&Bs[k * 132 + 64 + tc * 4];
            float a[8] = {a0.x, a0.y, a0.z, a0.w, a1.x, a1.y, a1.z, a1.w};
            float bb8[8] = {b0.x, b0.y, b0.z, b0.w, b1.x, b1.y, b1.z, b1.w};
            #pragma unroll
            for (int r = 0; r < 8; r++)
                #pragma unroll
                for (int c = 0; c < 8; c++) acc[r][c] += a[r] * bb8[c];
        }
    }

    // --- epilogue: bias + relu into acc ---
    float bias[8], pv[8];
    #pragma unroll
    for (int cp = 0; cp < 8; cp++) {
        int col = (cp < 4) ? (tc * 4 + cp) : (64 + tc * 4 + (cp - 4));
        bias[cp] = bb[col];
        pv[cp] = p[col];
    }
    #pragma unroll
    for (int rr = 0; rr < 8; rr++)
        #pragma unroll
        for (int cp = 0; cp < 8; cp++)
            acc[rr][cp] = fmaxf(acc[rr][cp] + bias[cp], 0.f);

    // --- score partials into LDS (overlay Bs; all waves past K-loop) ---
    float* scpart = Bs;   // MROWS*16 floats <= 32*132
    __syncthreads();
    #pragma unroll
    for (int rr = 0; rr < 8; rr++) {
        float sp = 0.f;
        #pragma unroll
        for (int cp = 0; cp < 8; cp++) sp += acc[rr][cp] * pv[cp];
        scpart[(tr * 8 + rr) * 16 + tc] = sp;
    }
    __syncthreads();
    if (tid < MROWS) {
        float sum = 0.f;
        #pragma unroll
        for (int t = 0; t < 16; t++) sum += scpart[tid * 16 + t];
        sc[tid] = tanhf(sum / nrmL);
    }
    __syncthreads();
    // --- rank (top_k: descending, lower index wins ties) ---
    if (tid < MROWS) {
        float scv = sc[tid];
        int rank = 0;
        for (int j = 0; j < MROWS; j++) {
            float o = sc[j];
            rank += (o > scv) || (o == scv && j < tid);
        }
        bool keep = rank < KKEEP;
        pos[tid] = keep ? rank : -1;
        if (mapping) mapping[g * MROWS + tid] = keep ? (g * KKEEP + rank) : -1;
    }
    __syncthreads();
    // --- pooled write + per-thread max/sum over kept rows ---
    float cm[8], cs[8];
    #pragma unroll
    for (int cp = 0; cp < 8; cp++) { cm[cp] = -INFINITY; cs[cp] = 0.f; }
    #pragma unroll
    for (int rr = 0; rr < 8; rr++) {
        int m = tr * 8 + rr;
        int r = pos[m];
        if (r < 0) continue;
        float sv = sc[m];
        float v[8];
        #pragma unroll
        for (int cp = 0; cp < 8; cp++) {
            v[cp] = acc[rr][cp] * sv;
            cm[cp] = fmaxf(cm[cp], v[cp]);
            cs[cp] += v[cp];
        }
        if (xout) {
            long rowp = ((long)g * KKEEP + r) * HID;
            float4 o0 = {v[0], v[1], v[2], v[3]};
            float4 o1 = {v[4], v[5], v[6], v[7]};
            *(float4*)(xout + rowp + tc * 4) = o0;
            *(float4*)(xout + rowp + 64 + tc * 4) = o1;
        }
    }
    float* redM = As;               // TRM*128 (overlay As)
    float* redS = As + TRM * 128;   // TRM*128
    #pragma unroll
    for (int cp = 0; cp < 8; cp++) {
        int col = (cp < 4) ? (tc * 4 + cp) : (64 + tc * 4 + (cp - 4));
        redM[tr * 128 + col] = cm[cp];
        redS[tr * 128 + col] = cs[cp];
    }
    __syncthreads();
    if (tid < 128) {
        float mx = redM[tid], sm = redS[tid];
        #pragma unroll 4
        for (int t = 1; t < TRM; t++) {
            mx = fmaxf(mx, redM[t * 128 + tid]);
            sm += redS[t * 128 + tid];
        }
        gout[g * 256 + tid] = mx;
        gout[g * 256 + 128 + tid] = sm / (float)KKEEP;
    }
}

// ---------------------------------------------------------------------------
// MLP head: h=g1+g2+g3; relu(h@lw1.T+lb1); relu(@lw2.T+lb2); sigmoid(@lw3.T+lb3)
__global__ __launch_bounds__(128) void k_mlp(const float* __restrict__ g1, const float* __restrict__ g2,
                      const float* __restrict__ g3,
                      const float* __restrict__ lw1, const float* __restrict__ lb1,
                      const float* __restrict__ lw2, const float* __restrict__ lb2,
                      const float* __restrict__ lw3, const float* __restrict__ lb3,
                      float* __restrict__ out) {
    int g = blockIdx.x, t = threadIdx.x;  // 128 threads
    __shared__ float h0[256];
    __shared__ float h1[128];
    __shared__ float h2r[64];
    h0[t]       = g1[g * 256 + t] + g2[g * 256 + t] + g3[g * 256 + t];
    h0[t + 128] = g1[g * 256 + 128 + t] + g2[g * 256 + 128 + t] + g3[g * 256 + 128 + t];
    __syncthreads();
    float a = lb1[t];
    #pragma unroll 4
    for (int j = 0; j < 256; j++) a += h0[j] * lw1[t * 256 + j];
    h1[t] = fmaxf(a, 0.f);
    __syncthreads();
    if (t < 64) {
        float a2 = lb2[t];
        #pragma unroll 4
        for (int j = 0; j < 128; j++) a2 += h1[j] * lw2[t * 128 + j];
        h2r[t] = fmaxf(a2, 0.f) * lw3[t];
    }
    __syncthreads();
    if (t == 0) {
        float s = 0.f;
        for (int j = 0; j < 64; j++) s += h2r[j];
        s += lb3[0];
        out[g] = 1.f / (1.f + expf(-s));
    }
}

// ---------------------------------------------------------------------------
extern "C" void kernel_launch(void* const* d_in, const int* in_sizes, int n_in,
                              void* d_out, int out_size, void* d_ws, size_t ws_size,
                              hipStream_t stream) {
    const int*   node_ids = (const int*)d_in[0];
    const int*   ei   = (const int*)d_in[1];   // edge_index (2, E)
    const float* emb  = (const float*)d_in[3];
    const float* w1n  = (const float*)d_in[4];
    const float* w1r  = (const float*)d_in[5];
    const float* b1   = (const float*)d_in[6];
    const float* w2n  = (const float*)d_in[7];
    const float* w2r  = (const float*)d_in[8];
    const float* b2   = (const float*)d_in[9];
    const float* w3n  = (const float*)d_in[10];
    const float* w3r  = (const float*)d_in[11];
    const float* b3   = (const float*)d_in[12];
    const float* p1   = (const float*)d_in[13];
    const float* p2   = (const float*)d_in[14];
    const float* p3   = (const float*)d_in[15];
    const float* lw1  = (const float*)d_in[16];
    const float* lb1  = (const float*)d_in[17];
    const float* lw2  = (const float*)d_in[18];
    const float* lb2  = (const float*)d_in[19];
    const float* lw3  = (const float*)d_in[20];
    const float* lb3  = (const float*)d_in[21];
    float* out = (float*)d_out;

    // Workspace layout (floats): ~120 MB total.
    float* ws  = (float*)d_ws;
    float* C   = ws;                           // N1*HID  (mean2 / mean3)
    float* D   = C + (size_t)N1 * HID;         // N1*HID  (x1p)
    float* D2  = D + (size_t)N1 * HID;         // N2*HID  (x2p) - fresh buffer:
                                               // in-place would race across blocks
    float* g1  = D2 + (size_t)N2 * HID;        // B*256
    float* g2  = g1 + B * 2 * HID;             // B*256
    float* g3  = g2 + B * 2 * HID;             // B*256
    int* map1  = (int*)(g3 + B * 2 * HID);     // N0
    int* map2  = map1 + N0;                    // N1

    // ---- Stage 1 (EMB -> HID), fully fused per graph ----
    k_stage1<<<B, 256, 0, stream>>>(node_ids, emb, ei, ei + E,
                                    w1n, w1r, b1, p1, D, map1, g1);

    // ---- Stage 2: agg (mean2 into C) then conv+pool fused ----
    k_aggcsr<<<dim3(B, 2), 256, 0, stream>>>(D, ei, ei + E, map1, nullptr, K1, C);
    k_convpool<K1, 320, K2><<<B, 320, 0, stream>>>(C, D, w2n, w2r, b2, p2,
                                                   D2, map2, g2);

    // ---- Stage 3: agg (mean3 into C) then conv+pool fused (gout only) ----
    k_aggcsr<<<dim3(B, 2), 256, 0, stream>>>(D2, ei, ei + E, map1, map2, K2, C);
    k_convpool<K2, 256, K3><<<B, 256, 0, stream>>>(C, D2, w3n, w3r, b3, p3,
                                                   nullptr, nullptr, g3);

    // ---- Head ----
    k_mlp<<<B, 128, 0, stream>>>(g1, g2, g3, lw1, lb1, lw2, lb2, lw3, lb3, out);
}

// Round 11
// 450.813 us; speedup vs baseline: 1.6162x; 1.0193x over previous
//
#include <hip/hip_runtime.h>
#include <math.h>

// Problem constants (from reference)
constexpr int B    = 512;
constexpr int NPG  = 200;    // nodes per graph, stage 0
constexpr int EPER = 2000;   // edges per graph
constexpr int EMB  = 9;
constexpr int HID  = 128;
constexpr int K1   = 160;    // ceil(0.8*200)
constexpr int K2   = 128;    // ceil(0.8*160)
constexpr int K3   = 103;    // ceil(0.8*128)
constexpr int N0   = B * NPG;   // 102400
constexpr int N1   = B * K1;    // 81920
constexpr int N2   = B * K2;    // 65536
constexpr int E    = B * EPER;  // 1024000

// ---------------------------------------------------------------------------
// Fused stage 1 (one block per graph, 256 threads): gather emb -> LDS,
// CSR build in LDS, neighbor mean (thread-per-dst), conv1 scores, top-K1
// rank, conv1 recompute for kept nodes -> pooled write + global max/mean.
__global__ __launch_bounds__(256) void k_stage1(
        const int* __restrict__ node_ids,
        const float* __restrict__ emb,
        const int* __restrict__ es, const int* __restrict__ ed,
        const float* __restrict__ w1n, const float* __restrict__ w1r,
        const float* __restrict__ b1, const float* __restrict__ p1,
        float* __restrict__ xout,    // pooled output (N1 x HID)
        int* __restrict__ mapping,   // old node id -> new (or -1), N0
        float* __restrict__ gout) {  // B x 256 global-pool
    const int g = blockIdx.x, tid = threadIdx.x;
    __shared__ float x0L[NPG * EMB];
    __shared__ float mnL[NPG * EMB];
    __shared__ int   idsL[NPG];
    __shared__ int   deg[256];
    __shared__ int   off2[257];
    __shared__ int   cur[256];
    __shared__ int   csr[EPER];
    __shared__ float sc[NPG];
    __shared__ int   pos[NPG];
    __shared__ float redM[4 * 128], redS[4 * 128];

    if (tid < NPG) idsL[tid] = node_ids[g * NPG + tid];
    deg[tid] = 0;
    __syncthreads();
    for (int i = tid; i < NPG * EMB; i += 256) {
        int n = i / EMB, j = i - n * EMB;
        x0L[i] = emb[(size_t)idsL[n] * EMB + j];
    }
    const int ebase = g * EPER, nbase = g * NPG;
    int lsrc[8], ldst[8];
    #pragma unroll
    for (int q = 0; q < 8; q++) {
        int e = tid + q * 256;
        lsrc[q] = es[ebase + e] - nbase;
        ldst[q] = ed[ebase + e] - nbase;
        atomicAdd(&deg[ldst[q]], 1);
    }
    __syncthreads();
    cur[tid] = deg[tid];
    __syncthreads();
    #pragma unroll
    for (int d = 1; d < 256; d <<= 1) {
        int t = (tid >= d) ? cur[tid - d] : 0;
        __syncthreads();
        cur[tid] += t;
        __syncthreads();
    }
    if (tid == 0) off2[0] = 0;
    off2[tid + 1] = cur[tid];
    __syncthreads();
    cur[tid] = off2[tid];
    __syncthreads();
    #pragma unroll
    for (int q = 0; q < 8; q++) {
        int slot = atomicAdd(&cur[ldst[q]], 1);
        csr[slot] = lsrc[q];
    }
    __syncthreads();
    if (tid < NPG) {
        int bg = off2[tid], en = off2[tid + 1];
        float a[EMB];
        #pragma unroll
        for (int j = 0; j < EMB; j++) a[j] = 0.f;
        for (int t = bg; t < en; t++) {
            int s = csr[t];
            #pragma unroll
            for (int j = 0; j < EMB; j++) a[j] += x0L[s * EMB + j];
        }
        float inv = 1.f / (float)((en - bg) > 1 ? (en - bg) : 1);
        #pragma unroll
        for (int j = 0; j < EMB; j++) mnL[tid * EMB + j] = a[j] * inv;
    }
    const int lane = tid & 63, wv = tid >> 6;
    float pl0 = p1[lane], pl1 = p1[64 + lane];
    float pp = pl0 * pl0 + pl1 * pl1;
    #pragma unroll
    for (int o = 32; o >= 1; o >>= 1) pp += __shfl_xor(pp, o, 64);
    float nrm = sqrtf(pp);
    float wn0[EMB], wn1[EMB], wr0[EMB], wr1[EMB];
    #pragma unroll
    for (int j = 0; j < EMB; j++) {
        wn0[j] = w1n[lane * EMB + j];
        wn1[j] = w1n[(lane + 64) * EMB + j];
        wr0[j] = w1r[lane * EMB + j];
        wr1[j] = w1r[(lane + 64) * EMB + j];
    }
    float bb0 = b1[lane], bb1 = b1[64 + lane];
    __syncthreads();
    for (int i = wv; i < NPG; i += 4) {
        float c0 = bb0, c1 = bb1;
        #pragma unroll
        for (int j = 0; j < EMB; j++) {
            float m = mnL[i * EMB + j];
            float x = x0L[i * EMB + j];
            c0 += m * wn0[j] + x * wr0[j];
            c1 += m * wn1[j] + x * wr1[j];
        }
        c0 = fmaxf(c0, 0.f);
        c1 = fmaxf(c1, 0.f);
        float d = c0 * pl0 + c1 * pl1;
        #pragma unroll
        for (int o = 32; o >= 1; o >>= 1) d += __shfl_xor(d, o, 64);
        if (lane == 0) sc[i] = tanhf(d / nrm);
    }
    __syncthreads();
    if (tid < NPG) {
        float scv = sc[tid];
        int rank = 0;
        for (int j = 0; j < NPG; j++) {
            float o = sc[j];
            rank += (o > scv) || (o == scv && j < tid);
        }
        bool keep = rank < K1;
        pos[tid] = keep ? rank : -1;
        mapping[g * NPG + tid] = keep ? (g * K1 + rank) : -1;
    }
    __syncthreads();
    float pm0 = -INFINITY, pm1 = -INFINITY, ps0 = 0.f, ps1 = 0.f;
    for (int i = wv; i < NPG; i += 4) {
        int r = pos[i];
        if (r < 0) continue;
        float c0 = bb0, c1 = bb1;
        #pragma unroll
        for (int j = 0; j < EMB; j++) {
            float m = mnL[i * EMB + j];
            float x = x0L[i * EMB + j];
            c0 += m * wn0[j] + x * wr0[j];
            c1 += m * wn1[j] + x * wr1[j];
        }
        float s = sc[i];
        float v0 = fmaxf(c0, 0.f) * s;
        float v1 = fmaxf(c1, 0.f) * s;
        long rowp = (long)(g * K1 + r) * HID;
        xout[rowp + lane] = v0;
        xout[rowp + 64 + lane] = v1;
        pm0 = fmaxf(pm0, v0); ps0 += v0;
        pm1 = fmaxf(pm1, v1); ps1 += v1;
    }
    redM[wv * 128 + lane] = pm0;      redS[wv * 128 + lane] = ps0;
    redM[wv * 128 + 64 + lane] = pm1; redS[wv * 128 + 64 + lane] = ps1;
    __syncthreads();
    if (tid < 128) {
        float mx = redM[tid], sm = redS[tid];
        #pragma unroll
        for (int w2 = 1; w2 < 4; w2++) {
            mx = fmaxf(mx, redM[w2 * 128 + tid]);
            sm += redS[w2 * 128 + tid];
        }
        gout[g * 256 + tid] = mx;
        gout[g * 256 + 128 + tid] = sm / (float)K1;
    }
}

// ---------------------------------------------------------------------------
// Stage-2/3 aggregation, CSR-based, FUSED edge remap, LDS-staged features.
// One block per (graph, feature-half). Emits the MEAN directly.
__global__ __launch_bounds__(256) void k_aggcsr(const float* __restrict__ x,
                         const int* __restrict__ es,
                         const int* __restrict__ ed,
                         const int* __restrict__ map1,
                         const int* __restrict__ map2,   // may be null
                         int npc,
                         float* __restrict__ sout) {
    int g = blockIdx.x;
    int w = blockIdx.y;   // feature half (0/1)
    int tid = threadIdx.x;  // 256
    __shared__ float xL[K1 * 68];   // 43.5 KB (npc <= 160)
    __shared__ int deg[256];
    __shared__ int scanbuf[256];
    __shared__ int off[257];
    __shared__ int cur[256];
    __shared__ int csr[EPER];

    deg[tid] = 0;
    const int ebase = g * EPER;
    const int nbase = g * npc;
    const int hoff0 = w * 64;
    for (int i = tid; i < npc * 16; i += 256) {
        int r = i >> 4, c = (i & 15) * 4;
        *(float4*)&xL[r * 68 + c] =
            *(const float4*)(x + (long)(nbase + r) * HID + hoff0 + c);
    }
    __syncthreads();
    for (int e = tid; e < EPER; e += 256) {
        int a = map1[es[ebase + e]];
        int b = map1[ed[ebase + e]];
        if (map2) {
            a = (a >= 0) ? map2[a] : -1;
            b = (b >= 0) ? map2[b] : -1;
        }
        if (a >= 0 && b >= 0) atomicAdd(&deg[b - nbase], 1);
    }
    __syncthreads();
    int v = deg[tid];
    scanbuf[tid] = v;
    __syncthreads();
    #pragma unroll
    for (int d = 1; d < 256; d <<= 1) {
        int t = (tid >= d) ? scanbuf[tid - d] : 0;
        __syncthreads();
        scanbuf[tid] += t;
        __syncthreads();
    }
    if (tid == 0) off[0] = 0;
    off[tid + 1] = scanbuf[tid];
    __syncthreads();
    cur[tid] = off[tid];
    __syncthreads();
    for (int e = tid; e < EPER; e += 256) {
        int a = map1[es[ebase + e]];
        int b = map1[ed[ebase + e]];
        if (map2) {
            a = (a >= 0) ? map2[a] : -1;
            b = (b >= 0) ? map2[b] : -1;
        }
        if (a >= 0 && b >= 0) {
            int slot = atomicAdd(&cur[b - nbase], 1);
            csr[slot] = a - nbase;      // local row id
        }
    }
    __syncthreads();
    int lane = tid & 63, wv = tid >> 6;
    for (int dl = wv; dl < npc; dl += 4) {
        int beg = off[dl], end = off[dl + 1];
        float acc = 0.f, acc2 = 0.f;
        int t = beg;
        for (; t + 1 < end; t += 2) {
            acc  += xL[csr[t]     * 68 + lane];
            acc2 += xL[csr[t + 1] * 68 + lane];
        }
        if (t < end) acc += xL[csr[t] * 68 + lane];
        float inv = 1.f / (float)((end - beg) > 1 ? (end - beg) : 1);
        sout[(long)(nbase + dl) * HID + hoff0 + lane] = (acc + acc2) * inv;
    }
}

// ---------------------------------------------------------------------------
// Conv (K=256: concat [mean, x] vs [wn; wr]) + FUSED topk-pool + global
// max/mean pool, ONE GRAPH PER BLOCK (MROWS = K1 or K2 rows).
// K-loop addressing/compute is the r4/r7 known-good structure (do NOT
// replace with XOR-swizzled tiles: r5/r6 spill pathology, WRITE 41->192MB).
// r11 change: DOUBLE-BUFFERED LDS tiles -> ONE barrier per chunk (was 2).
// Safety: waves skew <=1 iteration across a barrier, so a write to
// buf(ch&1) can only overlap compute(ch-1) on the other buffer. LDS grows
// 39->77KB but grid is 2 blocks/CU anyway (512 blocks), so occupancy is
// unchanged. Epilogue overlays live in buffer 0; final compute reads buf 1.
template <int MROWS, int NTHR, int KKEEP>
__global__ __launch_bounds__(NTHR, 2) void k_convpool(
        const float* __restrict__ s,    // mean, rows g*MROWS..
        const float* __restrict__ xin,  // prev pooled x, rows g*MROWS..
        const float* __restrict__ wn, const float* __restrict__ wr,
        const float* __restrict__ bb, const float* __restrict__ p,
        float* __restrict__ xout,       // may be null; rows g*KKEEP..
        int* __restrict__ mapping,      // may be null
        float* __restrict__ gout) {
    constexpr int GPA = (MROWS == 160) ? 164 : 132;
    constexpr int RST = MROWS / 4;   // A staging row stride (40 / 32)
    constexpr int TRM = MROWS / 8;   // 20 / 16
    __shared__ float As[2 * 32 * GPA];
    __shared__ float Bs[2 * 32 * 132];
    __shared__ float sc[MROWS];
    __shared__ int   pos[MROWS];
    __shared__ float nrmL;
    const int tid = threadIdx.x;
    const int g = blockIdx.x;
    const long row0 = (long)g * MROWS;
    const int tc = tid & 15, tr = tid >> 4;
    const int srow = tid >> 3;
    const int scol = (tid & 7) * 4;

    // ||p|| (wave 0)
    if (tid < 64) {
        float a = p[tid], b = p[64 + tid];
        float pp = a * a + b * b;
        #pragma unroll
        for (int o = 32; o >= 1; o >>= 1) pp += __shfl_xor(pp, o, 64);
        if (tid == 0) nrmL = sqrtf(pp);
    }

    float acc[8][8];
    #pragma unroll
    for (int r = 0; r < 8; r++)
        #pragma unroll
        for (int c = 0; c < 8; c++) acc[r][c] = 0.f;

    // prefetch chunk 0
    float4 av[4], bv[4];
    #pragma unroll
    for (int i = 0; i < 4; i++)
        av[i] = *(const float4*)(s + (row0 + srow + i * RST) * HID + scol);
    if (srow < 32) {
        #pragma unroll
        for (int i = 0; i < 4; i++)
            bv[i] = *(const float4*)(wn + (size_t)(srow + i * 32) * HID + scol);
    }

    for (int ch = 0; ch < 8; ch++) {
        float* Ab = As + (ch & 1) * (32 * GPA);
        float* Bb = Bs + (ch & 1) * (32 * 132);
        #pragma unroll
        for (int i = 0; i < 4; i++) {
            int r = srow + i * RST;
            Ab[(scol + 0) * GPA + r] = av[i].x;
            Ab[(scol + 1) * GPA + r] = av[i].y;
            Ab[(scol + 2) * GPA + r] = av[i].z;
            Ab[(scol + 3) * GPA + r] = av[i].w;
        }
        if (srow < 32) {
            #pragma unroll
            for (int i = 0; i < 4; i++) {
                int r = srow + i * 32;
                Bb[(scol + 0) * 132 + r] = bv[i].x;
                Bb[(scol + 1) * 132 + r] = bv[i].y;
                Bb[(scol + 2) * 132 + r] = bv[i].z;
                Bb[(scol + 3) * 132 + r] = bv[i].w;
            }
        }
        __syncthreads();
        if (ch + 1 < 8) {
            const float* xs = (ch + 1 < 4) ? s : xin;
            const float* ws = (ch + 1 < 4) ? wn : wr;
            int kofs = ((ch + 1) & 3) * 32;
            #pragma unroll
            for (int i = 0; i < 4; i++)
                av[i] = *(const float4*)(xs + (row0 + srow + i * RST) * HID + kofs + scol);
            if (srow < 32) {
                #pragma unroll
                for (int i = 0; i < 4; i++)
                    bv[i] = *(const float4*)(ws + (size_t)(srow + i * 32) * HID + kofs + scol);
            }
        }
        #pragma unroll 2
        for (int k = 0; k < 32; k++) {
            float4 a0 = *(const float4*)&Ab[k * GPA + tr * 8];
            float4 a1 = *(const float4*)&Ab[k * GPA + tr * 8 + 4];
            float4 b0 = *(const float4*)&Bb[k * 132 + tc * 4];
            float4 b1 = *(const float4*)&Bb[k * 132 + 64 + tc * 4];
            float a[8] = {a0.x, a0.y, a0.z, a0.w, a1.x, a1.y, a1.z, a1.w};
            float bb8[8] = {b0.x, b0.y, b0.z, b0.w, b1.x, b1.y, b1.z, b1.w};
            #pragma unroll
            for (int r = 0; r < 8; r++)
                #pragma unroll
                for (int c = 0; c < 8; c++) acc[r][c] += a[r] * bb8[c];
        }
    }

    // --- epilogue: bias + relu into acc ---
    float bias[8], pv[8];
    #pragma unroll
    for (int cp = 0; cp < 8; cp++) {
        int col = (cp < 4) ? (tc * 4 + cp) : (64 + tc * 4 + (cp - 4));
        bias[cp] = bb[col];
        pv[cp] = p[col];
    }
    #pragma unroll
    for (int rr = 0; rr < 8; rr++)
        #pragma unroll
        for (int cp = 0; cp < 8; cp++)
            acc[rr][cp] = fmaxf(acc[rr][cp] + bias[cp], 0.f);

    // --- score partials into LDS (overlay Bs buffer 0) ---
    float* scpart = Bs;   // MROWS*16 floats <= 32*132
    __syncthreads();
    #pragma unroll
    for (int rr = 0; rr < 8; rr++) {
        float sp = 0.f;
        #pragma unroll
        for (int cp = 0; cp < 8; cp++) sp += acc[rr][cp] * pv[cp];
        scpart[(tr * 8 + rr) * 16 + tc] = sp;
    }
    __syncthreads();
    if (tid < MROWS) {
        float sum = 0.f;
        #pragma unroll
        for (int t = 0; t < 16; t++) sum += scpart[tid * 16 + t];
        sc[tid] = tanhf(sum / nrmL);
    }
    __syncthreads();
    // --- rank (top_k: descending, lower index wins ties) ---
    if (tid < MROWS) {
        float scv = sc[tid];
        int rank = 0;
        for (int j = 0; j < MROWS; j++) {
            float o = sc[j];
            rank += (o > scv) || (o == scv && j < tid);
        }
        bool keep = rank < KKEEP;
        pos[tid] = keep ? rank : -1;
        if (mapping) mapping[g * MROWS + tid] = keep ? (g * KKEEP + rank) : -1;
    }
    __syncthreads();
    // --- pooled write + per-thread max/sum over kept rows ---
    float cm[8], cs[8];
    #pragma unroll
    for (int cp = 0; cp < 8; cp++) { cm[cp] = -INFINITY; cs[cp] = 0.f; }
    #pragma unroll
    for (int rr = 0; rr < 8; rr++) {
        int m = tr * 8 + rr;
        int r = pos[m];
        if (r < 0) continue;
        float sv = sc[m];
        float v[8];
        #pragma unroll
        for (int cp = 0; cp < 8; cp++) {
            v[cp] = acc[rr][cp] * sv;
            cm[cp] = fmaxf(cm[cp], v[cp]);
            cs[cp] += v[cp];
        }
        if (xout) {
            long rowp = ((long)g * KKEEP + r) * HID;
            float4 o0 = {v[0], v[1], v[2], v[3]};
            float4 o1 = {v[4], v[5], v[6], v[7]};
            *(float4*)(xout + rowp + tc * 4) = o0;
            *(float4*)(xout + rowp + 64 + tc * 4) = o1;
        }
    }
    float* redM = As;               // TRM*128 (overlay As buffer 0)
    float* redS = As + TRM * 128;   // TRM*128
    #pragma unroll
    for (int cp = 0; cp < 8; cp++) {
        int col = (cp < 4) ? (tc * 4 + cp) : (64 + tc * 4 + (cp - 4));
        redM[tr * 128 + col] = cm[cp];
        redS[tr * 128 + col] = cs[cp];
    }
    __syncthreads();
    if (tid < 128) {
        float mx = redM[tid], sm = redS[tid];
        #pragma unroll 4
        for (int t = 1; t < TRM; t++) {
            mx = fmaxf(mx, redM[t * 128 + tid]);
            sm += redS[t * 128 + tid];
        }
        gout[g * 256 + tid] = mx;
        gout[g * 256 + 128 + tid] = sm / (float)KKEEP;
    }
}

// ---------------------------------------------------------------------------
// MLP head: h=g1+g2+g3; relu(h@lw1.T+lb1); relu(@lw2.T+lb2); sigmoid(@lw3.T+lb3)
__global__ __launch_bounds__(128) void k_mlp(const float* __restrict__ g1, const float* __restrict__ g2,
                      const float* __restrict__ g3,
                      const float* __restrict__ lw1, const float* __restrict__ lb1,
                      const float* __restrict__ lw2, const float* __restrict__ lb2,
                      const float* __restrict__ lw3, const float* __restrict__ lb3,
                      float* __restrict__ out) {
    int g = blockIdx.x, t = threadIdx.x;  // 128 threads
    __shared__ float h0[256];
    __shared__ float h1[128];
    __shared__ float h2r[64];
    h0[t]       = g1[g * 256 + t] + g2[g * 256 + t] + g3[g * 256 + t];
    h0[t + 128] = g1[g * 256 + 128 + t] + g2[g * 256 + 128 + t] + g3[g * 256 + 128 + t];
    __syncthreads();
    float a = lb1[t];
    #pragma unroll 4
    for (int j = 0; j < 256; j++) a += h0[j] * lw1[t * 256 + j];
    h1[t] = fmaxf(a, 0.f);
    __syncthreads();
    if (t < 64) {
        float a2 = lb2[t];
        #pragma unroll 4
        for (int j = 0; j < 128; j++) a2 += h1[j] * lw2[t * 128 + j];
        h2r[t] = fmaxf(a2, 0.f) * lw3[t];
    }
    __syncthreads();
    if (t == 0) {
        float s = 0.f;
        for (int j = 0; j < 64; j++) s += h2r[j];
        s += lb3[0];
        out[g] = 1.f / (1.f + expf(-s));
    }
}

// ---------------------------------------------------------------------------
extern "C" void kernel_launch(void* const* d_in, const int* in_sizes, int n_in,
                              void* d_out, int out_size, void* d_ws, size_t ws_size,
                              hipStream_t stream) {
    const int*   node_ids = (const int*)d_in[0];
    const int*   ei   = (const int*)d_in[1];   // edge_index (2, E)
    const float* emb  = (const float*)d_in[3];
    const float* w1n  = (const float*)d_in[4];
    const float* w1r  = (const float*)d_in[5];
    const float* b1   = (const float*)d_in[6];
    const float* w2n  = (const float*)d_in[7];
    const float* w2r  = (const float*)d_in[8];
    const float* b2   = (const float*)d_in[9];
    const float* w3n  = (const float*)d_in[10];
    const float* w3r  = (const float*)d_in[11];
    const float* b3   = (const float*)d_in[12];
    const float* p1   = (const float*)d_in[13];
    const float* p2   = (const float*)d_in[14];
    const float* p3   = (const float*)d_in[15];
    const float* lw1  = (const float*)d_in[16];
    const float* lb1  = (const float*)d_in[17];
    const float* lw2  = (const float*)d_in[18];
    const float* lb2  = (const float*)d_in[19];
    const float* lw3  = (const float*)d_in[20];
    const float* lb3  = (const float*)d_in[21];
    float* out = (float*)d_out;

    // Workspace layout (floats): ~120 MB total.
    float* ws  = (float*)d_ws;
    float* C   = ws;                           // N1*HID  (mean2 / mean3)
    float* D   = C + (size_t)N1 * HID;         // N1*HID  (x1p)
    float* D2  = D + (size_t)N1 * HID;         // N2*HID  (x2p) - fresh buffer:
                                               // in-place would race across blocks
    float* g1  = D2 + (size_t)N2 * HID;        // B*256
    float* g2  = g1 + B * 2 * HID;             // B*256
    float* g3  = g2 + B * 2 * HID;             // B*256
    int* map1  = (int*)(g3 + B * 2 * HID);     // N0
    int* map2  = map1 + N0;                    // N1

    // ---- Stage 1 (EMB -> HID), fully fused per graph ----
    k_stage1<<<B, 256, 0, stream>>>(node_ids, emb, ei, ei + E,
                                    w1n, w1r, b1, p1, D, map1, g1);

    // ---- Stage 2: agg (mean2 into C) then conv+pool fused ----
    k_aggcsr<<<dim3(B, 2), 256, 0, stream>>>(D, ei, ei + E, map1, nullptr, K1, C);
    k_convpool<K1, 320, K2><<<B, 320, 0, stream>>>(C, D, w2n, w2r, b2, p2,
                                                   D2, map2, g2);

    // ---- Stage 3: agg (mean3 into C) then conv+pool fused (gout only) ----
    k_aggcsr<<<dim3(B, 2), 256, 0, stream>>>(D2, ei, ei + E, map1, map2, K2, C);
    k_convpool<K2, 256, K3><<<B, 256, 0, stream>>>(C, D2, w3n, w3r, b3, p3,
                                                   nullptr, nullptr, g3);

    // ---- Head ----
    k_mlp<<<B, 128, 0, stream>>>(g1, g2, g3, lw1, lb1, lw2, lb2, lw3, lb3, out);
}

// Round 12
// 442.674 us; speedup vs baseline: 1.6459x; 1.0184x over previous
//
#include <hip/hip_runtime.h>
#include <math.h>

// Problem constants (from reference)
constexpr int B    = 512;
constexpr int NPG  = 200;    // nodes per graph, stage 0
constexpr int EPER = 2000;   // edges per graph
constexpr int EMB  = 9;
constexpr int HID  = 128;
constexpr int K1   = 160;    // ceil(0.8*200)
constexpr int K2   = 128;    // ceil(0.8*160)
constexpr int K3   = 103;    // ceil(0.8*128)
constexpr int N0   = B * NPG;   // 102400
constexpr int N1   = B * K1;    // 81920
constexpr int N2   = B * K2;    // 65536
constexpr int E    = B * EPER;  // 1024000

// ---------------------------------------------------------------------------
// Fused stage 1 (one block per graph, 256 threads): gather emb -> LDS,
// CSR build in LDS, neighbor mean (thread-per-dst), conv1 scores, top-K1
// rank, conv1 recompute for kept nodes -> pooled write + global max/mean.
__global__ __launch_bounds__(256) void k_stage1(
        const int* __restrict__ node_ids,
        const float* __restrict__ emb,
        const int* __restrict__ es, const int* __restrict__ ed,
        const float* __restrict__ w1n, const float* __restrict__ w1r,
        const float* __restrict__ b1, const float* __restrict__ p1,
        float* __restrict__ xout,    // pooled output (N1 x HID)
        int* __restrict__ mapping,   // old node id -> new (or -1), N0
        float* __restrict__ gout) {  // B x 256 global-pool
    const int g = blockIdx.x, tid = threadIdx.x;
    __shared__ float x0L[NPG * EMB];
    __shared__ float mnL[NPG * EMB];
    __shared__ int   idsL[NPG];
    __shared__ int   deg[256];
    __shared__ int   off2[257];
    __shared__ int   cur[256];
    __shared__ int   csr[EPER];
    __shared__ float sc[NPG];
    __shared__ int   pos[NPG];
    __shared__ float redM[4 * 128], redS[4 * 128];

    if (tid < NPG) idsL[tid] = node_ids[g * NPG + tid];
    deg[tid] = 0;
    __syncthreads();
    for (int i = tid; i < NPG * EMB; i += 256) {
        int n = i / EMB, j = i - n * EMB;
        x0L[i] = emb[(size_t)idsL[n] * EMB + j];
    }
    const int ebase = g * EPER, nbase = g * NPG;
    int lsrc[8], ldst[8];
    #pragma unroll
    for (int q = 0; q < 8; q++) {
        int e = tid + q * 256;
        lsrc[q] = es[ebase + e] - nbase;
        ldst[q] = ed[ebase + e] - nbase;
        atomicAdd(&deg[ldst[q]], 1);
    }
    __syncthreads();
    cur[tid] = deg[tid];
    __syncthreads();
    #pragma unroll
    for (int d = 1; d < 256; d <<= 1) {
        int t = (tid >= d) ? cur[tid - d] : 0;
        __syncthreads();
        cur[tid] += t;
        __syncthreads();
    }
    if (tid == 0) off2[0] = 0;
    off2[tid + 1] = cur[tid];
    __syncthreads();
    cur[tid] = off2[tid];
    __syncthreads();
    #pragma unroll
    for (int q = 0; q < 8; q++) {
        int slot = atomicAdd(&cur[ldst[q]], 1);
        csr[slot] = lsrc[q];
    }
    __syncthreads();
    if (tid < NPG) {
        int bg = off2[tid], en = off2[tid + 1];
        float a[EMB];
        #pragma unroll
        for (int j = 0; j < EMB; j++) a[j] = 0.f;
        for (int t = bg; t < en; t++) {
            int s = csr[t];
            #pragma unroll
            for (int j = 0; j < EMB; j++) a[j] += x0L[s * EMB + j];
        }
        float inv = 1.f / (float)((en - bg) > 1 ? (en - bg) : 1);
        #pragma unroll
        for (int j = 0; j < EMB; j++) mnL[tid * EMB + j] = a[j] * inv;
    }
    const int lane = tid & 63, wv = tid >> 6;
    float pl0 = p1[lane], pl1 = p1[64 + lane];
    float pp = pl0 * pl0 + pl1 * pl1;
    #pragma unroll
    for (int o = 32; o >= 1; o >>= 1) pp += __shfl_xor(pp, o, 64);
    float nrm = sqrtf(pp);
    float wn0[EMB], wn1[EMB], wr0[EMB], wr1[EMB];
    #pragma unroll
    for (int j = 0; j < EMB; j++) {
        wn0[j] = w1n[lane * EMB + j];
        wn1[j] = w1n[(lane + 64) * EMB + j];
        wr0[j] = w1r[lane * EMB + j];
        wr1[j] = w1r[(lane + 64) * EMB + j];
    }
    float bb0 = b1[lane], bb1 = b1[64 + lane];
    __syncthreads();
    for (int i = wv; i < NPG; i += 4) {
        float c0 = bb0, c1 = bb1;
        #pragma unroll
        for (int j = 0; j < EMB; j++) {
            float m = mnL[i * EMB + j];
            float x = x0L[i * EMB + j];
            c0 += m * wn0[j] + x * wr0[j];
            c1 += m * wn1[j] + x * wr1[j];
        }
        c0 = fmaxf(c0, 0.f);
        c1 = fmaxf(c1, 0.f);
        float d = c0 * pl0 + c1 * pl1;
        #pragma unroll
        for (int o = 32; o >= 1; o >>= 1) d += __shfl_xor(d, o, 64);
        if (lane == 0) sc[i] = tanhf(d / nrm);
    }
    __syncthreads();
    if (tid < NPG) {
        float scv = sc[tid];
        int rank = 0;
        for (int j = 0; j < NPG; j++) {
            float o = sc[j];
            rank += (o > scv) || (o == scv && j < tid);
        }
        bool keep = rank < K1;
        pos[tid] = keep ? rank : -1;
        mapping[g * NPG + tid] = keep ? (g * K1 + rank) : -1;
    }
    __syncthreads();
    float pm0 = -INFINITY, pm1 = -INFINITY, ps0 = 0.f, ps1 = 0.f;
    for (int i = wv; i < NPG; i += 4) {
        int r = pos[i];
        if (r < 0) continue;
        float c0 = bb0, c1 = bb1;
        #pragma unroll
        for (int j = 0; j < EMB; j++) {
            float m = mnL[i * EMB + j];
            float x = x0L[i * EMB + j];
            c0 += m * wn0[j] + x * wr0[j];
            c1 += m * wn1[j] + x * wr1[j];
        }
        float s = sc[i];
        float v0 = fmaxf(c0, 0.f) * s;
        float v1 = fmaxf(c1, 0.f) * s;
        long rowp = (long)(g * K1 + r) * HID;
        xout[rowp + lane] = v0;
        xout[rowp + 64 + lane] = v1;
        pm0 = fmaxf(pm0, v0); ps0 += v0;
        pm1 = fmaxf(pm1, v1); ps1 += v1;
    }
    redM[wv * 128 + lane] = pm0;      redS[wv * 128 + lane] = ps0;
    redM[wv * 128 + 64 + lane] = pm1; redS[wv * 128 + 64 + lane] = ps1;
    __syncthreads();
    if (tid < 128) {
        float mx = redM[tid], sm = redS[tid];
        #pragma unroll
        for (int w2 = 1; w2 < 4; w2++) {
            mx = fmaxf(mx, redM[w2 * 128 + tid]);
            sm += redS[w2 * 128 + tid];
        }
        gout[g * 256 + tid] = mx;
        gout[g * 256 + 128 + tid] = sm / (float)K1;
    }
}

// ---------------------------------------------------------------------------
// Stage-2/3 aggregation, CSR-based, FUSED edge remap, LDS-staged features.
// One block per (graph, feature-half). Emits the MEAN directly.
__global__ __launch_bounds__(256) void k_aggcsr(const float* __restrict__ x,
                         const int* __restrict__ es,
                         const int* __restrict__ ed,
                         const int* __restrict__ map1,
                         const int* __restrict__ map2,   // may be null
                         int npc,
                         float* __restrict__ sout) {
    int g = blockIdx.x;
    int w = blockIdx.y;   // feature half (0/1)
    int tid = threadIdx.x;  // 256
    __shared__ float xL[K1 * 68];   // 43.5 KB (npc <= 160)
    __shared__ int deg[256];
    __shared__ int scanbuf[256];
    __shared__ int off[257];
    __shared__ int cur[256];
    __shared__ int csr[EPER];

    deg[tid] = 0;
    const int ebase = g * EPER;
    const int nbase = g * npc;
    const int hoff0 = w * 64;
    for (int i = tid; i < npc * 16; i += 256) {
        int r = i >> 4, c = (i & 15) * 4;
        *(float4*)&xL[r * 68 + c] =
            *(const float4*)(x + (long)(nbase + r) * HID + hoff0 + c);
    }
    __syncthreads();
    for (int e = tid; e < EPER; e += 256) {
        int a = map1[es[ebase + e]];
        int b = map1[ed[ebase + e]];
        if (map2) {
            a = (a >= 0) ? map2[a] : -1;
            b = (b >= 0) ? map2[b] : -1;
        }
        if (a >= 0 && b >= 0) atomicAdd(&deg[b - nbase], 1);
    }
    __syncthreads();
    int v = deg[tid];
    scanbuf[tid] = v;
    __syncthreads();
    #pragma unroll
    for (int d = 1; d < 256; d <<= 1) {
        int t = (tid >= d) ? scanbuf[tid - d] : 0;
        __syncthreads();
        scanbuf[tid] += t;
        __syncthreads();
    }
    if (tid == 0) off[0] = 0;
    off[tid + 1] = scanbuf[tid];
    __syncthreads();
    cur[tid] = off[tid];
    __syncthreads();
    for (int e = tid; e < EPER; e += 256) {
        int a = map1[es[ebase + e]];
        int b = map1[ed[ebase + e]];
        if (map2) {
            a = (a >= 0) ? map2[a] : -1;
            b = (b >= 0) ? map2[b] : -1;
        }
        if (a >= 0 && b >= 0) {
            int slot = atomicAdd(&cur[b - nbase], 1);
            csr[slot] = a - nbase;      // local row id
        }
    }
    __syncthreads();
    int lane = tid & 63, wv = tid >> 6;
    for (int dl = wv; dl < npc; dl += 4) {
        int beg = off[dl], end = off[dl + 1];
        float acc = 0.f, acc2 = 0.f;
        int t = beg;
        for (; t + 1 < end; t += 2) {
            acc  += xL[csr[t]     * 68 + lane];
            acc2 += xL[csr[t + 1] * 68 + lane];
        }
        if (t < end) acc += xL[csr[t] * 68 + lane];
        float inv = 1.f / (float)((end - beg) > 1 ? (end - beg) : 1);
        sout[(long)(nbase + dl) * HID + hoff0 + lane] = (acc + acc2) * inv;
    }
}

// ---------------------------------------------------------------------------
// Conv (K=256: concat [mean, x] vs [wn; wr]) + FUSED topk-pool + global
// max/mean pool, ONE GRAPH PER BLOCK (MROWS rows).
// r12: NTHR = 4*MROWS threads (640 / 512), 8x4 register tile per thread.
// Rationale: r10/r11 showed the 320-thread version latency-bound at 10
// waves/CU (VALUBusy 38%, occ 13.6%); doubling waves/CU to 20/16 gives the
// scheduler independent streams to hide LDS latency. LDS double-buffered
// (one barrier per chunk); 2 blocks/CU still fit (154/138 KB).
// K-loop addressing is the r4/r7 known-good k-major layout (do NOT
// XOR-swizzle: r5/r6 spill pathology). Tripwire: WRITE_SIZE must equal
// logical output; growth = spill = revert launch bounds.
template <int MROWS, int KKEEP, int MINW>
__global__ __launch_bounds__(MROWS * 4, MINW) void k_convpool(
        const float* __restrict__ s,    // mean, rows g*MROWS..
        const float* __restrict__ xin,  // prev pooled x, rows g*MROWS..
        const float* __restrict__ wn, const float* __restrict__ wr,
        const float* __restrict__ bb, const float* __restrict__ p,
        float* __restrict__ xout,       // may be null; rows g*KKEEP..
        int* __restrict__ mapping,      // may be null
        float* __restrict__ gout) {
    constexpr int GPA = (MROWS == 160) ? 164 : 132;
    constexpr int RST = MROWS / 2;   // A staging row stride (80 / 64)
    constexpr int TRM = MROWS / 8;   // 20 / 16
    __shared__ float As[2 * 32 * GPA];
    __shared__ float Bs[2 * 32 * 132];
    __shared__ float sc[MROWS];
    __shared__ int   pos[MROWS];
    __shared__ float nrmL;
    const int tid = threadIdx.x;
    const int g = blockIdx.x;
    const long row0 = (long)g * MROWS;
    const int tc = tid & 31, tr = tid >> 5;   // tr 0..TRM-1, tc 0..31
    const int srow = tid >> 3;                // 0..(MROWS/2-1)
    const int scol = (tid & 7) * 4;           // k-offset in chunk

    // ||p|| (wave 0)
    if (tid < 64) {
        float a = p[tid], b = p[64 + tid];
        float pp = a * a + b * b;
        #pragma unroll
        for (int o = 32; o >= 1; o >>= 1) pp += __shfl_xor(pp, o, 64);
        if (tid == 0) nrmL = sqrtf(pp);
    }

    float acc[8][4];
    #pragma unroll
    for (int r = 0; r < 8; r++)
        #pragma unroll
        for (int c = 0; c < 4; c++) acc[r][c] = 0.f;

    // prefetch chunk 0 (A: 2 iters of RST rows; B: threads srow<64, 2x64)
    float4 av[2], bv[2];
    #pragma unroll
    for (int i = 0; i < 2; i++)
        av[i] = *(const float4*)(s + (row0 + srow + i * RST) * HID + scol);
    if (srow < 64) {
        #pragma unroll
        for (int i = 0; i < 2; i++)
            bv[i] = *(const float4*)(wn + (size_t)(srow + i * 64) * HID + scol);
    }

    for (int ch = 0; ch < 8; ch++) {
        float* Ab = As + (ch & 1) * (32 * GPA);
        float* Bb = Bs + (ch & 1) * (32 * 132);
        #pragma unroll
        for (int i = 0; i < 2; i++) {
            int r = srow + i * RST;
            Ab[(scol + 0) * GPA + r] = av[i].x;
            Ab[(scol + 1) * GPA + r] = av[i].y;
            Ab[(scol + 2) * GPA + r] = av[i].z;
            Ab[(scol + 3) * GPA + r] = av[i].w;
        }
        if (srow < 64) {
            #pragma unroll
            for (int i = 0; i < 2; i++) {
                int r = srow + i * 64;
                Bb[(scol + 0) * 132 + r] = bv[i].x;
                Bb[(scol + 1) * 132 + r] = bv[i].y;
                Bb[(scol + 2) * 132 + r] = bv[i].z;
                Bb[(scol + 3) * 132 + r] = bv[i].w;
            }
        }
        __syncthreads();
        if (ch + 1 < 8) {
            const float* xs = (ch + 1 < 4) ? s : xin;
            const float* ws = (ch + 1 < 4) ? wn : wr;
            int kofs = ((ch + 1) & 3) * 32;
            #pragma unroll
            for (int i = 0; i < 2; i++)
                av[i] = *(const float4*)(xs + (row0 + srow + i * RST) * HID + kofs + scol);
            if (srow < 64) {
                #pragma unroll
                for (int i = 0; i < 2; i++)
                    bv[i] = *(const float4*)(ws + (size_t)(srow + i * 64) * HID + kofs + scol);
            }
        }
        #pragma unroll 2
        for (int k = 0; k < 32; k++) {
            float4 a0 = *(const float4*)&Ab[k * GPA + tr * 8];
            float4 a1 = *(const float4*)&Ab[k * GPA + tr * 8 + 4];
            float4 b0 = *(const float4*)&Bb[k * 132 + tc * 4];
            float a[8] = {a0.x, a0.y, a0.z, a0.w, a1.x, a1.y, a1.z, a1.w};
            float bb4[4] = {b0.x, b0.y, b0.z, b0.w};
            #pragma unroll
            for (int r = 0; r < 8; r++)
                #pragma unroll
                for (int c = 0; c < 4; c++) acc[r][c] += a[r] * bb4[c];
        }
        __syncthreads();
    }

    // --- epilogue: bias + relu into acc ---
    float bias[4], pv[4];
    #pragma unroll
    for (int cp = 0; cp < 4; cp++) {
        bias[cp] = bb[tc * 4 + cp];
        pv[cp]   = p[tc * 4 + cp];
    }
    #pragma unroll
    for (int rr = 0; rr < 8; rr++)
        #pragma unroll
        for (int cp = 0; cp < 4; cp++)
            acc[rr][cp] = fmaxf(acc[rr][cp] + bias[cp], 0.f);

    // --- score partials into LDS (overlay As buffer 0: MROWS*32 <= 32*GPA) ---
    float* scpart = As;
    #pragma unroll
    for (int rr = 0; rr < 8; rr++) {
        float sp = 0.f;
        #pragma unroll
        for (int cp = 0; cp < 4; cp++) sp += acc[rr][cp] * pv[cp];
        scpart[(tr * 8 + rr) * 32 + tc] = sp;
    }
    __syncthreads();
    if (tid < MROWS) {
        float sum = 0.f;
        #pragma unroll
        for (int t = 0; t < 32; t++) sum += scpart[tid * 32 + t];
        sc[tid] = tanhf(sum / nrmL);
    }
    __syncthreads();
    // --- rank (top_k: descending, lower index wins ties) ---
    if (tid < MROWS) {
        float scv = sc[tid];
        int rank = 0;
        for (int j = 0; j < MROWS; j++) {
            float o = sc[j];
            rank += (o > scv) || (o == scv && j < tid);
        }
        bool keep = rank < KKEEP;
        pos[tid] = keep ? rank : -1;
        if (mapping) mapping[g * MROWS + tid] = keep ? (g * KKEEP + rank) : -1;
    }
    __syncthreads();
    // --- pooled write + per-thread max/sum over kept rows ---
    float cm[4], cs[4];
    #pragma unroll
    for (int cp = 0; cp < 4; cp++) { cm[cp] = -INFINITY; cs[cp] = 0.f; }
    #pragma unroll
    for (int rr = 0; rr < 8; rr++) {
        int m = tr * 8 + rr;
        int r = pos[m];
        if (r < 0) continue;
        float sv = sc[m];
        float v[4];
        #pragma unroll
        for (int cp = 0; cp < 4; cp++) {
            v[cp] = acc[rr][cp] * sv;
            cm[cp] = fmaxf(cm[cp], v[cp]);
            cs[cp] += v[cp];
        }
        if (xout) {
            long rowp = ((long)g * KKEEP + r) * HID;
            float4 o0 = {v[0], v[1], v[2], v[3]};
            *(float4*)(xout + rowp + tc * 4) = o0;
        }
    }
    // redM/redS overlay the whole Bs region (2*32*132 = 8448 >= 2*TRM*128)
    float* redM = Bs;
    float* redS = Bs + TRM * 128;
    #pragma unroll
    for (int cp = 0; cp < 4; cp++) {
        int col = tc * 4 + cp;
        redM[tr * 128 + col] = cm[cp];
        redS[tr * 128 + col] = cs[cp];
    }
    __syncthreads();
    if (tid < 128) {
        float mx = redM[tid], sm = redS[tid];
        #pragma unroll 4
        for (int t = 1; t < TRM; t++) {
            mx = fmaxf(mx, redM[t * 128 + tid]);
            sm += redS[t * 128 + tid];
        }
        gout[g * 256 + tid] = mx;
        gout[g * 256 + 128 + tid] = sm / (float)KKEEP;
    }
}

// ---------------------------------------------------------------------------
// MLP head: h=g1+g2+g3; relu(h@lw1.T+lb1); relu(@lw2.T+lb2); sigmoid(@lw3.T+lb3)
__global__ __launch_bounds__(128) void k_mlp(const float* __restrict__ g1, const float* __restrict__ g2,
                      const float* __restrict__ g3,
                      const float* __restrict__ lw1, const float* __restrict__ lb1,
                      const float* __restrict__ lw2, const float* __restrict__ lb2,
                      const float* __restrict__ lw3, const float* __restrict__ lb3,
                      float* __restrict__ out) {
    int g = blockIdx.x, t = threadIdx.x;  // 128 threads
    __shared__ float h0[256];
    __shared__ float h1[128];
    __shared__ float h2r[64];
    h0[t]       = g1[g * 256 + t] + g2[g * 256 + t] + g3[g * 256 + t];
    h0[t + 128] = g1[g * 256 + 128 + t] + g2[g * 256 + 128 + t] + g3[g * 256 + 128 + t];
    __syncthreads();
    float a = lb1[t];
    #pragma unroll 4
    for (int j = 0; j < 256; j++) a += h0[j] * lw1[t * 256 + j];
    h1[t] = fmaxf(a, 0.f);
    __syncthreads();
    if (t < 64) {
        float a2 = lb2[t];
        #pragma unroll 4
        for (int j = 0; j < 128; j++) a2 += h1[j] * lw2[t * 128 + j];
        h2r[t] = fmaxf(a2, 0.f) * lw3[t];
    }
    __syncthreads();
    if (t == 0) {
        float s = 0.f;
        for (int j = 0; j < 64; j++) s += h2r[j];
        s += lb3[0];
        out[g] = 1.f / (1.f + expf(-s));
    }
}

// ---------------------------------------------------------------------------
extern "C" void kernel_launch(void* const* d_in, const int* in_sizes, int n_in,
                              void* d_out, int out_size, void* d_ws, size_t ws_size,
                              hipStream_t stream) {
    const int*   node_ids = (const int*)d_in[0];
    const int*   ei   = (const int*)d_in[1];   // edge_index (2, E)
    const float* emb  = (const float*)d_in[3];
    const float* w1n  = (const float*)d_in[4];
    const float* w1r  = (const float*)d_in[5];
    const float* b1   = (const float*)d_in[6];
    const float* w2n  = (const float*)d_in[7];
    const float* w2r  = (const float*)d_in[8];
    const float* b2   = (const float*)d_in[9];
    const float* w3n  = (const float*)d_in[10];
    const float* w3r  = (const float*)d_in[11];
    const float* b3   = (const float*)d_in[12];
    const float* p1   = (const float*)d_in[13];
    const float* p2   = (const float*)d_in[14];
    const float* p3   = (const float*)d_in[15];
    const float* lw1  = (const float*)d_in[16];
    const float* lb1  = (const float*)d_in[17];
    const float* lw2  = (const float*)d_in[18];
    const float* lb2  = (const float*)d_in[19];
    const float* lw3  = (const float*)d_in[20];
    const float* lb3  = (const float*)d_in[21];
    float* out = (float*)d_out;

    // Workspace layout (floats): ~120 MB total.
    float* ws  = (float*)d_ws;
    float* C   = ws;                           // N1*HID  (mean2 / mean3)
    float* D   = C + (size_t)N1 * HID;         // N1*HID  (x1p)
    float* D2  = D + (size_t)N1 * HID;         // N2*HID  (x2p) - fresh buffer:
                                               // in-place would race across blocks
    float* g1  = D2 + (size_t)N2 * HID;        // B*256
    float* g2  = g1 + B * 2 * HID;             // B*256
    float* g3  = g2 + B * 2 * HID;             // B*256
    int* map1  = (int*)(g3 + B * 2 * HID);     // N0
    int* map2  = map1 + N0;                    // N1

    // ---- Stage 1 (EMB -> HID), fully fused per graph ----
    k_stage1<<<B, 256, 0, stream>>>(node_ids, emb, ei, ei + E,
                                    w1n, w1r, b1, p1, D, map1, g1);

    // ---- Stage 2: agg (mean2 into C) then conv+pool fused ----
    k_aggcsr<<<dim3(B, 2), 256, 0, stream>>>(D, ei, ei + E, map1, nullptr, K1, C);
    k_convpool<K1, K2, 5><<<B, K1 * 4, 0, stream>>>(C, D, w2n, w2r, b2, p2,
                                                    D2, map2, g2);

    // ---- Stage 3: agg (mean3 into C) then conv+pool fused (gout only) ----
    k_aggcsr<<<dim3(B, 2), 256, 0, stream>>>(D2, ei, ei + E, map1, map2, K2, C);
    k_convpool<K2, K3, 4><<<B, K2 * 4, 0, stream>>>(C, D2, w3n, w3r, b3, p3,
                                                    nullptr, nullptr, g3);

    // ---- Head ----
    k_mlp<<<B, 128, 0, stream>>>(g1, g2, g3, lw1, lb1, lw2, lb2, lw3, lb3, out);
}

// Round 13
// 379.062 us; speedup vs baseline: 1.9221x; 1.1678x over previous
//
#include <hip/hip_runtime.h>
#include <math.h>

// Problem constants (from reference)
constexpr int B    = 512;
constexpr int NPG  = 200;    // nodes per graph, stage 0
constexpr int EPER = 2000;   // edges per graph
constexpr int EMB  = 9;
constexpr int HID  = 128;
constexpr int K1   = 160;    // ceil(0.8*200)
constexpr int K2   = 128;    // ceil(0.8*160)
constexpr int K3   = 103;    // ceil(0.8*128)
constexpr int N0   = B * NPG;   // 102400
constexpr int N1   = B * K1;    // 81920
constexpr int N2   = B * K2;    // 65536
constexpr int E    = B * EPER;  // 1024000

// ---------------------------------------------------------------------------
// Fused stage 1 (one block per graph, 256 threads): gather emb -> LDS,
// CSR build in LDS, neighbor mean (thread-per-dst), conv1 scores, top-K1
// rank, conv1 recompute for kept nodes -> pooled write + global max/mean.
__global__ __launch_bounds__(256) void k_stage1(
        const int* __restrict__ node_ids,
        const float* __restrict__ emb,
        const int* __restrict__ es, const int* __restrict__ ed,
        const float* __restrict__ w1n, const float* __restrict__ w1r,
        const float* __restrict__ b1, const float* __restrict__ p1,
        float* __restrict__ xout,    // pooled output (N1 x HID)
        int* __restrict__ mapping,   // old node id -> new (or -1), N0
        float* __restrict__ gout) {  // B x 256 global-pool
    const int g = blockIdx.x, tid = threadIdx.x;
    __shared__ float x0L[NPG * EMB];
    __shared__ float mnL[NPG * EMB];
    __shared__ int   idsL[NPG];
    __shared__ int   deg[256];
    __shared__ int   off2[257];
    __shared__ int   cur[256];
    __shared__ int   csr[EPER];
    __shared__ float sc[NPG];
    __shared__ int   pos[NPG];
    __shared__ float redM[4 * 128], redS[4 * 128];

    if (tid < NPG) idsL[tid] = node_ids[g * NPG + tid];
    deg[tid] = 0;
    __syncthreads();
    for (int i = tid; i < NPG * EMB; i += 256) {
        int n = i / EMB, j = i - n * EMB;
        x0L[i] = emb[(size_t)idsL[n] * EMB + j];
    }
    const int ebase = g * EPER, nbase = g * NPG;
    int lsrc[8], ldst[8];
    #pragma unroll
    for (int q = 0; q < 8; q++) {
        int e = tid + q * 256;
        lsrc[q] = es[ebase + e] - nbase;
        ldst[q] = ed[ebase + e] - nbase;
        atomicAdd(&deg[ldst[q]], 1);
    }
    __syncthreads();
    cur[tid] = deg[tid];
    __syncthreads();
    #pragma unroll
    for (int d = 1; d < 256; d <<= 1) {
        int t = (tid >= d) ? cur[tid - d] : 0;
        __syncthreads();
        cur[tid] += t;
        __syncthreads();
    }
    if (tid == 0) off2[0] = 0;
    off2[tid + 1] = cur[tid];
    __syncthreads();
    cur[tid] = off2[tid];
    __syncthreads();
    #pragma unroll
    for (int q = 0; q < 8; q++) {
        int slot = atomicAdd(&cur[ldst[q]], 1);
        csr[slot] = lsrc[q];
    }
    __syncthreads();
    if (tid < NPG) {
        int bg = off2[tid], en = off2[tid + 1];
        float a[EMB];
        #pragma unroll
        for (int j = 0; j < EMB; j++) a[j] = 0.f;
        for (int t = bg; t < en; t++) {
            int s = csr[t];
            #pragma unroll
            for (int j = 0; j < EMB; j++) a[j] += x0L[s * EMB + j];
        }
        float inv = 1.f / (float)((en - bg) > 1 ? (en - bg) : 1);
        #pragma unroll
        for (int j = 0; j < EMB; j++) mnL[tid * EMB + j] = a[j] * inv;
    }
    const int lane = tid & 63, wv = tid >> 6;
    float pl0 = p1[lane], pl1 = p1[64 + lane];
    float pp = pl0 * pl0 + pl1 * pl1;
    #pragma unroll
    for (int o = 32; o >= 1; o >>= 1) pp += __shfl_xor(pp, o, 64);
    float nrm = sqrtf(pp);
    float wn0[EMB], wn1[EMB], wr0[EMB], wr1[EMB];
    #pragma unroll
    for (int j = 0; j < EMB; j++) {
        wn0[j] = w1n[lane * EMB + j];
        wn1[j] = w1n[(lane + 64) * EMB + j];
        wr0[j] = w1r[lane * EMB + j];
        wr1[j] = w1r[(lane + 64) * EMB + j];
    }
    float bb0 = b1[lane], bb1 = b1[64 + lane];
    __syncthreads();
    for (int i = wv; i < NPG; i += 4) {
        float c0 = bb0, c1 = bb1;
        #pragma unroll
        for (int j = 0; j < EMB; j++) {
            float m = mnL[i * EMB + j];
            float x = x0L[i * EMB + j];
            c0 += m * wn0[j] + x * wr0[j];
            c1 += m * wn1[j] + x * wr1[j];
        }
        c0 = fmaxf(c0, 0.f);
        c1 = fmaxf(c1, 0.f);
        float d = c0 * pl0 + c1 * pl1;
        #pragma unroll
        for (int o = 32; o >= 1; o >>= 1) d += __shfl_xor(d, o, 64);
        if (lane == 0) sc[i] = tanhf(d / nrm);
    }
    __syncthreads();
    if (tid < NPG) {
        float scv = sc[tid];
        int rank = 0;
        for (int j = 0; j < NPG; j++) {
            float o = sc[j];
            rank += (o > scv) || (o == scv && j < tid);
        }
        bool keep = rank < K1;
        pos[tid] = keep ? rank : -1;
        mapping[g * NPG + tid] = keep ? (g * K1 + rank) : -1;
    }
    __syncthreads();
    float pm0 = -INFINITY, pm1 = -INFINITY, ps0 = 0.f, ps1 = 0.f;
    for (int i = wv; i < NPG; i += 4) {
        int r = pos[i];
        if (r < 0) continue;
        float c0 = bb0, c1 = bb1;
        #pragma unroll
        for (int j = 0; j < EMB; j++) {
            float m = mnL[i * EMB + j];
            float x = x0L[i * EMB + j];
            c0 += m * wn0[j] + x * wr0[j];
            c1 += m * wn1[j] + x * wr1[j];
        }
        float s = sc[i];
        float v0 = fmaxf(c0, 0.f) * s;
        float v1 = fmaxf(c1, 0.f) * s;
        long rowp = (long)(g * K1 + r) * HID;
        xout[rowp + lane] = v0;
        xout[rowp + 64 + lane] = v1;
        pm0 = fmaxf(pm0, v0); ps0 += v0;
        pm1 = fmaxf(pm1, v1); ps1 += v1;
    }
    redM[wv * 128 + lane] = pm0;      redS[wv * 128 + lane] = ps0;
    redM[wv * 128 + 64 + lane] = pm1; redS[wv * 128 + 64 + lane] = ps1;
    __syncthreads();
    if (tid < 128) {
        float mx = redM[tid], sm = redS[tid];
        #pragma unroll
        for (int w2 = 1; w2 < 4; w2++) {
            mx = fmaxf(mx, redM[w2 * 128 + tid]);
            sm += redS[w2 * 128 + tid];
        }
        gout[g * 256 + tid] = mx;
        gout[g * 256 + 128 + tid] = sm / (float)K1;
    }
}

// ---------------------------------------------------------------------------
// Fused stage 2/3: agg + conv + topk-pool + global-pool, ONE GRAPH PER BLOCK.
// Linearity trick: mean(x_src)@Wn^T == mean over src of (x@Wn^T). So:
//   1. stage the graph's x block (MROWS x 128) into LDS (xY, pitch 132)
//   2. build CSR (raw edges + map chain) in LDS
//   3. GEMM Y = x@wn^T, Z = x@wr^T: A read DIRECTLY from resident xY
//      (no staging, no K-loop global traffic); weights staged per 32-k
//      chunk in the r4-verified k-major transposed layout (do NOT
//      XOR-swizzle: r5/r6 spill pathology)
//   4. overwrite xY with Y; out = meanY(CSR) + Z + b -> relu
//   5. r12 epilogue: scores -> rank -> pooled write + global max/mean.
// LDS ~132/115 KB -> 1 block/CU, 10/8 waves. Tripwire: WRITE_SIZE must be
// ~= logical outputs (28 MB stage2); growth = spill = loosen bounds.
template <int MROWS, int KKEEP, int NTHR, int MINW>
__global__ __launch_bounds__(NTHR, MINW) void k_stage23(
        const float* __restrict__ xin,   // rows g*MROWS..
        const int* __restrict__ es, const int* __restrict__ ed,
        const int* __restrict__ map1,
        const int* __restrict__ map2,    // may be null (stage 2)
        const float* __restrict__ wn, const float* __restrict__ wr,
        const float* __restrict__ bb, const float* __restrict__ p,
        float* __restrict__ xout,        // may be null; rows g*KKEEP..
        int* __restrict__ mapout,        // may be null
        float* __restrict__ gout) {
    constexpr int TRM = MROWS / 8;   // 20 / 16 == NTHR/32
    __shared__ float xY[MROWS * 132];      // x block, later Y block
    __shared__ float Bw[2 * 32 * 132];     // wn-chunk | wr-chunk (k-major)
    __shared__ int   csr[EPER];
    __shared__ int   deg[256], scanb[256], off2[257], cur[256];
    __shared__ float sc[MROWS];
    __shared__ int   pos[MROWS];
    __shared__ float nrmL;

    const int tid = threadIdx.x;
    const int g = blockIdx.x;
    const long row0 = (long)g * MROWS;
    const int tc = tid & 31, tr = tid >> 5;   // tr in [0, TRM)

    // --- stage x block into LDS (coalesced float4) ---
    for (int i = tid; i < MROWS * 32; i += NTHR) {
        int r = i >> 5, c = (i & 31) * 4;
        *(float4*)&xY[r * 132 + c] =
            *(const float4*)(xin + (row0 + r) * HID + c);
    }
    // --- CSR build (raw edges + map chain) ---
    if (tid < 256) deg[tid] = 0;
    __syncthreads();
    const int ebase = g * EPER, nbase = g * MROWS;
    for (int e = tid; e < EPER; e += NTHR) {
        int a = map1[es[ebase + e]];
        int b = map1[ed[ebase + e]];
        if (map2) {
            a = (a >= 0) ? map2[a] : -1;
            b = (b >= 0) ? map2[b] : -1;
        }
        if (a >= 0 && b >= 0) atomicAdd(&deg[b - nbase], 1);
    }
    __syncthreads();
    if (tid < 256) scanb[tid] = deg[tid];
    __syncthreads();
    #pragma unroll
    for (int d = 1; d < 256; d <<= 1) {
        int t = (tid < 256 && tid >= d) ? scanb[tid - d] : 0;
        __syncthreads();
        if (tid < 256) scanb[tid] += t;
        __syncthreads();
    }
    if (tid == 0) off2[0] = 0;
    if (tid < 256) off2[tid + 1] = scanb[tid];
    __syncthreads();
    if (tid < 256) cur[tid] = off2[tid];
    __syncthreads();
    for (int e = tid; e < EPER; e += NTHR) {
        int a = map1[es[ebase + e]];
        int b = map1[ed[ebase + e]];
        if (map2) {
            a = (a >= 0) ? map2[a] : -1;
            b = (b >= 0) ? map2[b] : -1;
        }
        if (a >= 0 && b >= 0) {
            int slot = atomicAdd(&cur[b - nbase], 1);
            csr[slot] = a - nbase;       // local row id
        }
    }
    // ||p|| (wave 0, no LDS dependency)
    if (tid < 64) {
        float a = p[tid], b2 = p[64 + tid];
        float pp = a * a + b2 * b2;
        #pragma unroll
        for (int o = 32; o >= 1; o >>= 1) pp += __shfl_xor(pp, o, 64);
        if (tid == 0) nrmL = sqrtf(pp);
    }
    __syncthreads();   // xY + csr ready

    // --- GEMM: Y = x@wn^T, Z = x@wr^T (K=128 in 4 chunks of 32) ---
    float accY[8][4], accZ[8][4];
    #pragma unroll
    for (int r = 0; r < 8; r++)
        #pragma unroll
        for (int c = 0; c < 4; c++) { accY[r][c] = 0.f; accZ[r][c] = 0.f; }

    const int sr = tid >> 3, sc4 = (tid & 7) * 4;
    const bool stager = (sr < 64);
    const float* wsrc0 = (sr < 32) ? wn : wr;
    const int wrow = (sr < 32) ? sr : sr - 32;
    float* Bmine = Bw + ((sr < 32) ? 0 : 32 * 132);
    float4 bvv[4];
    if (stager) {
        #pragma unroll
        for (int i = 0; i < 4; i++)
            bvv[i] = *(const float4*)(wsrc0 + (size_t)(wrow + i * 32) * HID + sc4);
    }
    for (int ch = 0; ch < 4; ch++) {
        if (stager) {
            #pragma unroll
            for (int i = 0; i < 4; i++) {
                int r = wrow + i * 32;
                Bmine[(sc4 + 0) * 132 + r] = bvv[i].x;
                Bmine[(sc4 + 1) * 132 + r] = bvv[i].y;
                Bmine[(sc4 + 2) * 132 + r] = bvv[i].z;
                Bmine[(sc4 + 3) * 132 + r] = bvv[i].w;
            }
        }
        __syncthreads();
        if (ch + 1 < 4 && stager) {
            #pragma unroll
            for (int i = 0; i < 4; i++)
                bvv[i] = *(const float4*)(wsrc0 + (size_t)(wrow + i * 32) * HID
                                          + (ch + 1) * 32 + sc4);
        }
        for (int kq = 0; kq < 8; kq++) {
            float4 af[8];
            #pragma unroll
            for (int rr = 0; rr < 8; rr++)
                af[rr] = *(const float4*)&xY[(tr * 8 + rr) * 132 + ch * 32 + kq * 4];
            #pragma unroll
            for (int kk = 0; kk < 4; kk++) {
                int k = kq * 4 + kk;
                float4 bn = *(const float4*)&Bw[k * 132 + tc * 4];
                float4 br = *(const float4*)&Bw[32 * 132 + k * 132 + tc * 4];
                #pragma unroll
                for (int rr = 0; rr < 8; rr++) {
                    float a = (kk == 0) ? af[rr].x : (kk == 1) ? af[rr].y
                             : (kk == 2) ? af[rr].z : af[rr].w;
                    accY[rr][0] += a * bn.x; accY[rr][1] += a * bn.y;
                    accY[rr][2] += a * bn.z; accY[rr][3] += a * bn.w;
                    accZ[rr][0] += a * br.x; accZ[rr][1] += a * br.y;
                    accZ[rr][2] += a * br.z; accZ[rr][3] += a * br.w;
                }
            }
        }
        __syncthreads();
    }

    // --- overwrite xY with Y ---
    #pragma unroll
    for (int rr = 0; rr < 8; rr++) {
        float4 yv = {accY[rr][0], accY[rr][1], accY[rr][2], accY[rr][3]};
        *(float4*)&xY[(tr * 8 + rr) * 132 + tc * 4] = yv;
    }
    __syncthreads();

    // --- out = meanY + Z + b -> relu ---
    float bias[4], pv[4];
    #pragma unroll
    for (int c = 0; c < 4; c++) {
        bias[c] = bb[tc * 4 + c];
        pv[c]   = p[tc * 4 + c];
    }
    float outv[8][4];
    #pragma unroll
    for (int rr = 0; rr < 8; rr++) {
        int m = tr * 8 + rr;
        int bg = off2[m], en = off2[m + 1];
        float s0 = 0.f, s1 = 0.f, s2 = 0.f, s3 = 0.f;
        for (int t = bg; t < en; t++) {
            float4 yv = *(const float4*)&xY[csr[t] * 132 + tc * 4];
            s0 += yv.x; s1 += yv.y; s2 += yv.z; s3 += yv.w;
        }
        float inv = 1.f / (float)((en - bg) > 1 ? (en - bg) : 1);
        outv[rr][0] = fmaxf(s0 * inv + accZ[rr][0] + bias[0], 0.f);
        outv[rr][1] = fmaxf(s1 * inv + accZ[rr][1] + bias[1], 0.f);
        outv[rr][2] = fmaxf(s2 * inv + accZ[rr][2] + bias[2], 0.f);
        outv[rr][3] = fmaxf(s3 * inv + accZ[rr][3] + bias[3], 0.f);
    }

    // --- scores (fixed-order reduce over 32 partials) ---
    float* scpart = Bw;   // MROWS*32 <= 8448
    #pragma unroll
    for (int rr = 0; rr < 8; rr++) {
        float sp = outv[rr][0] * pv[0] + outv[rr][1] * pv[1]
                 + outv[rr][2] * pv[2] + outv[rr][3] * pv[3];
        scpart[(tr * 8 + rr) * 32 + tc] = sp;
    }
    __syncthreads();
    if (tid < MROWS) {
        float sum = 0.f;
        #pragma unroll
        for (int t = 0; t < 32; t++) sum += scpart[tid * 32 + t];
        sc[tid] = tanhf(sum / nrmL);
    }
    __syncthreads();
    // --- rank (top_k: descending, lower index wins ties) ---
    if (tid < MROWS) {
        float scv = sc[tid];
        int rank = 0;
        for (int j = 0; j < MROWS; j++) {
            float o = sc[j];
            rank += (o > scv) || (o == scv && j < tid);
        }
        bool keep = rank < KKEEP;
        pos[tid] = keep ? rank : -1;
        if (mapout) mapout[g * MROWS + tid] = keep ? (g * KKEEP + rank) : -1;
    }
    __syncthreads();
    // --- pooled write + per-thread max/sum over kept rows ---
    float cm[4], cs[4];
    #pragma unroll
    for (int c = 0; c < 4; c++) { cm[c] = -INFINITY; cs[c] = 0.f; }
    #pragma unroll
    for (int rr = 0; rr < 8; rr++) {
        int m = tr * 8 + rr;
        int r = pos[m];
        if (r < 0) continue;
        float sv = sc[m];
        float v0 = outv[rr][0] * sv, v1 = outv[rr][1] * sv;
        float v2 = outv[rr][2] * sv, v3 = outv[rr][3] * sv;
        cm[0] = fmaxf(cm[0], v0); cs[0] += v0;
        cm[1] = fmaxf(cm[1], v1); cs[1] += v1;
        cm[2] = fmaxf(cm[2], v2); cs[2] += v2;
        cm[3] = fmaxf(cm[3], v3); cs[3] += v3;
        if (xout) {
            float4 o0 = {v0, v1, v2, v3};
            *(float4*)(xout + ((long)g * KKEEP + r) * HID + tc * 4) = o0;
        }
    }
    float* redM = Bw;                    // TRM*128 (scpart dead past barrier)
    float* redS = Bw + TRM * 128;
    #pragma unroll
    for (int c = 0; c < 4; c++) {
        redM[tr * 128 + tc * 4 + c] = cm[c];
        redS[tr * 128 + tc * 4 + c] = cs[c];
    }
    __syncthreads();
    if (tid < 128) {
        float mx = redM[tid], sm = redS[tid];
        #pragma unroll 4
        for (int t = 1; t < TRM; t++) {
            mx = fmaxf(mx, redM[t * 128 + tid]);
            sm += redS[t * 128 + tid];
        }
        gout[g * 256 + tid] = mx;
        gout[g * 256 + 128 + tid] = sm / (float)KKEEP;
    }
}

// ---------------------------------------------------------------------------
// MLP head: h=g1+g2+g3; relu(h@lw1.T+lb1); relu(@lw2.T+lb2); sigmoid(@lw3.T+lb3)
__global__ __launch_bounds__(128) void k_mlp(const float* __restrict__ g1, const float* __restrict__ g2,
                      const float* __restrict__ g3,
                      const float* __restrict__ lw1, const float* __restrict__ lb1,
                      const float* __restrict__ lw2, const float* __restrict__ lb2,
                      const float* __restrict__ lw3, const float* __restrict__ lb3,
                      float* __restrict__ out) {
    int g = blockIdx.x, t = threadIdx.x;  // 128 threads
    __shared__ float h0[256];
    __shared__ float h1[128];
    __shared__ float h2r[64];
    h0[t]       = g1[g * 256 + t] + g2[g * 256 + t] + g3[g * 256 + t];
    h0[t + 128] = g1[g * 256 + 128 + t] + g2[g * 256 + 128 + t] + g3[g * 256 + 128 + t];
    __syncthreads();
    float a = lb1[t];
    #pragma unroll 4
    for (int j = 0; j < 256; j++) a += h0[j] * lw1[t * 256 + j];
    h1[t] = fmaxf(a, 0.f);
    __syncthreads();
    if (t < 64) {
        float a2 = lb2[t];
        #pragma unroll 4
        for (int j = 0; j < 128; j++) a2 += h1[j] * lw2[t * 128 + j];
        h2r[t] = fmaxf(a2, 0.f) * lw3[t];
    }
    __syncthreads();
    if (t == 0) {
        float s = 0.f;
        for (int j = 0; j < 64; j++) s += h2r[j];
        s += lb3[0];
        out[g] = 1.f / (1.f + expf(-s));
    }
}

// ---------------------------------------------------------------------------
extern "C" void kernel_launch(void* const* d_in, const int* in_sizes, int n_in,
                              void* d_out, int out_size, void* d_ws, size_t ws_size,
                              hipStream_t stream) {
    const int*   node_ids = (const int*)d_in[0];
    const int*   ei   = (const int*)d_in[1];   // edge_index (2, E)
    const float* emb  = (const float*)d_in[3];
    const float* w1n  = (const float*)d_in[4];
    const float* w1r  = (const float*)d_in[5];
    const float* b1   = (const float*)d_in[6];
    const float* w2n  = (const float*)d_in[7];
    const float* w2r  = (const float*)d_in[8];
    const float* b2   = (const float*)d_in[9];
    const float* w3n  = (const float*)d_in[10];
    const float* w3r  = (const float*)d_in[11];
    const float* b3   = (const float*)d_in[12];
    const float* p1   = (const float*)d_in[13];
    const float* p2   = (const float*)d_in[14];
    const float* p3   = (const float*)d_in[15];
    const float* lw1  = (const float*)d_in[16];
    const float* lb1  = (const float*)d_in[17];
    const float* lw2  = (const float*)d_in[18];
    const float* lb2  = (const float*)d_in[19];
    const float* lw3  = (const float*)d_in[20];
    const float* lb3  = (const float*)d_in[21];
    float* out = (float*)d_out;

    // Workspace layout (floats).
    float* ws  = (float*)d_ws;
    float* D   = ws;                           // N1*HID  (x1p)
    float* D2  = D + (size_t)N1 * HID;         // N2*HID  (x2p)
    float* g1  = D2 + (size_t)N2 * HID;        // B*256
    float* g2  = g1 + B * 2 * HID;             // B*256
    float* g3  = g2 + B * 2 * HID;             // B*256
    int* map1  = (int*)(g3 + B * 2 * HID);     // N0
    int* map2  = map1 + N0;                    // N1

    // ---- Stage 1 (EMB -> HID), fully fused per graph ----
    k_stage1<<<B, 256, 0, stream>>>(node_ids, emb, ei, ei + E,
                                    w1n, w1r, b1, p1, D, map1, g1);

    // ---- Stage 2: agg+conv+pool fully fused, one graph per block ----
    k_stage23<K1, K2, 640, 3><<<B, 640, 0, stream>>>(
        D, ei, ei + E, map1, nullptr, w2n, w2r, b2, p2, D2, map2, g2);

    // ---- Stage 3: agg+conv+pool fully fused (gout only) ----
    k_stage23<K2, K3, 512, 2><<<B, 512, 0, stream>>>(
        D2, ei, ei + E, map1, map2, w3n, w3r, b3, p3, nullptr, nullptr, g3);

    // ---- Head ----
    k_mlp<<<B, 128, 0, stream>>>(g1, g2, g3, lw1, lb1, lw2, lb2, lw3, lb3, out);
}

// Round 14
// 364.334 us; speedup vs baseline: 1.9998x; 1.0404x over previous
//
#include <hip/hip_runtime.h>
#include <math.h>

// Problem constants (from reference)
constexpr int B    = 512;
constexpr int NPG  = 200;    // nodes per graph, stage 0
constexpr int EPER = 2000;   // edges per graph
constexpr int EMB  = 9;
constexpr int HID  = 128;
constexpr int K1   = 160;    // ceil(0.8*200)
constexpr int K2   = 128;    // ceil(0.8*160)
constexpr int K3   = 103;    // ceil(0.8*128)
constexpr int E    = B * EPER;  // 1024000

// ---------------------------------------------------------------------------
// ONE KERNEL for all three GNN stages, one graph per block (640 threads).
// All intermediates (x1p, x2p, Y) live in LDS (xY, 160x132); only g1/g2/g3
// (1.5 MB total) are written to global. Edge remap via LDS pos1/pos2 (no
// global map arrays). GEMM K-loop layout is the r4/r7/r13-verified k-major
// transposed form (do NOT XOR-swizzle: r5/r6 spill pathology).
// Phases:
//   A: emb gather -> CSR -> neighbor mean -> conv1 scores -> rank -> conv1
//      recompute kept -> x1p into xY + g1.
//   B: CSR (pos1 remap) -> Y=x@w2n^T,Z=x@w2r^T (A resident in xY) ->
//      Y overwrites xY -> out=meanY+Z+b -> scores -> rank(pos2) ->
//      pooled rows written back into xY rows 0..127 + g2.
//   C: CSR (pos1∘pos2) -> same with w3, 512 compute threads -> g3 only.
__global__ __launch_bounds__(640, 2) void k_fused(
        const int* __restrict__ node_ids,
        const float* __restrict__ emb,
        const int* __restrict__ es, const int* __restrict__ ed,
        const float* __restrict__ w1n, const float* __restrict__ w1r,
        const float* __restrict__ b1, const float* __restrict__ p1,
        const float* __restrict__ w2n, const float* __restrict__ w2r,
        const float* __restrict__ b2, const float* __restrict__ p2,
        const float* __restrict__ w3n, const float* __restrict__ w3r,
        const float* __restrict__ b3, const float* __restrict__ p3,
        float* __restrict__ g1, float* __restrict__ g2,
        float* __restrict__ g3) {
    const int g = blockIdx.x, tid = threadIdx.x;
    const int lane = tid & 63, wv = tid >> 6;   // 10 waves

    __shared__ float xY[K1 * 132];              // 84.5 KB: x1p -> Y -> x2p -> Y3
    __shared__ float S[2 * 32 * 132];           // 33.8 KB scratch union
    __shared__ int   csr[EPER];                 // 8 KB
    __shared__ int   deg[256], scanb[256], off2[257], cur[256];
    __shared__ int   idsL[NPG];                 // reused as posC in phase C
    __shared__ float sc[NPG];
    __shared__ int   pos1[NPG], pos2[K1];

    const int eb = g * EPER, nb0 = g * NPG;

    // ======================= Phase A: stage 1 =======================
    {
        float* x0L  = S;          // 1800
        float* mnL  = S + 1800;   // 1800
        float* redA = S + 3600;   // 2560 = 10*128*2
        if (tid < NPG) idsL[tid] = node_ids[g * NPG + tid];
        if (tid < 256) deg[tid] = 0;
        __syncthreads();
        for (int i = tid; i < NPG * EMB; i += 640) {
            int n = i / EMB, j = i - n * EMB;
            x0L[i] = emb[(size_t)idsL[n] * EMB + j];
        }
        for (int e = tid; e < EPER; e += 640)
            atomicAdd(&deg[ed[eb + e] - nb0], 1);
        __syncthreads();
        if (tid < 256) scanb[tid] = deg[tid];
        __syncthreads();
        #pragma unroll
        for (int d = 1; d < 256; d <<= 1) {
            int t = (tid < 256 && tid >= d) ? scanb[tid - d] : 0;
            __syncthreads();
            if (tid < 256) scanb[tid] += t;
            __syncthreads();
        }
        if (tid == 0) off2[0] = 0;
        if (tid < 256) off2[tid + 1] = scanb[tid];
        __syncthreads();
        if (tid < 256) cur[tid] = off2[tid];
        __syncthreads();
        for (int e = tid; e < EPER; e += 640) {
            int slot = atomicAdd(&cur[ed[eb + e] - nb0], 1);
            csr[slot] = es[eb + e] - nb0;
        }
        __syncthreads();
        if (tid < NPG) {
            int bg = off2[tid], en = off2[tid + 1];
            float a[EMB];
            #pragma unroll
            for (int j = 0; j < EMB; j++) a[j] = 0.f;
            for (int t = bg; t < en; t++) {
                int s = csr[t];
                #pragma unroll
                for (int j = 0; j < EMB; j++) a[j] += x0L[s * EMB + j];
            }
            float inv = 1.f / (float)((en - bg) > 1 ? (en - bg) : 1);
            #pragma unroll
            for (int j = 0; j < EMB; j++) mnL[tid * EMB + j] = a[j] * inv;
        }
        float pl0 = p1[lane], pl1 = p1[64 + lane];
        float pp = pl0 * pl0 + pl1 * pl1;
        #pragma unroll
        for (int o = 32; o >= 1; o >>= 1) pp += __shfl_xor(pp, o, 64);
        float nrm = sqrtf(pp);
        float wn0[EMB], wn1[EMB], wr0[EMB], wr1[EMB];
        #pragma unroll
        for (int j = 0; j < EMB; j++) {
            wn0[j] = w1n[lane * EMB + j];
            wn1[j] = w1n[(lane + 64) * EMB + j];
            wr0[j] = w1r[lane * EMB + j];
            wr1[j] = w1r[(lane + 64) * EMB + j];
        }
        float bb0 = b1[lane], bb1 = b1[64 + lane];
        __syncthreads();
        for (int i = wv; i < NPG; i += 10) {
            float c0 = bb0, c1 = bb1;
            #pragma unroll
            for (int j = 0; j < EMB; j++) {
                float m = mnL[i * EMB + j];
                float x = x0L[i * EMB + j];
                c0 += m * wn0[j] + x * wr0[j];
                c1 += m * wn1[j] + x * wr1[j];
            }
            c0 = fmaxf(c0, 0.f);
            c1 = fmaxf(c1, 0.f);
            float d = c0 * pl0 + c1 * pl1;
            #pragma unroll
            for (int o = 32; o >= 1; o >>= 1) d += __shfl_xor(d, o, 64);
            if (lane == 0) sc[i] = tanhf(d / nrm);
        }
        __syncthreads();
        if (tid < NPG) {
            float scv = sc[tid];
            int rank = 0;
            for (int j = 0; j < NPG; j++) {
                float o = sc[j];
                rank += (o > scv) || (o == scv && j < tid);
            }
            pos1[tid] = (rank < K1) ? rank : -1;
        }
        __syncthreads();
        float pm0 = -INFINITY, pm1 = -INFINITY, ps0 = 0.f, ps1 = 0.f;
        for (int i = wv; i < NPG; i += 10) {
            int r = pos1[i];
            if (r < 0) continue;
            float c0 = bb0, c1 = bb1;
            #pragma unroll
            for (int j = 0; j < EMB; j++) {
                float m = mnL[i * EMB + j];
                float x = x0L[i * EMB + j];
                c0 += m * wn0[j] + x * wr0[j];
                c1 += m * wn1[j] + x * wr1[j];
            }
            float s = sc[i];
            float v0 = fmaxf(c0, 0.f) * s;
            float v1 = fmaxf(c1, 0.f) * s;
            xY[r * 132 + lane] = v0;
            xY[r * 132 + 64 + lane] = v1;
            pm0 = fmaxf(pm0, v0); ps0 += v0;
            pm1 = fmaxf(pm1, v1); ps1 += v1;
        }
        redA[wv * 128 + lane] = pm0;
        redA[wv * 128 + 64 + lane] = pm1;
        redA[1280 + wv * 128 + lane] = ps0;
        redA[1280 + wv * 128 + 64 + lane] = ps1;
        __syncthreads();
        if (tid < 128) {
            float mx = redA[tid], sm = redA[1280 + tid];
            #pragma unroll
            for (int w = 1; w < 10; w++) {
                mx = fmaxf(mx, redA[w * 128 + tid]);
                sm += redA[1280 + w * 128 + tid];
            }
            g1[g * 256 + tid] = mx;
            g1[g * 256 + 128 + tid] = sm / (float)K1;
        }
        __syncthreads();
    }

    // ======================= Phase B: stage 2 =======================
    {
        if (tid < 256) deg[tid] = 0;
        __syncthreads();
        for (int e = tid; e < EPER; e += 640) {
            int a = pos1[es[eb + e] - nb0];
            int b = pos1[ed[eb + e] - nb0];
            if (a >= 0 && b >= 0) atomicAdd(&deg[b], 1);
        }
        __syncthreads();
        if (tid < 256) scanb[tid] = deg[tid];
        __syncthreads();
        #pragma unroll
        for (int d = 1; d < 256; d <<= 1) {
            int t = (tid < 256 && tid >= d) ? scanb[tid - d] : 0;
            __syncthreads();
            if (tid < 256) scanb[tid] += t;
            __syncthreads();
        }
        if (tid == 0) off2[0] = 0;
        if (tid < 256) off2[tid + 1] = scanb[tid];
        __syncthreads();
        if (tid < 256) cur[tid] = off2[tid];
        __syncthreads();
        for (int e = tid; e < EPER; e += 640) {
            int a = pos1[es[eb + e] - nb0];
            int b = pos1[ed[eb + e] - nb0];
            if (a >= 0 && b >= 0) {
                int slot = atomicAdd(&cur[b], 1);
                csr[slot] = a;
            }
        }
        __syncthreads();

        const int tc = tid & 31, tr = tid >> 5;   // tr 0..19
        float accY[8][4], accZ[8][4];
        #pragma unroll
        for (int r = 0; r < 8; r++)
            #pragma unroll
            for (int c = 0; c < 4; c++) { accY[r][c] = 0.f; accZ[r][c] = 0.f; }

        const int sr = tid >> 3, sc4 = (tid & 7) * 4;
        const bool stager = (sr < 64);
        const float* wsrc0 = (sr < 32) ? w2n : w2r;
        const int wrow = (sr < 32) ? sr : sr - 32;
        float* Bmine = S + ((sr < 32) ? 0 : 32 * 132);
        float4 bvv[4];
        if (stager) {
            #pragma unroll
            for (int i = 0; i < 4; i++)
                bvv[i] = *(const float4*)(wsrc0 + (size_t)(wrow + i * 32) * HID + sc4);
        }
        for (int ch = 0; ch < 4; ch++) {
            if (stager) {
                #pragma unroll
                for (int i = 0; i < 4; i++) {
                    int r = wrow + i * 32;
                    Bmine[(sc4 + 0) * 132 + r] = bvv[i].x;
                    Bmine[(sc4 + 1) * 132 + r] = bvv[i].y;
                    Bmine[(sc4 + 2) * 132 + r] = bvv[i].z;
                    Bmine[(sc4 + 3) * 132 + r] = bvv[i].w;
                }
            }
            __syncthreads();
            if (ch + 1 < 4 && stager) {
                #pragma unroll
                for (int i = 0; i < 4; i++)
                    bvv[i] = *(const float4*)(wsrc0 + (size_t)(wrow + i * 32) * HID
                                              + (ch + 1) * 32 + sc4);
            }
            for (int kq = 0; kq < 8; kq++) {
                float4 af[8];
                #pragma unroll
                for (int rr = 0; rr < 8; rr++)
                    af[rr] = *(const float4*)&xY[(tr * 8 + rr) * 132 + ch * 32 + kq * 4];
                #pragma unroll
                for (int kk = 0; kk < 4; kk++) {
                    int k = kq * 4 + kk;
                    float4 bn = *(const float4*)&S[k * 132 + tc * 4];
                    float4 br = *(const float4*)&S[32 * 132 + k * 132 + tc * 4];
                    #pragma unroll
                    for (int rr = 0; rr < 8; rr++) {
                        float a = (kk == 0) ? af[rr].x : (kk == 1) ? af[rr].y
                                 : (kk == 2) ? af[rr].z : af[rr].w;
                        accY[rr][0] += a * bn.x; accY[rr][1] += a * bn.y;
                        accY[rr][2] += a * bn.z; accY[rr][3] += a * bn.w;
                        accZ[rr][0] += a * br.x; accZ[rr][1] += a * br.y;
                        accZ[rr][2] += a * br.z; accZ[rr][3] += a * br.w;
                    }
                }
            }
            __syncthreads();
        }
        #pragma unroll
        for (int rr = 0; rr < 8; rr++) {
            float4 yv = {accY[rr][0], accY[rr][1], accY[rr][2], accY[rr][3]};
            *(float4*)&xY[(tr * 8 + rr) * 132 + tc * 4] = yv;
        }
        __syncthreads();

        float bias[4], pv[4];
        #pragma unroll
        for (int c = 0; c < 4; c++) {
            bias[c] = b2[tc * 4 + c];
            pv[c]   = p2[tc * 4 + c];
        }
        float a0 = p2[lane], a1 = p2[64 + lane];
        float pp = a0 * a0 + a1 * a1;
        #pragma unroll
        for (int o = 32; o >= 1; o >>= 1) pp += __shfl_xor(pp, o, 64);
        float nrm = sqrtf(pp);
        float outv[8][4];
        #pragma unroll
        for (int rr = 0; rr < 8; rr++) {
            int m = tr * 8 + rr;
            int bg = off2[m], en = off2[m + 1];
            float s0 = 0.f, s1 = 0.f, s2 = 0.f, s3 = 0.f;
            for (int t = bg; t < en; t++) {
                float4 yv = *(const float4*)&xY[csr[t] * 132 + tc * 4];
                s0 += yv.x; s1 += yv.y; s2 += yv.z; s3 += yv.w;
            }
            float inv = 1.f / (float)((en - bg) > 1 ? (en - bg) : 1);
            outv[rr][0] = fmaxf(s0 * inv + accZ[rr][0] + bias[0], 0.f);
            outv[rr][1] = fmaxf(s1 * inv + accZ[rr][1] + bias[1], 0.f);
            outv[rr][2] = fmaxf(s2 * inv + accZ[rr][2] + bias[2], 0.f);
            outv[rr][3] = fmaxf(s3 * inv + accZ[rr][3] + bias[3], 0.f);
        }
        float* scpart = S;
        __syncthreads();
        #pragma unroll
        for (int rr = 0; rr < 8; rr++) {
            float sp = outv[rr][0] * pv[0] + outv[rr][1] * pv[1]
                     + outv[rr][2] * pv[2] + outv[rr][3] * pv[3];
            scpart[(tr * 8 + rr) * 32 + tc] = sp;
        }
        __syncthreads();
        if (tid < K1) {
            float sum = 0.f;
            #pragma unroll
            for (int t = 0; t < 32; t++) sum += scpart[tid * 32 + t];
            sc[tid] = tanhf(sum / nrm);
        }
        __syncthreads();
        if (tid < K1) {
            float scv = sc[tid];
            int rank = 0;
            for (int j = 0; j < K1; j++) {
                float o = sc[j];
                rank += (o > scv) || (o == scv && j < tid);
            }
            pos2[tid] = (rank < K2) ? rank : -1;
        }
        __syncthreads();
        float cm[4], cs[4];
        #pragma unroll
        for (int c = 0; c < 4; c++) { cm[c] = -INFINITY; cs[c] = 0.f; }
        #pragma unroll
        for (int rr = 0; rr < 8; rr++) {
            int m = tr * 8 + rr;
            int r = pos2[m];
            if (r < 0) continue;
            float sv = sc[m];
            float v0 = outv[rr][0] * sv, v1 = outv[rr][1] * sv;
            float v2 = outv[rr][2] * sv, v3 = outv[rr][3] * sv;
            cm[0] = fmaxf(cm[0], v0); cs[0] += v0;
            cm[1] = fmaxf(cm[1], v1); cs[1] += v1;
            cm[2] = fmaxf(cm[2], v2); cs[2] += v2;
            cm[3] = fmaxf(cm[3], v3); cs[3] += v3;
            float4 o0 = {v0, v1, v2, v3};
            *(float4*)&xY[r * 132 + tc * 4] = o0;   // x2p stays in LDS
        }
        float* redM = S;
        float* redS = S + 20 * 128;
        #pragma unroll
        for (int c = 0; c < 4; c++) {
            redM[tr * 128 + tc * 4 + c] = cm[c];
            redS[tr * 128 + tc * 4 + c] = cs[c];
        }
        __syncthreads();
        if (tid < 128) {
            float mx = redM[tid], sm = redS[tid];
            #pragma unroll 4
            for (int t = 1; t < 20; t++) {
                mx = fmaxf(mx, redM[t * 128 + tid]);
                sm += redS[t * 128 + tid];
            }
            g2[g * 256 + tid] = mx;
            g2[g * 256 + 128 + tid] = sm / (float)K2;
        }
        __syncthreads();
    }

    // ======================= Phase C: stage 3 =======================
    {
        if (tid < 256) deg[tid] = 0;
        __syncthreads();
        for (int e = tid; e < EPER; e += 640) {
            int a = pos1[es[eb + e] - nb0];
            int b = pos1[ed[eb + e] - nb0];
            a = (a >= 0) ? pos2[a] : -1;
            b = (b >= 0) ? pos2[b] : -1;
            if (a >= 0 && b >= 0) atomicAdd(&deg[b], 1);
        }
        __syncthreads();
        if (tid < 256) scanb[tid] = deg[tid];
        __syncthreads();
        #pragma unroll
        for (int d = 1; d < 256; d <<= 1) {
            int t = (tid < 256 && tid >= d) ? scanb[tid - d] : 0;
            __syncthreads();
            if (tid < 256) scanb[tid] += t;
            __syncthreads();
        }
        if (tid == 0) off2[0] = 0;
        if (tid < 256) off2[tid + 1] = scanb[tid];
        __syncthreads();
        if (tid < 256) cur[tid] = off2[tid];
        __syncthreads();
        for (int e = tid; e < EPER; e += 640) {
            int a = pos1[es[eb + e] - nb0];
            int b = pos1[ed[eb + e] - nb0];
            a = (a >= 0) ? pos2[a] : -1;
            b = (b >= 0) ? pos2[b] : -1;
            if (a >= 0 && b >= 0) {
                int slot = atomicAdd(&cur[b], 1);
                csr[slot] = a;
            }
        }
        __syncthreads();

        const int tc = tid & 31, tr = tid >> 5;   // use tr<16
        const bool comp = (tid < 512);
        float accY[8][4], accZ[8][4];
        #pragma unroll
        for (int r = 0; r < 8; r++)
            #pragma unroll
            for (int c = 0; c < 4; c++) { accY[r][c] = 0.f; accZ[r][c] = 0.f; }

        const int sr = tid >> 3, sc4 = (tid & 7) * 4;
        const bool stager = (sr < 64);
        const float* wsrc0 = (sr < 32) ? w3n : w3r;
        const int wrow = (sr < 32) ? sr : sr - 32;
        float* Bmine = S + ((sr < 32) ? 0 : 32 * 132);
        float4 bvv[4];
        if (stager) {
            #pragma unroll
            for (int i = 0; i < 4; i++)
                bvv[i] = *(const float4*)(wsrc0 + (size_t)(wrow + i * 32) * HID + sc4);
        }
        for (int ch = 0; ch < 4; ch++) {
            if (stager) {
                #pragma unroll
                for (int i = 0; i < 4; i++) {
                    int r = wrow + i * 32;
                    Bmine[(sc4 + 0) * 132 + r] = bvv[i].x;
                    Bmine[(sc4 + 1) * 132 + r] = bvv[i].y;
                    Bmine[(sc4 + 2) * 132 + r] = bvv[i].z;
                    Bmine[(sc4 + 3) * 132 + r] = bvv[i].w;
                }
            }
            __syncthreads();
            if (ch + 1 < 4 && stager) {
                #pragma unroll
                for (int i = 0; i < 4; i++)
                    bvv[i] = *(const float4*)(wsrc0 + (size_t)(wrow + i * 32) * HID
                                              + (ch + 1) * 32 + sc4);
            }
            if (comp) {
                for (int kq = 0; kq < 8; kq++) {
                    float4 af[8];
                    #pragma unroll
                    for (int rr = 0; rr < 8; rr++)
                        af[rr] = *(const float4*)&xY[(tr * 8 + rr) * 132 + ch * 32 + kq * 4];
                    #pragma unroll
                    for (int kk = 0; kk < 4; kk++) {
                        int k = kq * 4 + kk;
                        float4 bn = *(const float4*)&S[k * 132 + tc * 4];
                        float4 br = *(const float4*)&S[32 * 132 + k * 132 + tc * 4];
                        #pragma unroll
                        for (int rr = 0; rr < 8; rr++) {
                            float a = (kk == 0) ? af[rr].x : (kk == 1) ? af[rr].y
                                     : (kk == 2) ? af[rr].z : af[rr].w;
                            accY[rr][0] += a * bn.x; accY[rr][1] += a * bn.y;
                            accY[rr][2] += a * bn.z; accY[rr][3] += a * bn.w;
                            accZ[rr][0] += a * br.x; accZ[rr][1] += a * br.y;
                            accZ[rr][2] += a * br.z; accZ[rr][3] += a * br.w;
                        }
                    }
                }
            }
            __syncthreads();
        }
        if (comp) {
            #pragma unroll
            for (int rr = 0; rr < 8; rr++) {
                float4 yv = {accY[rr][0], accY[rr][1], accY[rr][2], accY[rr][3]};
                *(float4*)&xY[(tr * 8 + rr) * 132 + tc * 4] = yv;
            }
        }
        __syncthreads();

        float bias[4], pv[4];
        #pragma unroll
        for (int c = 0; c < 4; c++) {
            bias[c] = b3[tc * 4 + c];
            pv[c]   = p3[tc * 4 + c];
        }
        float a0 = p3[lane], a1 = p3[64 + lane];
        float pp = a0 * a0 + a1 * a1;
        #pragma unroll
        for (int o = 32; o >= 1; o >>= 1) pp += __shfl_xor(pp, o, 64);
        float nrm = sqrtf(pp);
        float outv[8][4];
        float* scpart = S;
        if (comp) {
            #pragma unroll
            for (int rr = 0; rr < 8; rr++) {
                int m = tr * 8 + rr;
                int bg = off2[m], en = off2[m + 1];
                float s0 = 0.f, s1 = 0.f, s2 = 0.f, s3 = 0.f;
                for (int t = bg; t < en; t++) {
                    float4 yv = *(const float4*)&xY[csr[t] * 132 + tc * 4];
                    s0 += yv.x; s1 += yv.y; s2 += yv.z; s3 += yv.w;
                }
                float inv = 1.f / (float)((en - bg) > 1 ? (en - bg) : 1);
                outv[rr][0] = fmaxf(s0 * inv + accZ[rr][0] + bias[0], 0.f);
                outv[rr][1] = fmaxf(s1 * inv + accZ[rr][1] + bias[1], 0.f);
                outv[rr][2] = fmaxf(s2 * inv + accZ[rr][2] + bias[2], 0.f);
                outv[rr][3] = fmaxf(s3 * inv + accZ[rr][3] + bias[3], 0.f);
            }
        }
        __syncthreads();
        if (comp) {
            #pragma unroll
            for (int rr = 0; rr < 8; rr++) {
                float sp = outv[rr][0] * pv[0] + outv[rr][1] * pv[1]
                         + outv[rr][2] * pv[2] + outv[rr][3] * pv[3];
                scpart[(tr * 8 + rr) * 32 + tc] = sp;
            }
        }
        __syncthreads();
        if (tid < K2) {
            float sum = 0.f;
            #pragma unroll
            for (int t = 0; t < 32; t++) sum += scpart[tid * 32 + t];
            sc[tid] = tanhf(sum / nrm);
        }
        __syncthreads();
        int* posC = idsL;   // idsL dead since phase A gather
        if (tid < K2) {
            float scv = sc[tid];
            int rank = 0;
            for (int j = 0; j < K2; j++) {
                float o = sc[j];
                rank += (o > scv) || (o == scv && j < tid);
            }
            posC[tid] = (rank < K3) ? rank : -1;
        }
        __syncthreads();
        float cm[4], cs[4];
        #pragma unroll
        for (int c = 0; c < 4; c++) { cm[c] = -INFINITY; cs[c] = 0.f; }
        if (comp) {
            #pragma unroll
            for (int rr = 0; rr < 8; rr++) {
                int m = tr * 8 + rr;
                int r = posC[m];
                if (r < 0) continue;
                float sv = sc[m];
                #pragma unroll
                for (int c = 0; c < 4; c++) {
                    float v = outv[rr][c] * sv;
                    cm[c] = fmaxf(cm[c], v);
                    cs[c] += v;
                }
            }
        }
        float* redM = S;
        float* redS = S + 16 * 128;
        if (comp) {
            #pragma unroll
            for (int c = 0; c < 4; c++) {
                redM[tr * 128 + tc * 4 + c] = cm[c];
                redS[tr * 128 + tc * 4 + c] = cs[c];
            }
        }
        __syncthreads();
        if (tid < 128) {
            float mx = redM[tid], sm = redS[tid];
            #pragma unroll 4
            for (int t = 1; t < 16; t++) {
                mx = fmaxf(mx, redM[t * 128 + tid]);
                sm += redS[t * 128 + tid];
            }
            g3[g * 256 + tid] = mx;
            g3[g * 256 + 128 + tid] = sm / (float)K3;
        }
    }
}

// ---------------------------------------------------------------------------
// MLP head: h=g1+g2+g3; relu(h@lw1.T+lb1); relu(@lw2.T+lb2); sigmoid(@lw3.T+lb3)
__global__ __launch_bounds__(128) void k_mlp(const float* __restrict__ g1, const float* __restrict__ g2,
                      const float* __restrict__ g3,
                      const float* __restrict__ lw1, const float* __restrict__ lb1,
                      const float* __restrict__ lw2, const float* __restrict__ lb2,
                      const float* __restrict__ lw3, const float* __restrict__ lb3,
                      float* __restrict__ out) {
    int g = blockIdx.x, t = threadIdx.x;  // 128 threads
    __shared__ float h0[256];
    __shared__ float h1[128];
    __shared__ float h2r[64];
    h0[t]       = g1[g * 256 + t] + g2[g * 256 + t] + g3[g * 256 + t];
    h0[t + 128] = g1[g * 256 + 128 + t] + g2[g * 256 + 128 + t] + g3[g * 256 + 128 + t];
    __syncthreads();
    float a = lb1[t];
    #pragma unroll 4
    for (int j = 0; j < 256; j++) a += h0[j] * lw1[t * 256 + j];
    h1[t] = fmaxf(a, 0.f);
    __syncthreads();
    if (t < 64) {
        float a2 = lb2[t];
        #pragma unroll 4
        for (int j = 0; j < 128; j++) a2 += h1[j] * lw2[t * 128 + j];
        h2r[t] = fmaxf(a2, 0.f) * lw3[t];
    }
    __syncthreads();
    if (t == 0) {
        float s = 0.f;
        for (int j = 0; j < 64; j++) s += h2r[j];
        s += lb3[0];
        out[g] = 1.f / (1.f + expf(-s));
    }
}

// ---------------------------------------------------------------------------
extern "C" void kernel_launch(void* const* d_in, const int* in_sizes, int n_in,
                              void* d_out, int out_size, void* d_ws, size_t ws_size,
                              hipStream_t stream) {
    const int*   node_ids = (const int*)d_in[0];
    const int*   ei   = (const int*)d_in[1];   // edge_index (2, E)
    const float* emb  = (const float*)d_in[3];
    const float* w1n  = (const float*)d_in[4];
    const float* w1r  = (const float*)d_in[5];
    const float* b1   = (const float*)d_in[6];
    const float* w2n  = (const float*)d_in[7];
    const float* w2r  = (const float*)d_in[8];
    const float* b2   = (const float*)d_in[9];
    const float* w3n  = (const float*)d_in[10];
    const float* w3r  = (const float*)d_in[11];
    const float* b3   = (const float*)d_in[12];
    const float* p1   = (const float*)d_in[13];
    const float* p2   = (const float*)d_in[14];
    const float* p3   = (const float*)d_in[15];
    const float* lw1  = (const float*)d_in[16];
    const float* lb1  = (const float*)d_in[17];
    const float* lw2  = (const float*)d_in[18];
    const float* lb2  = (const float*)d_in[19];
    const float* lw3  = (const float*)d_in[20];
    const float* lb3  = (const float*)d_in[21];
    float* out = (float*)d_out;

    // Workspace: only the three global-pool buffers (1.5 MB).
    float* ws  = (float*)d_ws;
    float* g1  = ws;                 // B*256
    float* g2  = g1 + B * 2 * HID;   // B*256
    float* g3  = g2 + B * 2 * HID;   // B*256

    k_fused<<<B, 640, 0, stream>>>(node_ids, emb, ei, ei + E,
                                   w1n, w1r, b1, p1,
                                   w2n, w2r, b2, p2,
                                   w3n, w3r, b3, p3,
                                   g1, g2, g3);
    k_mlp<<<B, 128, 0, stream>>>(g1, g2, g3, lw1, lb1, lw2, lb2, lw3, lb3, out);
}